// Round 19
// baseline (583.780 us; speedup 1.0000x reference)
//
#include <hip/hip_runtime.h>

#define EPSBN 1e-5f
#define NB 1024           // buckets (dst >> 8), 256 nodes per bucket
#define GB 512            // blocks for cnt/reorder tiles
#define CAP 12288         // LDS sort buffer capacity (edges)

typedef float vf4 __attribute__((ext_vector_type(4)));
typedef int   vi2 __attribute__((ext_vector_type(2)));
typedef int   vi4 __attribute__((ext_vector_type(4)));
typedef unsigned int uint32;

__device__ __forceinline__ float ftanh(float x) {
    return 1.0f - 2.0f / (__expf(2.0f * x) + 1.0f);
}

__device__ __forceinline__ float wave_sum(float v) {
#pragma unroll
    for (int off = 32; off > 0; off >>= 1) v += __shfl_down(v, off);
    return v;
}

__device__ __forceinline__ void z1_of(const float4 hi, const float4 hj,
                                      const float* __restrict__ w, const float* __restrict__ b,
                                      float* z) {
#pragma unroll
    for (int j = 0; j < 8; ++j) {
        z[j] = b[j]
             + hi.x * w[0 * 8 + j] + hi.y * w[1 * 8 + j] + hi.z * w[2 * 8 + j] + hi.w * w[3 * 8 + j]
             + hj.x * w[4 * 8 + j] + hj.y * w[5 * 8 + j] + hj.z * w[6 * 8 + j] + hj.w * w[7 * 8 + j];
    }
}

__device__ __forceinline__ void mat8x4(const float* u, const float* w,
                                       const float* b, float* z) {
#pragma unroll
    for (int c = 0; c < 4; ++c) {
        float t = b[c];
#pragma unroll
        for (int k = 0; k < 8; ++k) t += u[k] * w[k * 4 + c];
        z[c] = t;
    }
}

__device__ __forceinline__ void mat8x8(const float* u, const float* __restrict__ w,
                                       const float* __restrict__ b, float* z) {
#pragma unroll
    for (int j = 0; j < 8; ++j) {
        float t = b[j];
#pragma unroll
        for (int k = 0; k < 8; ++k) t += u[k] * w[k * 8 + j];
        z[j] = t;
    }
}

template <int NV>
__device__ __forceinline__ void block_reduce_atomics(float* a, float* __restrict__ sums) {
    __shared__ float red[NV * 4];
    int wid = threadIdx.x >> 6, lane = threadIdx.x & 63;
#pragma unroll
    for (int i = 0; i < NV; ++i) {
        float v = wave_sum(a[i]);
        if (lane == 0) red[i * 4 + wid] = v;
    }
    __syncthreads();
    if (threadIdx.x < NV) {
        float v = red[threadIdx.x * 4 + 0] + red[threadIdx.x * 4 + 1]
                + red[threadIdx.x * 4 + 2] + red[threadIdx.x * 4 + 3];
        atomicAdd(&sums[threadIdx.x], v);
    }
}

// compute BN scale/shift into LDS from raw sums (all threads; syncs inside)
__device__ __forceinline__ void fin_lds(const float* __restrict__ sums,
                                        const float* __restrict__ g, const float* __restrict__ be,
                                        int d, float inv, float* out) {
    int j = threadIdx.x;
    if (j < d) {
        float mu = sums[j] * inv;
        float var = sums[d + j] * inv - mu * mu;
        float s = g[j] * rsqrtf(var + EPSBN);
        out[j] = s;
        out[d + j] = be[j] - mu * s;
    }
    __syncthreads();
}

// per-edge z1-stats accumulate (h-based; used in fused k_cnt + fallback)
__device__ __forceinline__ void stats1_edge(float4 hi, float4 hj,
                                            const float* __restrict__ w1, const float* __restrict__ b1,
                                            float* a) {
    float z[8];
    z1_of(hi, hj, w1, b1, z);
#pragma unroll
    for (int j = 0; j < 8; ++j) { a[j] += z[j]; a[8 + j] += z[j] * z[j]; }
}

// h-based z2 (fallback path only)
__device__ __forceinline__ vf4 z2_edge(float4 hi, float4 hj,
                                       const float* __restrict__ w1, const float* __restrict__ b1,
                                       const float* ss1,
                                       const float* __restrict__ w2, const float* __restrict__ b2) {
    float z[8], m1[8], z2[4];
    z1_of(hi, hj, w1, b1, z);
#pragma unroll
    for (int j = 0; j < 8; ++j) m1[j] = ftanh(z[j] * ss1[j] + ss1[8 + j]);
    mat8x4(m1, w2, b2, z2);
    vf4 r = {z2[0], z2[1], z2[2], z2[3]};
    return r;
}

__device__ __forceinline__ void stats2_edge(float4 hi, float4 hj,
                                            const float* __restrict__ w1, const float* __restrict__ b1,
                                            const float* ss1,
                                            const float* __restrict__ w2, const float* __restrict__ b2,
                                            float* a) {
    vf4 q = z2_edge(hi, hj, w1, b1, ss1, w2, b2);
    a[0] += q.x; a[4] += q.x * q.x;
    a[1] += q.y; a[5] += q.y * q.y;
    a[2] += q.z; a[6] += q.z * q.z;
    a[3] += q.w; a[7] += q.w * q.w;
}

// table-based m1 (BN1 pre-folded into tables)
__device__ __forceinline__ void m1_of(vf4 ziA, vf4 ziB, vf4 zjA, vf4 zjB, float* m1) {
    m1[0] = ftanh(ziA.x + zjA.x); m1[1] = ftanh(ziA.y + zjA.y);
    m1[2] = ftanh(ziA.z + zjA.z); m1[3] = ftanh(ziA.w + zjA.w);
    m1[4] = ftanh(ziB.x + zjB.x); m1[5] = ftanh(ziB.y + zjB.y);
    m1[6] = ftanh(ziB.z + zjB.z); m1[7] = ftanh(ziB.w + zjB.w);
}

// table-based z2-stats
__device__ __forceinline__ void stats2t_edge(int s, int d,
                                             const vf4* __restrict__ ziS, const vf4* __restrict__ zjS,
                                             const float* __restrict__ w2, const float* __restrict__ b2,
                                             float* a) {
    vf4 ziA = ziS[2 * (size_t)d], ziB = ziS[2 * (size_t)d + 1];
    vf4 zjA = zjS[2 * (size_t)s], zjB = zjS[2 * (size_t)s + 1];
    float m1[8], z2[4];
    m1_of(ziA, ziB, zjA, zjB, m1);
    mat8x4(m1, w2, b2, z2);
    a[0] += z2[0]; a[4] += z2[0] * z2[0];
    a[1] += z2[1]; a[5] += z2[1] * z2[1];
    a[2] += z2[2]; a[6] += z2[2] * z2[2];
    a[3] += z2[3]; a[7] += z2[3] * z2[3];
}

// ---------------- node input projection ----------------
__global__ __launch_bounds__(256) void k_h(const float* __restrict__ pos, const float* __restrict__ vel,
                                           const float* __restrict__ w, const float* __restrict__ b,
                                           float4* __restrict__ h, int n) {
    int i = blockIdx.x * blockDim.x + threadIdx.x;
    if (i >= n) return;
    float2 p = ((const float2*)pos)[i];
    float2 v = ((const float2*)vel)[i];
    float o[4];
#pragma unroll
    for (int d = 0; d < 4; ++d)
        o[d] = b[d] + p.x * w[0 * 4 + d] + p.y * w[1 * 4 + d] + v.x * w[2 * 4 + d] + v.y * w[3 * 4 + d];
    h[i] = make_float4(o[0], o[1], o[2], o[3]);
}

// ---------------- z-tables: zi_raw = Wi^T h, zj_raw = Wj^T h + b1 ----------------
__global__ __launch_bounds__(256) void k_zt(const float4* __restrict__ h,
                                            const float* __restrict__ w1, const float* __restrict__ b1,
                                            vf4* __restrict__ zi, vf4* __restrict__ zj, int n) {
    int i = blockIdx.x * blockDim.x + threadIdx.x;
    if (i >= n) return;
    float4 hv = h[i];
    float zi8[8], zj8[8];
#pragma unroll
    for (int j = 0; j < 8; ++j) {
        zi8[j] = hv.x * w1[0 * 8 + j] + hv.y * w1[1 * 8 + j] + hv.z * w1[2 * 8 + j] + hv.w * w1[3 * 8 + j];
        zj8[j] = b1[j]
               + hv.x * w1[4 * 8 + j] + hv.y * w1[5 * 8 + j] + hv.z * w1[6 * 8 + j] + hv.w * w1[7 * 8 + j];
    }
    vf4 a = {zi8[0], zi8[1], zi8[2], zi8[3]};
    vf4 b_ = {zi8[4], zi8[5], zi8[6], zi8[7]};
    vf4 c = {zj8[0], zj8[1], zj8[2], zj8[3]};
    vf4 d = {zj8[4], zj8[5], zj8[6], zj8[7]};
    zi[2 * (size_t)i] = a; zi[2 * (size_t)i + 1] = b_;
    zj[2 * (size_t)i] = c; zj[2 * (size_t)i + 1] = d;
}

// ---------------- fold BN1 into z-tables (after stats1 known) ----------------
__global__ __launch_bounds__(256) void k_fold(vf4* __restrict__ zi, vf4* __restrict__ zj,
                                              const float* __restrict__ sums1,
                                              const float* __restrict__ g1, const float* __restrict__ be1,
                                              float invE, int n) {
    __shared__ float ss1[16];
    fin_lds(sums1, g1, be1, 8, invE, ss1);
    int i = blockIdx.x * blockDim.x + threadIdx.x;
    if (i >= n) return;
    vf4 a = zi[2 * (size_t)i], b = zi[2 * (size_t)i + 1];
    a.x *= ss1[0]; a.y *= ss1[1]; a.z *= ss1[2]; a.w *= ss1[3];
    b.x *= ss1[4]; b.y *= ss1[5]; b.z *= ss1[6]; b.w *= ss1[7];
    zi[2 * (size_t)i] = a; zi[2 * (size_t)i + 1] = b;
    vf4 c = zj[2 * (size_t)i], d = zj[2 * (size_t)i + 1];
    c.x = c.x * ss1[0] + ss1[8];  c.y = c.y * ss1[1] + ss1[9];
    c.z = c.z * ss1[2] + ss1[10]; c.w = c.w * ss1[3] + ss1[11];
    d.x = d.x * ss1[4] + ss1[12]; d.y = d.y * ss1[5] + ss1[13];
    d.z = d.z * ss1[6] + ss1[14]; d.w = d.w * ss1[7] + ss1[15];
    zj[2 * (size_t)i] = c; zj[2 * (size_t)i + 1] = d;
}

// ---------------- fold BN2 into w2/b2 (after z2 stats known) ----------------
__global__ void k_foldw(const float* __restrict__ sums2,
                        const float* __restrict__ g2, const float* __restrict__ be2, float invE,
                        const float* __restrict__ w2, const float* __restrict__ b2,
                        float* __restrict__ w2f, float* __restrict__ b2f) {
    __shared__ float ss2[8];
    int j = threadIdx.x;
    if (j < 4) {
        float mu = sums2[j] * invE;
        float var = sums2[4 + j] * invE - mu * mu;
        float s = g2[j] * rsqrtf(var + EPSBN);
        ss2[j] = s;
        ss2[4 + j] = be2[j] - mu * s;
    }
    __syncthreads();
    if (j < 32) w2f[j] = w2[j] * ss2[j & 3];
    if (j < 4)  b2f[j] = b2[j] * ss2[j] + ss2[4 + j];
}

// ---------------- count + fused z1 stats (h-based gathers; no scatter) ----------------
__global__ __launch_bounds__(256, 2) void k_cnt(const int* __restrict__ idx, const float4* __restrict__ h,
                                                const float* __restrict__ w1, const float* __restrict__ b1,
                                                uint32* __restrict__ cntmat, float* __restrict__ sums,
                                                int E_, int T) {
    __shared__ uint32 hist[NB];
    for (int b = threadIdx.x; b < NB; b += 256) hist[b] = 0;
    float a[16];
#pragma unroll
    for (int i = 0; i < 16; ++i) a[i] = 0.f;
    __syncthreads();
    int lo = blockIdx.x * T, hi2 = min(E_, lo + T);
    for (int e0 = lo + 4 * threadIdx.x; e0 < hi2; e0 += 1024) {
        int m = min(4, hi2 - e0);
        if (m == 4) {
            int s0 = __builtin_nontemporal_load(idx + e0);
            int s1 = __builtin_nontemporal_load(idx + e0 + 1);
            int s2 = __builtin_nontemporal_load(idx + e0 + 2);
            int s3 = __builtin_nontemporal_load(idx + e0 + 3);
            int d0 = __builtin_nontemporal_load(idx + E_ + e0);
            int d1 = __builtin_nontemporal_load(idx + E_ + e0 + 1);
            int d2 = __builtin_nontemporal_load(idx + E_ + e0 + 2);
            int d3 = __builtin_nontemporal_load(idx + E_ + e0 + 3);
            float4 hi0 = h[d0], hj0 = h[s0];
            float4 hi1 = h[d1], hj1 = h[s1];
            float4 hi2 = h[d2], hj2 = h[s2];
            float4 hi3 = h[d3], hj3 = h[s3];
            atomicAdd(&hist[d0 >> 8], 1u);
            atomicAdd(&hist[d1 >> 8], 1u);
            atomicAdd(&hist[d2 >> 8], 1u);
            atomicAdd(&hist[d3 >> 8], 1u);
            stats1_edge(hi0, hj0, w1, b1, a);
            stats1_edge(hi1, hj1, w1, b1, a);
            stats1_edge(hi2, hj2, w1, b1, a);
            stats1_edge(hi3, hj3, w1, b1, a);
        } else {
            for (int k = 0; k < m; ++k) {
                int s = __builtin_nontemporal_load(idx + e0 + k);
                int d = __builtin_nontemporal_load(idx + E_ + e0 + k);
                float4 hi = h[d], hj = h[s];
                atomicAdd(&hist[d >> 8], 1u);
                stats1_edge(hi, hj, w1, b1, a);
            }
        }
    }
    __syncthreads();
    for (int b = threadIdx.x; b < NB; b += 256)
        cntmat[(size_t)b * GB + blockIdx.x] = hist[b];
    block_reduce_atomics<16>(a, sums);
}

// block-scan of 512 uints (256 threads x 2), exclusive
__device__ __forceinline__ void scan512(uint32* v, uint32* excl_out, uint32* total) {
    __shared__ uint32 ts[256];
    uint32 local = v[0] + v[1];
    ts[threadIdx.x] = local;
    __syncthreads();
    for (int off = 1; off < 256; off <<= 1) {
        uint32 t = (threadIdx.x >= (uint32)off) ? ts[threadIdx.x - off] : 0u;
        __syncthreads();
        ts[threadIdx.x] += t;
        __syncthreads();
    }
    *excl_out = ts[threadIdx.x] - local;
    *total = ts[255];
}

// block-scan of 1024 uints (256 threads x 4), exclusive
__device__ __forceinline__ void scan1024(uint32* v, uint32* excl_out, uint32* total) {
    __shared__ uint32 ts[256];
    uint32 local = v[0] + v[1] + v[2] + v[3];
    ts[threadIdx.x] = local;
    __syncthreads();
    for (int off = 1; off < 256; off <<= 1) {
        uint32 t = (threadIdx.x >= (uint32)off) ? ts[threadIdx.x - off] : 0u;
        __syncthreads();
        ts[threadIdx.x] += t;
        __syncthreads();
    }
    *excl_out = ts[threadIdx.x] - local;
    *total = ts[255];
}

__global__ __launch_bounds__(256) void k_scanA(uint32* __restrict__ cntmat, uint32* __restrict__ rowtot) {
    size_t base = (size_t)blockIdx.x * GB + threadIdx.x * 2;
    uint32 v[2];
    v[0] = cntmat[base]; v[1] = cntmat[base + 1];
    uint32 excl, tot;
    scan512(v, &excl, &tot);
    cntmat[base] = excl;
    cntmat[base + 1] = excl + v[0];
    if (threadIdx.x == 0) rowtot[blockIdx.x] = tot;
}

__global__ __launch_bounds__(256) void k_scanB(const uint32* __restrict__ rowtot, uint32* __restrict__ bbase) {
    uint32 v[4];
#pragma unroll
    for (int k = 0; k < 4; ++k) v[k] = rowtot[threadIdx.x * 4 + k];
    uint32 excl, tot;
    scan1024(v, &excl, &tot);
    uint32 run = excl;
#pragma unroll
    for (int k = 0; k < 4; ++k) { uint32 t = v[k]; bbase[threadIdx.x * 4 + k] = run; run += t; }
    if (threadIdx.x == 0) bbase[NB] = tot;
}

// ---------------- reorder: pure 8B scatter, 4-edge batches ----------------
__global__ __launch_bounds__(256) void k_reorder(const int* __restrict__ idx,
                                                 const uint32* __restrict__ cntmat, const uint32* __restrict__ bbase,
                                                 vi2* __restrict__ sp, int E_, int T) {
    __shared__ uint32 cur[NB];
    for (int b = threadIdx.x; b < NB; b += 256)
        cur[b] = bbase[b] + cntmat[(size_t)b * GB + blockIdx.x];
    __syncthreads();
    int lo = blockIdx.x * T, hi2 = min(E_, lo + T);
    for (int e0 = lo + 4 * threadIdx.x; e0 < hi2; e0 += 1024) {
        int m = min(4, hi2 - e0);
        if (m == 4) {
            int s0 = __builtin_nontemporal_load(idx + e0);
            int s1 = __builtin_nontemporal_load(idx + e0 + 1);
            int s2 = __builtin_nontemporal_load(idx + e0 + 2);
            int s3 = __builtin_nontemporal_load(idx + e0 + 3);
            int d0 = __builtin_nontemporal_load(idx + E_ + e0);
            int d1 = __builtin_nontemporal_load(idx + E_ + e0 + 1);
            int d2 = __builtin_nontemporal_load(idx + E_ + e0 + 2);
            int d3 = __builtin_nontemporal_load(idx + E_ + e0 + 3);
            uint32 p0 = atomicAdd(&cur[d0 >> 8], 1u);
            uint32 p1 = atomicAdd(&cur[d1 >> 8], 1u);
            uint32 p2 = atomicAdd(&cur[d2 >> 8], 1u);
            uint32 p3 = atomicAdd(&cur[d3 >> 8], 1u);
            vi2 v0 = {s0, d0}; sp[p0] = v0;
            vi2 v1 = {s1, d1}; sp[p1] = v1;
            vi2 v2 = {s2, d2}; sp[p2] = v2;
            vi2 v3 = {s3, d3}; sp[p3] = v3;
        } else {
            for (int k = 0; k < m; ++k) {
                int s = __builtin_nontemporal_load(idx + e0 + k);
                int d = __builtin_nontemporal_load(idx + E_ + e0 + k);
                uint32 pos = atomicAdd(&cur[d >> 8], 1u);
                vi2 v = {s, d};
                sp[pos] = v;
            }
        }
    }
}

// ---------------- sort2: per-bucket counting sort staged in LDS -> CSR ----------------
__global__ __launch_bounds__(256) void k_sort2(const vi2* __restrict__ sp,
                                               const uint32* __restrict__ bbase, const uint32* __restrict__ rowtot,
                                               int* __restrict__ src2, uint32* __restrict__ nodeoff, int n) {
    extern __shared__ uint32 buf[];
    __shared__ uint32 hist[256];
    __shared__ uint32 cur[256];
    __shared__ uint32 ts[256];
    int b = blockIdx.x;
    uint32 start = bbase[b];
    uint32 len = rowtot[b];
    uint32 end = start + len;
    hist[threadIdx.x] = 0;
    __syncthreads();
    for (uint32 e = start + threadIdx.x; e < end; e += 256) {
        vi2 v = __builtin_nontemporal_load(&sp[e]);
        atomicAdd(&hist[v.y & 255], 1u);
    }
    __syncthreads();
    uint32 local = hist[threadIdx.x];
    ts[threadIdx.x] = local;
    __syncthreads();
    for (int off = 1; off < 256; off <<= 1) {
        uint32 t = (threadIdx.x >= (uint32)off) ? ts[threadIdx.x - off] : 0u;
        __syncthreads();
        ts[threadIdx.x] += t;
        __syncthreads();
    }
    uint32 excl = ts[threadIdx.x] - local;
    cur[threadIdx.x] = excl;
    int node = (b << 8) + threadIdx.x;
    if (node <= n) nodeoff[node] = start + excl;
    __syncthreads();
    for (uint32 e = start + threadIdx.x; e < end; e += 256) {
        vi2 v = __builtin_nontemporal_load(&sp[e]);
        uint32 pos = atomicAdd(&cur[v.y & 255], 1u);
        if (pos < (uint32)CAP) buf[pos] = (uint32)v.x;
        else src2[start + pos] = v.x;
    }
    __syncthreads();
    uint32 lim = min(len, (uint32)CAP);
    for (uint32 k = threadIdx.x; k < lim; k += 256)
        src2[start + k] = (int)buf[k];
}

// ---------------- finalize BN stats -> scale/shift (fallback path only) ----------------
__global__ void k_fin(const float* __restrict__ sums, float* __restrict__ ss,
                      const float* __restrict__ g, const float* __restrict__ be,
                      int d, float inv_count) {
    int j = threadIdx.x;
    if (j >= d) return;
    float mu = sums[j] * inv_count;
    float var = sums[d + j] * inv_count - mu * mu;
    float s = g[j] * rsqrtf(var + EPSBN);
    ss[j] = s;
    ss[d + j] = be[j] - mu * s;
}

// ---------------- E2: table-based z2 stats over sorted sp ----------------
__global__ __launch_bounds__(256, 2) void e_pass2(const vi2* __restrict__ sp,
                                                  const vf4* __restrict__ ziS, const vf4* __restrict__ zjS,
                                                  const float* __restrict__ w2, const float* __restrict__ b2,
                                                  float* __restrict__ sums2, int E_) {
    float a[8];
#pragma unroll
    for (int i = 0; i < 8; ++i) a[i] = 0.f;
    int stride4 = gridDim.x * blockDim.x * 4;
    for (int e0 = (blockIdx.x * blockDim.x + threadIdx.x) * 4; e0 < E_; e0 += stride4) {
        int m = min(4, E_ - e0);
        if (m == 4) {
            vi4 A = __builtin_nontemporal_load((const vi4*)(sp + e0));
            vi4 B = __builtin_nontemporal_load((const vi4*)(sp + e0 + 2));
            stats2t_edge(A.x, A.y, ziS, zjS, w2, b2, a);
            stats2t_edge(A.z, A.w, ziS, zjS, w2, b2, a);
            stats2t_edge(B.x, B.y, ziS, zjS, w2, b2, a);
            stats2t_edge(B.z, B.w, ziS, zjS, w2, b2, a);
        } else {
            for (int k = 0; k < m; ++k) {
                vi2 v = __builtin_nontemporal_load(&sp[e0 + k]);
                stats2t_edge(v.x, v.y, ziS, zjS, w2, b2, a);
            }
        }
    }
    block_reduce_atomics<8>(a, sums2);
}

// ---------------- aggregate over CSR: 32-lane group per node; tables; folded BN2 ----------------
__global__ __launch_bounds__(256, 2) void e_aggr_csr(const int* __restrict__ src2, const uint32* __restrict__ nodeoff,
                                                     const vf4* __restrict__ ziS, const vf4* __restrict__ zjS,
                                                     const float* __restrict__ w2f, const float* __restrict__ b2f,
                                                     float* __restrict__ acc, int n) {
    __shared__ float w2l[32];
    __shared__ float b2l[4];
    if (threadIdx.x < 32) w2l[threadIdx.x] = w2f[threadIdx.x];
    if (threadIdx.x < 4)  b2l[threadIdx.x] = b2f[threadIdx.x];
    __syncthreads();
    int lane = threadIdx.x & 31;
    int gid0 = (blockIdx.x * 256 + threadIdx.x) >> 5;
    int gstride = (gridDim.x * 256) >> 5;
    for (int i = gid0; i < n; i += gstride) {
        uint32 e0 = nodeoff[i], e1 = nodeoff[i + 1];
        vf4 ziA = ziS[2 * (size_t)i], ziB = ziS[2 * (size_t)i + 1];
        float a0 = 0.f, a1 = 0.f, a2 = 0.f, a3 = 0.f;
        for (uint32 e = e0 + lane; e < e1; e += 32) {
            int s = src2[e];
            vf4 zjA = zjS[2 * (size_t)s], zjB = zjS[2 * (size_t)s + 1];
            if (s != i) {    // self-loop <=> h_i == h_j for random-normal inputs
                float m1[8], z2[4];
                m1_of(ziA, ziB, zjA, zjB, m1);
                mat8x4(m1, w2l, b2l, z2);
                a0 += ftanh(z2[0]);
                a1 += ftanh(z2[1]);
                a2 += ftanh(z2[2]);
                a3 += ftanh(z2[3]);
            }
        }
#pragma unroll
        for (int off = 16; off > 0; off >>= 1) {
            a0 += __shfl_down(a0, off, 32);
            a1 += __shfl_down(a1, off, 32);
            a2 += __shfl_down(a2, off, 32);
            a3 += __shfl_down(a3, off, 32);
        }
        if (lane == 0) {
            float* ap = acc + 8 * (size_t)i;
            ap[0] = a0; ap[1] = a1; ap[2] = a2; ap[3] = a3;
            ap[4] = (float)(e1 - e0);
        }
    }
}

// ---------------- fallback edge kernels (round-1 style, used if ws too small) ----------------
__global__ __launch_bounds__(256) void fb_stats1(const int* __restrict__ idx, const float4* __restrict__ h,
                                                 const float* __restrict__ w1, const float* __restrict__ b1,
                                                 float* __restrict__ sums, float* __restrict__ acc, int E_) {
    float a[16];
#pragma unroll
    for (int i = 0; i < 16; ++i) a[i] = 0.f;
    int stride = gridDim.x * blockDim.x;
    for (int e = blockIdx.x * blockDim.x + threadIdx.x; e < E_; e += stride) {
        int s = __builtin_nontemporal_load(idx + e);
        int d = __builtin_nontemporal_load(idx + E_ + e);
        float4 hi = h[d], hj = h[s];
        stats1_edge(hi, hj, w1, b1, a);
        atomicAdd(acc + 8 * (size_t)d + 4, 1.0f);
    }
    block_reduce_atomics<16>(a, sums);
}

__global__ __launch_bounds__(256) void fb_stats2(const int* __restrict__ idx, const float4* __restrict__ h,
                                                 const float* __restrict__ w1, const float* __restrict__ b1,
                                                 const float* __restrict__ ss1,
                                                 const float* __restrict__ w2, const float* __restrict__ b2,
                                                 float* __restrict__ sums2, int E_) {
    float a[8];
#pragma unroll
    for (int i = 0; i < 8; ++i) a[i] = 0.f;
    int stride = gridDim.x * blockDim.x;
    for (int e = blockIdx.x * blockDim.x + threadIdx.x; e < E_; e += stride) {
        int s = __builtin_nontemporal_load(idx + e);
        int d = __builtin_nontemporal_load(idx + E_ + e);
        float4 hi = h[d], hj = h[s];
        stats2_edge(hi, hj, w1, b1, ss1, w2, b2, a);
    }
    block_reduce_atomics<8>(a, sums2);
}

__global__ __launch_bounds__(256) void fb_scatter(const int* __restrict__ idx, const float4* __restrict__ h,
                                                  const float* __restrict__ w1, const float* __restrict__ b1,
                                                  const float* __restrict__ ss1,
                                                  const float* __restrict__ w2, const float* __restrict__ b2,
                                                  const float* __restrict__ ss2,
                                                  float* __restrict__ acc, int E_) {
    int stride = gridDim.x * blockDim.x;
    for (int e = blockIdx.x * blockDim.x + threadIdx.x; e < E_; e += stride) {
        int s = __builtin_nontemporal_load(idx + e);
        int d = __builtin_nontemporal_load(idx + E_ + e);
        float4 hi = h[d], hj = h[s];
        bool zero = (hi.x == hj.x) && (hi.y == hj.y) && (hi.z == hj.z) && (hi.w == hj.w);
        if (zero) continue;
        vf4 q = z2_edge(hi, hj, w1, b1, ss1, w2, b2);
        float m0 = ftanh(q.x * ss2[0] + ss2[4]);
        float m1v = ftanh(q.y * ss2[1] + ss2[5]);
        float m2v = ftanh(q.z * ss2[2] + ss2[6]);
        float m3 = ftanh(q.w * ss2[3] + ss2[7]);
        float* ap = acc + 8 * (size_t)d;
        atomicAdd(ap + 0, m0);
        atomicAdd(ap + 1, m1v);
        atomicAdd(ap + 2, m2v);
        atomicAdd(ap + 3, m3);
    }
}

// ---------------- node update MLP ----------------
__device__ __forceinline__ void load_u(int i, const float4* __restrict__ h,
                                       const float* __restrict__ acc, float* u) {
    float4 hv = h[i];
    const float* ap = acc + 8 * (size_t)i;
    float c = fmaxf(ap[4], 1.0f);
    u[0] = hv.x; u[1] = hv.y; u[2] = hv.z; u[3] = hv.w;
    u[4] = ap[0]; u[5] = ap[1]; u[6] = ap[2] / c; u[7] = ap[3] / c;
}

__global__ __launch_bounds__(256) void n_stats1(const float4* __restrict__ h,
                                                const float* __restrict__ acc,
                                                const float* __restrict__ w, const float* __restrict__ b,
                                                float* __restrict__ sums, int n) {
    float a[16];
#pragma unroll
    for (int i = 0; i < 16; ++i) a[i] = 0.f;
    int stride = gridDim.x * blockDim.x;
    for (int i = blockIdx.x * blockDim.x + threadIdx.x; i < n; i += stride) {
        float u[8], z[8];
        load_u(i, h, acc, u);
        mat8x8(u, w, b, z);
#pragma unroll
        for (int j = 0; j < 8; ++j) { a[j] += z[j]; a[8 + j] += z[j] * z[j]; }
    }
    block_reduce_atomics<16>(a, sums);
}

__global__ __launch_bounds__(256) void n_stats2(const float4* __restrict__ h,
                                                const float* __restrict__ acc,
                                                const float* __restrict__ w1, const float* __restrict__ b1,
                                                const float* __restrict__ sums3,
                                                const float* __restrict__ g3, const float* __restrict__ be3,
                                                float invN,
                                                const float* __restrict__ w2, const float* __restrict__ b2,
                                                float* __restrict__ sums, int n) {
    __shared__ float ss3[16];
    fin_lds(sums3, g3, be3, 8, invN, ss3);
    float a[8];
#pragma unroll
    for (int i = 0; i < 8; ++i) a[i] = 0.f;
    int stride = gridDim.x * blockDim.x;
    for (int i = blockIdx.x * blockDim.x + threadIdx.x; i < n; i += stride) {
        float u[8], z[8], u1[8], z4[4];
        load_u(i, h, acc, u);
        mat8x8(u, w1, b1, z);
#pragma unroll
        for (int j = 0; j < 8; ++j) u1[j] = ftanh(z[j] * ss3[j] + ss3[8 + j]);
        mat8x4(u1, w2, b2, z4);
#pragma unroll
        for (int c = 0; c < 4; ++c) { a[c] += z4[c]; a[4 + c] += z4[c] * z4[c]; }
    }
    block_reduce_atomics<8>(a, sums);
}

__global__ __launch_bounds__(256) void n_final(const float4* __restrict__ h,
                                               const float* __restrict__ acc,
                                               const float* __restrict__ w1, const float* __restrict__ b1,
                                               const float* __restrict__ sums3,
                                               const float* __restrict__ g3, const float* __restrict__ be3,
                                               const float* __restrict__ sums4,
                                               const float* __restrict__ g4, const float* __restrict__ be4,
                                               float invN,
                                               const float* __restrict__ w2, const float* __restrict__ b2,
                                               const float* __restrict__ pw, const float* __restrict__ pb,
                                               float2* __restrict__ out, int n) {
    __shared__ float ss3[16];
    __shared__ float ss4[8];
    fin_lds(sums3, g3, be3, 8, invN, ss3);
    fin_lds(sums4, g4, be4, 4, invN, ss4);
    int stride = gridDim.x * blockDim.x;
    for (int i = blockIdx.x * blockDim.x + threadIdx.x; i < n; i += stride) {
        float u[8], z[8], u1[8], z4[4], u2[4];
        load_u(i, h, acc, u);
        mat8x8(u, w1, b1, z);
#pragma unroll
        for (int j = 0; j < 8; ++j) u1[j] = ftanh(z[j] * ss3[j] + ss3[8 + j]);
        mat8x4(u1, w2, b2, z4);
#pragma unroll
        for (int c = 0; c < 4; ++c) u2[c] = ftanh(z4[c] * ss4[c] + ss4[4 + c]);
        float o0 = pb[0] + u2[0] * pw[0] + u2[1] * pw[2] + u2[2] * pw[4] + u2[3] * pw[6];
        float o1 = pb[1] + u2[0] * pw[1] + u2[1] * pw[3] + u2[2] * pw[5] + u2[3] * pw[7];
        out[i] = make_float2(o0, o1);
    }
}

extern "C" void kernel_launch(void* const* d_in, const int* in_sizes, int n_in,
                              void* d_out, int out_size, void* d_ws, size_t ws_size,
                              hipStream_t stream) {
    const float* pos  = (const float*)d_in[0];
    const float* vel  = (const float*)d_in[1];
    const int*   eidx = (const int*)d_in[2];
    const float* lin_w = (const float*)d_in[3];
    const float* lin_b = (const float*)d_in[4];
    const float* mw1 = (const float*)d_in[5];
    const float* mb1 = (const float*)d_in[6];
    const float* mg1 = (const float*)d_in[7];
    const float* mbe1 = (const float*)d_in[8];
    const float* mw2 = (const float*)d_in[9];
    const float* mb2 = (const float*)d_in[10];
    const float* mg2 = (const float*)d_in[11];
    const float* mbe2 = (const float*)d_in[12];
    const float* uw1 = (const float*)d_in[13];
    const float* ub1 = (const float*)d_in[14];
    const float* ug1 = (const float*)d_in[15];
    const float* ube1 = (const float*)d_in[16];
    const float* uw2 = (const float*)d_in[17];
    const float* ub2 = (const float*)d_in[18];
    const float* ug2 = (const float*)d_in[19];
    const float* ube2 = (const float*)d_in[20];
    const float* pw = (const float*)d_in[21];
    const float* pb = (const float*)d_in[22];

    int n  = in_sizes[0] / 2;
    int E_ = in_sizes[2] / 2;
    float invE = 1.0f / (float)E_;
    float invN = 1.0f / (float)n;

    // ---- workspace layout (bump allocator, 16B aligned) ----
    char* base = (char*)d_ws;
    size_t off = 0;
    auto alloc = [&](size_t bytes) {
        off = (off + 15) & ~(size_t)15;
        void* p = base + off;
        off += bytes;
        return p;
    };
    float4* h       = (float4*)alloc(16 * (size_t)n);                // 4 MB
    float*  acc     = (float*)alloc(32 * (size_t)n);                 // 8 MB
    float*  sums    = (float*)alloc(512);
    float*  ss      = sums + 64;
    float*  w2fb    = (float*)alloc(256);                            // folded w2 (32) + b2 (4)
    uint32* bbase   = (uint32*)alloc(4 * (NB + 1));
    uint32* rowtot  = (uint32*)alloc(4 * NB);
    uint32* cntmat  = (uint32*)alloc(4 * (size_t)NB * GB);           // 2 MB
    uint32* nodeoff = (uint32*)alloc(4 * ((size_t)n + 1));           // 1 MB
    vf4*    ziS     = (vf4*)alloc(32 * (size_t)n);                   // 8 MB
    vf4*    zjS     = (vf4*)alloc(32 * (size_t)n);                   // 8 MB
    int*    src2    = (int*)alloc(4 * (size_t)E_);                   // 32 MB
    vi2*    sp      = (vi2*)alloc(8 * (size_t)E_);                   // 64 MB
    size_t need_sort = off;                                           // ~127 MB

    bool big = ws_size >= need_sort;

    int nblk = (n + 255) / 256;
    int nbuckets = (n + 255) >> 8;
    int T = (E_ + GB - 1) / GB;

    k_h<<<nblk, 256, 0, stream>>>(pos, vel, lin_w, lin_b, h, n);

    if (big) {
        (void)hipMemsetAsync(sums, 0, 256, stream);

        k_zt<<<nblk, 256, 0, stream>>>(h, mw1, mb1, ziS, zjS, n);

        // fused histogram + z1 stats (gather-only)
        k_cnt<<<GB, 256, 0, stream>>>(eidx, h, mw1, mb1, cntmat, sums, E_, T);
        k_scanA<<<NB, 256, 0, stream>>>(cntmat, rowtot);
        k_scanB<<<1, 256, 0, stream>>>(rowtot, bbase);

        // fold BN1 into z-tables
        k_fold<<<nblk, 256, 0, stream>>>(ziS, zjS, sums, mg1, mbe1, invE, n);

        k_reorder<<<GB, 256, 0, stream>>>(eidx, cntmat, bbase, sp, E_, T);
        k_sort2<<<nbuckets, 256, CAP * 4, stream>>>(sp, bbase, rowtot, src2, nodeoff, n);

        e_pass2<<<2048, 256, 0, stream>>>(sp, ziS, zjS, mw2, mb2, sums + 16, E_);

        k_foldw<<<1, 64, 0, stream>>>(sums + 16, mg2, mbe2, invE, mw2, mb2, w2fb, w2fb + 32);

        e_aggr_csr<<<4096, 256, 0, stream>>>(src2, nodeoff, ziS, zjS, w2fb, w2fb + 32, acc, n);

        n_stats1<<<nblk, 256, 0, stream>>>(h, acc, uw1, ub1, sums + 24, n);
        n_stats2<<<nblk, 256, 0, stream>>>(h, acc, uw1, ub1, sums + 24, ug1, ube1, invN,
                                           uw2, ub2, sums + 40, n);
        n_final<<<nblk, 256, 0, stream>>>(h, acc, uw1, ub1, sums + 24, ug1, ube1,
                                          sums + 40, ug2, ube2, invN,
                                          uw2, ub2, pw, pb, (float2*)d_out, n);
    } else {
        (void)hipMemsetAsync(acc, 0, 32 * (size_t)n + 256, stream);

        fb_stats1<<<4096, 256, 0, stream>>>(eidx, h, mw1, mb1, sums, acc, E_);
        k_fin<<<1, 64, 0, stream>>>(sums, ss, mg1, mbe1, 8, invE);

        fb_stats2<<<4096, 256, 0, stream>>>(eidx, h, mw1, mb1, ss, mw2, mb2, sums + 16, E_);
        k_fin<<<1, 64, 0, stream>>>(sums + 16, ss + 16, mg2, mbe2, 4, invE);

        fb_scatter<<<4096, 256, 0, stream>>>(eidx, h, mw1, mb1, ss, mw2, mb2, ss + 16, acc, E_);

        n_stats1<<<nblk, 256, 0, stream>>>(h, acc, uw1, ub1, sums + 24, n);
        n_stats2<<<nblk, 256, 0, stream>>>(h, acc, uw1, ub1, sums + 24, ug1, ube1, invN,
                                           uw2, ub2, sums + 40, n);
        n_final<<<nblk, 256, 0, stream>>>(h, acc, uw1, ub1, sums + 24, ug1, ube1,
                                          sums + 40, ug2, ube2, invN,
                                          uw2, ub2, pw, pb, (float2*)d_out, n);
    }
}

// Round 20
// 555.013 us; speedup vs baseline: 1.0518x; 1.0518x over previous
//
#include <hip/hip_runtime.h>

#define EPSBN 1e-5f
#define NB 512            // buckets (dst >> 9), 512 nodes per bucket
#define GB 256            // blocks for cnt/reorder tiles (long runs: ~61 edges/bucket/block)
#define CAP 18000         // LDS sort buffer capacity (edges); mean ~16360 + 13 sigma

typedef float vf4 __attribute__((ext_vector_type(4)));
typedef int   vi2 __attribute__((ext_vector_type(2)));
typedef int   vi4 __attribute__((ext_vector_type(4)));
typedef unsigned int uint32;

__device__ __forceinline__ float ftanh(float x) {
    return 1.0f - 2.0f / (__expf(2.0f * x) + 1.0f);
}

__device__ __forceinline__ float wave_sum(float v) {
#pragma unroll
    for (int off = 32; off > 0; off >>= 1) v += __shfl_down(v, off);
    return v;
}

__device__ __forceinline__ void z1_of(const float4 hi, const float4 hj,
                                      const float* __restrict__ w, const float* __restrict__ b,
                                      float* z) {
#pragma unroll
    for (int j = 0; j < 8; ++j) {
        z[j] = b[j]
             + hi.x * w[0 * 8 + j] + hi.y * w[1 * 8 + j] + hi.z * w[2 * 8 + j] + hi.w * w[3 * 8 + j]
             + hj.x * w[4 * 8 + j] + hj.y * w[5 * 8 + j] + hj.z * w[6 * 8 + j] + hj.w * w[7 * 8 + j];
    }
}

__device__ __forceinline__ void mat8x4(const float* u, const float* w,
                                       const float* b, float* z) {
#pragma unroll
    for (int c = 0; c < 4; ++c) {
        float t = b[c];
#pragma unroll
        for (int k = 0; k < 8; ++k) t += u[k] * w[k * 4 + c];
        z[c] = t;
    }
}

__device__ __forceinline__ void mat8x8(const float* u, const float* __restrict__ w,
                                       const float* __restrict__ b, float* z) {
#pragma unroll
    for (int j = 0; j < 8; ++j) {
        float t = b[j];
#pragma unroll
        for (int k = 0; k < 8; ++k) t += u[k] * w[k * 8 + j];
        z[j] = t;
    }
}

template <int NV>
__device__ __forceinline__ void block_reduce_atomics(float* a, float* __restrict__ sums) {
    __shared__ float red[NV * 4];
    int wid = threadIdx.x >> 6, lane = threadIdx.x & 63;
#pragma unroll
    for (int i = 0; i < NV; ++i) {
        float v = wave_sum(a[i]);
        if (lane == 0) red[i * 4 + wid] = v;
    }
    __syncthreads();
    if (threadIdx.x < NV) {
        float v = red[threadIdx.x * 4 + 0] + red[threadIdx.x * 4 + 1]
                + red[threadIdx.x * 4 + 2] + red[threadIdx.x * 4 + 3];
        atomicAdd(&sums[threadIdx.x], v);
    }
}

// compute BN scale/shift into LDS from raw sums (all threads; syncs inside)
__device__ __forceinline__ void fin_lds(const float* __restrict__ sums,
                                        const float* __restrict__ g, const float* __restrict__ be,
                                        int d, float inv, float* out) {
    int j = threadIdx.x;
    if (j < d) {
        float mu = sums[j] * inv;
        float var = sums[d + j] * inv - mu * mu;
        float s = g[j] * rsqrtf(var + EPSBN);
        out[j] = s;
        out[d + j] = be[j] - mu * s;
    }
    __syncthreads();
}

// per-edge z1-stats accumulate (h-based; used in fused k_cnt + fallback)
__device__ __forceinline__ void stats1_edge(float4 hi, float4 hj,
                                            const float* __restrict__ w1, const float* __restrict__ b1,
                                            float* a) {
    float z[8];
    z1_of(hi, hj, w1, b1, z);
#pragma unroll
    for (int j = 0; j < 8; ++j) { a[j] += z[j]; a[8 + j] += z[j] * z[j]; }
}

// h-based z2 (fallback path only)
__device__ __forceinline__ vf4 z2_edge(float4 hi, float4 hj,
                                       const float* __restrict__ w1, const float* __restrict__ b1,
                                       const float* ss1,
                                       const float* __restrict__ w2, const float* __restrict__ b2) {
    float z[8], m1[8], z2[4];
    z1_of(hi, hj, w1, b1, z);
#pragma unroll
    for (int j = 0; j < 8; ++j) m1[j] = ftanh(z[j] * ss1[j] + ss1[8 + j]);
    mat8x4(m1, w2, b2, z2);
    vf4 r = {z2[0], z2[1], z2[2], z2[3]};
    return r;
}

__device__ __forceinline__ void stats2_edge(float4 hi, float4 hj,
                                            const float* __restrict__ w1, const float* __restrict__ b1,
                                            const float* ss1,
                                            const float* __restrict__ w2, const float* __restrict__ b2,
                                            float* a) {
    vf4 q = z2_edge(hi, hj, w1, b1, ss1, w2, b2);
    a[0] += q.x; a[4] += q.x * q.x;
    a[1] += q.y; a[5] += q.y * q.y;
    a[2] += q.z; a[6] += q.z * q.z;
    a[3] += q.w; a[7] += q.w * q.w;
}

// table-based m1 (BN1 pre-folded into tables)
__device__ __forceinline__ void m1_of(vf4 ziA, vf4 ziB, vf4 zjA, vf4 zjB, float* m1) {
    m1[0] = ftanh(ziA.x + zjA.x); m1[1] = ftanh(ziA.y + zjA.y);
    m1[2] = ftanh(ziA.z + zjA.z); m1[3] = ftanh(ziA.w + zjA.w);
    m1[4] = ftanh(ziB.x + zjB.x); m1[5] = ftanh(ziB.y + zjB.y);
    m1[6] = ftanh(ziB.z + zjB.z); m1[7] = ftanh(ziB.w + zjB.w);
}

// table-based z2-stats
__device__ __forceinline__ void stats2t_edge(int s, int d,
                                             const vf4* __restrict__ ziS, const vf4* __restrict__ zjS,
                                             const float* __restrict__ w2, const float* __restrict__ b2,
                                             float* a) {
    vf4 ziA = ziS[2 * (size_t)d], ziB = ziS[2 * (size_t)d + 1];
    vf4 zjA = zjS[2 * (size_t)s], zjB = zjS[2 * (size_t)s + 1];
    float m1[8], z2[4];
    m1_of(ziA, ziB, zjA, zjB, m1);
    mat8x4(m1, w2, b2, z2);
    a[0] += z2[0]; a[4] += z2[0] * z2[0];
    a[1] += z2[1]; a[5] += z2[1] * z2[1];
    a[2] += z2[2]; a[6] += z2[2] * z2[2];
    a[3] += z2[3]; a[7] += z2[3] * z2[3];
}

// ---------------- node input projection ----------------
__global__ __launch_bounds__(256) void k_h(const float* __restrict__ pos, const float* __restrict__ vel,
                                           const float* __restrict__ w, const float* __restrict__ b,
                                           float4* __restrict__ h, int n) {
    int i = blockIdx.x * blockDim.x + threadIdx.x;
    if (i >= n) return;
    float2 p = ((const float2*)pos)[i];
    float2 v = ((const float2*)vel)[i];
    float o[4];
#pragma unroll
    for (int d = 0; d < 4; ++d)
        o[d] = b[d] + p.x * w[0 * 4 + d] + p.y * w[1 * 4 + d] + v.x * w[2 * 4 + d] + v.y * w[3 * 4 + d];
    h[i] = make_float4(o[0], o[1], o[2], o[3]);
}

// ---------------- z-tables: zi_raw = Wi^T h, zj_raw = Wj^T h + b1 ----------------
__global__ __launch_bounds__(256) void k_zt(const float4* __restrict__ h,
                                            const float* __restrict__ w1, const float* __restrict__ b1,
                                            vf4* __restrict__ zi, vf4* __restrict__ zj, int n) {
    int i = blockIdx.x * blockDim.x + threadIdx.x;
    if (i >= n) return;
    float4 hv = h[i];
    float zi8[8], zj8[8];
#pragma unroll
    for (int j = 0; j < 8; ++j) {
        zi8[j] = hv.x * w1[0 * 8 + j] + hv.y * w1[1 * 8 + j] + hv.z * w1[2 * 8 + j] + hv.w * w1[3 * 8 + j];
        zj8[j] = b1[j]
               + hv.x * w1[4 * 8 + j] + hv.y * w1[5 * 8 + j] + hv.z * w1[6 * 8 + j] + hv.w * w1[7 * 8 + j];
    }
    vf4 a = {zi8[0], zi8[1], zi8[2], zi8[3]};
    vf4 b_ = {zi8[4], zi8[5], zi8[6], zi8[7]};
    vf4 c = {zj8[0], zj8[1], zj8[2], zj8[3]};
    vf4 d = {zj8[4], zj8[5], zj8[6], zj8[7]};
    zi[2 * (size_t)i] = a; zi[2 * (size_t)i + 1] = b_;
    zj[2 * (size_t)i] = c; zj[2 * (size_t)i + 1] = d;
}

// ---------------- fold BN1 into z-tables (after stats1 known) ----------------
__global__ __launch_bounds__(256) void k_fold(vf4* __restrict__ zi, vf4* __restrict__ zj,
                                              const float* __restrict__ sums1,
                                              const float* __restrict__ g1, const float* __restrict__ be1,
                                              float invE, int n) {
    __shared__ float ss1[16];
    fin_lds(sums1, g1, be1, 8, invE, ss1);
    int i = blockIdx.x * blockDim.x + threadIdx.x;
    if (i >= n) return;
    vf4 a = zi[2 * (size_t)i], b = zi[2 * (size_t)i + 1];
    a.x *= ss1[0]; a.y *= ss1[1]; a.z *= ss1[2]; a.w *= ss1[3];
    b.x *= ss1[4]; b.y *= ss1[5]; b.z *= ss1[6]; b.w *= ss1[7];
    zi[2 * (size_t)i] = a; zi[2 * (size_t)i + 1] = b;
    vf4 c = zj[2 * (size_t)i], d = zj[2 * (size_t)i + 1];
    c.x = c.x * ss1[0] + ss1[8];  c.y = c.y * ss1[1] + ss1[9];
    c.z = c.z * ss1[2] + ss1[10]; c.w = c.w * ss1[3] + ss1[11];
    d.x = d.x * ss1[4] + ss1[12]; d.y = d.y * ss1[5] + ss1[13];
    d.z = d.z * ss1[6] + ss1[14]; d.w = d.w * ss1[7] + ss1[15];
    zj[2 * (size_t)i] = c; zj[2 * (size_t)i + 1] = d;
}

// ---------------- fold BN2 into w2/b2 ----------------
__global__ void k_foldw(const float* __restrict__ sums2,
                        const float* __restrict__ g2, const float* __restrict__ be2, float invE,
                        const float* __restrict__ w2, const float* __restrict__ b2,
                        float* __restrict__ w2f, float* __restrict__ b2f) {
    __shared__ float ss2[8];
    int j = threadIdx.x;
    if (j < 4) {
        float mu = sums2[j] * invE;
        float var = sums2[4 + j] * invE - mu * mu;
        float s = g2[j] * rsqrtf(var + EPSBN);
        ss2[j] = s;
        ss2[4 + j] = be2[j] - mu * s;
    }
    __syncthreads();
    if (j < 32) w2f[j] = w2[j] * ss2[j & 3];
    if (j < 4)  b2f[j] = b2[j] * ss2[j] + ss2[4 + j];
}

// ---------------- count + fused z1 stats (h-based gathers; no scatter) ----------------
__global__ __launch_bounds__(256, 2) void k_cnt(const int* __restrict__ idx, const float4* __restrict__ h,
                                                const float* __restrict__ w1, const float* __restrict__ b1,
                                                uint32* __restrict__ cntmat, float* __restrict__ sums,
                                                int E_, int T) {
    __shared__ uint32 hist[NB];
    for (int b = threadIdx.x; b < NB; b += 256) hist[b] = 0;
    float a[16];
#pragma unroll
    for (int i = 0; i < 16; ++i) a[i] = 0.f;
    __syncthreads();
    int lo = blockIdx.x * T, hi2 = min(E_, lo + T);
    for (int e0 = lo + 4 * threadIdx.x; e0 < hi2; e0 += 1024) {
        int m = min(4, hi2 - e0);
        if (m == 4) {
            int s0 = __builtin_nontemporal_load(idx + e0);
            int s1 = __builtin_nontemporal_load(idx + e0 + 1);
            int s2 = __builtin_nontemporal_load(idx + e0 + 2);
            int s3 = __builtin_nontemporal_load(idx + e0 + 3);
            int d0 = __builtin_nontemporal_load(idx + E_ + e0);
            int d1 = __builtin_nontemporal_load(idx + E_ + e0 + 1);
            int d2 = __builtin_nontemporal_load(idx + E_ + e0 + 2);
            int d3 = __builtin_nontemporal_load(idx + E_ + e0 + 3);
            float4 hi0 = h[d0], hj0 = h[s0];
            float4 hi1 = h[d1], hj1 = h[s1];
            float4 hi2 = h[d2], hj2 = h[s2];
            float4 hi3 = h[d3], hj3 = h[s3];
            atomicAdd(&hist[d0 >> 9], 1u);
            atomicAdd(&hist[d1 >> 9], 1u);
            atomicAdd(&hist[d2 >> 9], 1u);
            atomicAdd(&hist[d3 >> 9], 1u);
            stats1_edge(hi0, hj0, w1, b1, a);
            stats1_edge(hi1, hj1, w1, b1, a);
            stats1_edge(hi2, hj2, w1, b1, a);
            stats1_edge(hi3, hj3, w1, b1, a);
        } else {
            for (int k = 0; k < m; ++k) {
                int s = __builtin_nontemporal_load(idx + e0 + k);
                int d = __builtin_nontemporal_load(idx + E_ + e0 + k);
                float4 hi = h[d], hj = h[s];
                atomicAdd(&hist[d >> 9], 1u);
                stats1_edge(hi, hj, w1, b1, a);
            }
        }
    }
    __syncthreads();
    for (int b = threadIdx.x; b < NB; b += 256)
        cntmat[(size_t)b * GB + blockIdx.x] = hist[b];
    block_reduce_atomics<16>(a, sums);
}

// block-scan of 256 uints (1/thread), exclusive
__device__ __forceinline__ void scan256(uint32 v, uint32* excl_out, uint32* total) {
    __shared__ uint32 ts[256];
    ts[threadIdx.x] = v;
    __syncthreads();
    for (int off = 1; off < 256; off <<= 1) {
        uint32 t = (threadIdx.x >= (uint32)off) ? ts[threadIdx.x - off] : 0u;
        __syncthreads();
        ts[threadIdx.x] += t;
        __syncthreads();
    }
    *excl_out = ts[threadIdx.x] - v;
    *total = ts[255];
}

// block-scan of 512 uints (2/thread), exclusive
__device__ __forceinline__ void scan512(uint32* v, uint32* excl_out, uint32* total) {
    __shared__ uint32 ts[256];
    uint32 local = v[0] + v[1];
    ts[threadIdx.x] = local;
    __syncthreads();
    for (int off = 1; off < 256; off <<= 1) {
        uint32 t = (threadIdx.x >= (uint32)off) ? ts[threadIdx.x - off] : 0u;
        __syncthreads();
        ts[threadIdx.x] += t;
        __syncthreads();
    }
    *excl_out = ts[threadIdx.x] - local;
    *total = ts[255];
}

// scan each bucket row of cntmat (GB=256 tiles), exclusive, write row totals
__global__ __launch_bounds__(256) void k_scanA(uint32* __restrict__ cntmat, uint32* __restrict__ rowtot) {
    size_t base = (size_t)blockIdx.x * GB + threadIdx.x;
    uint32 v = cntmat[base];
    uint32 excl, tot;
    scan256(v, &excl, &tot);
    cntmat[base] = excl;
    if (threadIdx.x == 0) rowtot[blockIdx.x] = tot;
}

// scan 512 rowtots -> bucket bases
__global__ __launch_bounds__(256) void k_scanB(const uint32* __restrict__ rowtot, uint32* __restrict__ bbase) {
    uint32 v[2];
    v[0] = rowtot[threadIdx.x * 2]; v[1] = rowtot[threadIdx.x * 2 + 1];
    uint32 excl, tot;
    scan512(v, &excl, &tot);
    bbase[threadIdx.x * 2] = excl;
    bbase[threadIdx.x * 2 + 1] = excl + v[0];
    if (threadIdx.x == 0) bbase[NB] = tot;
}

// ---------------- reorder: pure 8B scatter, 4-edge batches, long runs ----------------
__global__ __launch_bounds__(256) void k_reorder(const int* __restrict__ idx,
                                                 const uint32* __restrict__ cntmat, const uint32* __restrict__ bbase,
                                                 vi2* __restrict__ sp, int E_, int T) {
    __shared__ uint32 cur[NB];
    for (int b = threadIdx.x; b < NB; b += 256)
        cur[b] = bbase[b] + cntmat[(size_t)b * GB + blockIdx.x];
    __syncthreads();
    int lo = blockIdx.x * T, hi2 = min(E_, lo + T);
    for (int e0 = lo + 4 * threadIdx.x; e0 < hi2; e0 += 1024) {
        int m = min(4, hi2 - e0);
        if (m == 4) {
            int s0 = __builtin_nontemporal_load(idx + e0);
            int s1 = __builtin_nontemporal_load(idx + e0 + 1);
            int s2 = __builtin_nontemporal_load(idx + e0 + 2);
            int s3 = __builtin_nontemporal_load(idx + e0 + 3);
            int d0 = __builtin_nontemporal_load(idx + E_ + e0);
            int d1 = __builtin_nontemporal_load(idx + E_ + e0 + 1);
            int d2 = __builtin_nontemporal_load(idx + E_ + e0 + 2);
            int d3 = __builtin_nontemporal_load(idx + E_ + e0 + 3);
            uint32 p0 = atomicAdd(&cur[d0 >> 9], 1u);
            uint32 p1 = atomicAdd(&cur[d1 >> 9], 1u);
            uint32 p2 = atomicAdd(&cur[d2 >> 9], 1u);
            uint32 p3 = atomicAdd(&cur[d3 >> 9], 1u);
            vi2 v0 = {s0, d0}; sp[p0] = v0;
            vi2 v1 = {s1, d1}; sp[p1] = v1;
            vi2 v2 = {s2, d2}; sp[p2] = v2;
            vi2 v3 = {s3, d3}; sp[p3] = v3;
        } else {
            for (int k = 0; k < m; ++k) {
                int s = __builtin_nontemporal_load(idx + e0 + k);
                int d = __builtin_nontemporal_load(idx + E_ + e0 + k);
                uint32 pos = atomicAdd(&cur[d >> 9], 1u);
                vi2 v = {s, d};
                sp[pos] = v;
            }
        }
    }
}

// ---------------- sort2: per-bucket counting sort staged in LDS -> CSR ----------------
__global__ __launch_bounds__(256) void k_sort2(const vi2* __restrict__ sp,
                                               const uint32* __restrict__ bbase, const uint32* __restrict__ rowtot,
                                               int* __restrict__ src2, uint32* __restrict__ nodeoff, int n) {
    extern __shared__ uint32 buf[];      // CAP entries (72 KB)
    __shared__ uint32 hist[512];
    __shared__ uint32 cur[512];
    int b = blockIdx.x;
    uint32 start = bbase[b];
    uint32 len = rowtot[b];
    uint32 end = start + len;
    hist[threadIdx.x] = 0;
    hist[threadIdx.x + 256] = 0;
    __syncthreads();
    for (uint32 e = start + threadIdx.x; e < end; e += 256) {
        vi2 v = __builtin_nontemporal_load(&sp[e]);
        atomicAdd(&hist[v.y & 511], 1u);
    }
    __syncthreads();
    uint32 vv[2];
    vv[0] = hist[2 * threadIdx.x];
    vv[1] = hist[2 * threadIdx.x + 1];
    uint32 excl, tot;
    scan512(vv, &excl, &tot);
    cur[2 * threadIdx.x] = excl;
    cur[2 * threadIdx.x + 1] = excl + vv[0];
    int nodebase = b << 9;
    int node0 = nodebase + 2 * threadIdx.x;
    if (node0 <= n)     nodeoff[node0] = start + excl;
    if (node0 + 1 <= n) nodeoff[node0 + 1] = start + excl + vv[0];
    __syncthreads();
    for (uint32 e = start + threadIdx.x; e < end; e += 256) {
        vi2 v = __builtin_nontemporal_load(&sp[e]);
        uint32 pos = atomicAdd(&cur[v.y & 511], 1u);
        if (pos < (uint32)CAP) buf[pos] = (uint32)v.x;
        else src2[start + pos] = v.x;
    }
    __syncthreads();
    uint32 lim = min(len, (uint32)CAP);
    for (uint32 k = threadIdx.x; k < lim; k += 256)
        src2[start + k] = (int)buf[k];
}

// ---------------- finalize BN stats -> scale/shift (fallback path only) ----------------
__global__ void k_fin(const float* __restrict__ sums, float* __restrict__ ss,
                      const float* __restrict__ g, const float* __restrict__ be,
                      int d, float inv_count) {
    int j = threadIdx.x;
    if (j >= d) return;
    float mu = sums[j] * inv_count;
    float var = sums[d + j] * inv_count - mu * mu;
    float s = g[j] * rsqrtf(var + EPSBN);
    ss[j] = s;
    ss[d + j] = be[j] - mu * s;
}

// ---------------- E2: table-based z2 stats over sorted sp ----------------
__global__ __launch_bounds__(256, 2) void e_pass2(const vi2* __restrict__ sp,
                                                  const vf4* __restrict__ ziS, const vf4* __restrict__ zjS,
                                                  const float* __restrict__ w2, const float* __restrict__ b2,
                                                  float* __restrict__ sums2, int E_) {
    float a[8];
#pragma unroll
    for (int i = 0; i < 8; ++i) a[i] = 0.f;
    int stride4 = gridDim.x * blockDim.x * 4;
    for (int e0 = (blockIdx.x * blockDim.x + threadIdx.x) * 4; e0 < E_; e0 += stride4) {
        int m = min(4, E_ - e0);
        if (m == 4) {
            vi4 A = __builtin_nontemporal_load((const vi4*)(sp + e0));
            vi4 B = __builtin_nontemporal_load((const vi4*)(sp + e0 + 2));
            stats2t_edge(A.x, A.y, ziS, zjS, w2, b2, a);
            stats2t_edge(A.z, A.w, ziS, zjS, w2, b2, a);
            stats2t_edge(B.x, B.y, ziS, zjS, w2, b2, a);
            stats2t_edge(B.z, B.w, ziS, zjS, w2, b2, a);
        } else {
            for (int k = 0; k < m; ++k) {
                vi2 v = __builtin_nontemporal_load(&sp[e0 + k]);
                stats2t_edge(v.x, v.y, ziS, zjS, w2, b2, a);
            }
        }
    }
    block_reduce_atomics<8>(a, sums2);
}

// ---------------- aggregate over CSR: 16-lane group per node; tables; folded BN2 ----------------
__global__ __launch_bounds__(256, 2) void e_aggr_csr(const int* __restrict__ src2, const uint32* __restrict__ nodeoff,
                                                     const vf4* __restrict__ ziS, const vf4* __restrict__ zjS,
                                                     const float* __restrict__ w2f, const float* __restrict__ b2f,
                                                     float* __restrict__ acc, int n) {
    __shared__ float w2l[32];
    __shared__ float b2l[4];
    if (threadIdx.x < 32) w2l[threadIdx.x] = w2f[threadIdx.x];
    if (threadIdx.x < 4)  b2l[threadIdx.x] = b2f[threadIdx.x];
    __syncthreads();
    int lane = threadIdx.x & 15;
    int gid0 = (blockIdx.x * 256 + threadIdx.x) >> 4;
    int gstride = (gridDim.x * 256) >> 4;
    for (int i = gid0; i < n; i += gstride) {
        uint32 e0 = nodeoff[i], e1 = nodeoff[i + 1];
        vf4 ziA = ziS[2 * (size_t)i], ziB = ziS[2 * (size_t)i + 1];
        float a0 = 0.f, a1 = 0.f, a2 = 0.f, a3 = 0.f;
        for (uint32 e = e0 + lane; e < e1; e += 16) {
            int s = src2[e];
            vf4 zjA = zjS[2 * (size_t)s], zjB = zjS[2 * (size_t)s + 1];
            if (s != i) {    // self-loop <=> h_i == h_j for random-normal inputs
                float m1[8], z2[4];
                m1_of(ziA, ziB, zjA, zjB, m1);
                mat8x4(m1, w2l, b2l, z2);
                a0 += ftanh(z2[0]);
                a1 += ftanh(z2[1]);
                a2 += ftanh(z2[2]);
                a3 += ftanh(z2[3]);
            }
        }
#pragma unroll
        for (int off = 8; off > 0; off >>= 1) {
            a0 += __shfl_down(a0, off, 16);
            a1 += __shfl_down(a1, off, 16);
            a2 += __shfl_down(a2, off, 16);
            a3 += __shfl_down(a3, off, 16);
        }
        if (lane == 0) {
            float* ap = acc + 8 * (size_t)i;
            ap[0] = a0; ap[1] = a1; ap[2] = a2; ap[3] = a3;
            ap[4] = (float)(e1 - e0);
        }
    }
}

// ---------------- fallback edge kernels (round-1 style, used if ws too small) ----------------
__global__ __launch_bounds__(256) void fb_stats1(const int* __restrict__ idx, const float4* __restrict__ h,
                                                 const float* __restrict__ w1, const float* __restrict__ b1,
                                                 float* __restrict__ sums, float* __restrict__ acc, int E_) {
    float a[16];
#pragma unroll
    for (int i = 0; i < 16; ++i) a[i] = 0.f;
    int stride = gridDim.x * blockDim.x;
    for (int e = blockIdx.x * blockDim.x + threadIdx.x; e < E_; e += stride) {
        int s = __builtin_nontemporal_load(idx + e);
        int d = __builtin_nontemporal_load(idx + E_ + e);
        float4 hi = h[d], hj = h[s];
        stats1_edge(hi, hj, w1, b1, a);
        atomicAdd(acc + 8 * (size_t)d + 4, 1.0f);
    }
    block_reduce_atomics<16>(a, sums);
}

__global__ __launch_bounds__(256) void fb_stats2(const int* __restrict__ idx, const float4* __restrict__ h,
                                                 const float* __restrict__ w1, const float* __restrict__ b1,
                                                 const float* __restrict__ ss1,
                                                 const float* __restrict__ w2, const float* __restrict__ b2,
                                                 float* __restrict__ sums2, int E_) {
    float a[8];
#pragma unroll
    for (int i = 0; i < 8; ++i) a[i] = 0.f;
    int stride = gridDim.x * blockDim.x;
    for (int e = blockIdx.x * blockDim.x + threadIdx.x; e < E_; e += stride) {
        int s = __builtin_nontemporal_load(idx + e);
        int d = __builtin_nontemporal_load(idx + E_ + e);
        float4 hi = h[d], hj = h[s];
        stats2_edge(hi, hj, w1, b1, ss1, w2, b2, a);
    }
    block_reduce_atomics<8>(a, sums2);
}

__global__ __launch_bounds__(256) void fb_scatter(const int* __restrict__ idx, const float4* __restrict__ h,
                                                  const float* __restrict__ w1, const float* __restrict__ b1,
                                                  const float* __restrict__ ss1,
                                                  const float* __restrict__ w2, const float* __restrict__ b2,
                                                  const float* __restrict__ ss2,
                                                  float* __restrict__ acc, int E_) {
    int stride = gridDim.x * blockDim.x;
    for (int e = blockIdx.x * blockDim.x + threadIdx.x; e < E_; e += stride) {
        int s = __builtin_nontemporal_load(idx + e);
        int d = __builtin_nontemporal_load(idx + E_ + e);
        float4 hi = h[d], hj = h[s];
        bool zero = (hi.x == hj.x) && (hi.y == hj.y) && (hi.z == hj.z) && (hi.w == hj.w);
        if (zero) continue;
        vf4 q = z2_edge(hi, hj, w1, b1, ss1, w2, b2);
        float m0 = ftanh(q.x * ss2[0] + ss2[4]);
        float m1v = ftanh(q.y * ss2[1] + ss2[5]);
        float m2v = ftanh(q.z * ss2[2] + ss2[6]);
        float m3 = ftanh(q.w * ss2[3] + ss2[7]);
        float* ap = acc + 8 * (size_t)d;
        atomicAdd(ap + 0, m0);
        atomicAdd(ap + 1, m1v);
        atomicAdd(ap + 2, m2v);
        atomicAdd(ap + 3, m3);
    }
}

// ---------------- node update MLP ----------------
__device__ __forceinline__ void load_u(int i, const float4* __restrict__ h,
                                       const float* __restrict__ acc, float* u) {
    float4 hv = h[i];
    const float* ap = acc + 8 * (size_t)i;
    float c = fmaxf(ap[4], 1.0f);
    u[0] = hv.x; u[1] = hv.y; u[2] = hv.z; u[3] = hv.w;
    u[4] = ap[0]; u[5] = ap[1]; u[6] = ap[2] / c; u[7] = ap[3] / c;
}

__global__ __launch_bounds__(256) void n_stats1(const float4* __restrict__ h,
                                                const float* __restrict__ acc,
                                                const float* __restrict__ w, const float* __restrict__ b,
                                                float* __restrict__ sums, int n) {
    float a[16];
#pragma unroll
    for (int i = 0; i < 16; ++i) a[i] = 0.f;
    int stride = gridDim.x * blockDim.x;
    for (int i = blockIdx.x * blockDim.x + threadIdx.x; i < n; i += stride) {
        float u[8], z[8];
        load_u(i, h, acc, u);
        mat8x8(u, w, b, z);
#pragma unroll
        for (int j = 0; j < 8; ++j) { a[j] += z[j]; a[8 + j] += z[j] * z[j]; }
    }
    block_reduce_atomics<16>(a, sums);
}

__global__ __launch_bounds__(256) void n_stats2(const float4* __restrict__ h,
                                                const float* __restrict__ acc,
                                                const float* __restrict__ w1, const float* __restrict__ b1,
                                                const float* __restrict__ sums3,
                                                const float* __restrict__ g3, const float* __restrict__ be3,
                                                float invN,
                                                const float* __restrict__ w2, const float* __restrict__ b2,
                                                float* __restrict__ sums, int n) {
    __shared__ float ss3[16];
    fin_lds(sums3, g3, be3, 8, invN, ss3);
    float a[8];
#pragma unroll
    for (int i = 0; i < 8; ++i) a[i] = 0.f;
    int stride = gridDim.x * blockDim.x;
    for (int i = blockIdx.x * blockDim.x + threadIdx.x; i < n; i += stride) {
        float u[8], z[8], u1[8], z4[4];
        load_u(i, h, acc, u);
        mat8x8(u, w1, b1, z);
#pragma unroll
        for (int j = 0; j < 8; ++j) u1[j] = ftanh(z[j] * ss3[j] + ss3[8 + j]);
        mat8x4(u1, w2, b2, z4);
#pragma unroll
        for (int c = 0; c < 4; ++c) { a[c] += z4[c]; a[4 + c] += z4[c] * z4[c]; }
    }
    block_reduce_atomics<8>(a, sums);
}

__global__ __launch_bounds__(256) void n_final(const float4* __restrict__ h,
                                               const float* __restrict__ acc,
                                               const float* __restrict__ w1, const float* __restrict__ b1,
                                               const float* __restrict__ sums3,
                                               const float* __restrict__ g3, const float* __restrict__ be3,
                                               const float* __restrict__ sums4,
                                               const float* __restrict__ g4, const float* __restrict__ be4,
                                               float invN,
                                               const float* __restrict__ w2, const float* __restrict__ b2,
                                               const float* __restrict__ pw, const float* __restrict__ pb,
                                               float2* __restrict__ out, int n) {
    __shared__ float ss3[16];
    __shared__ float ss4[8];
    fin_lds(sums3, g3, be3, 8, invN, ss3);
    fin_lds(sums4, g4, be4, 4, invN, ss4);
    int stride = gridDim.x * blockDim.x;
    for (int i = blockIdx.x * blockDim.x + threadIdx.x; i < n; i += stride) {
        float u[8], z[8], u1[8], z4[4], u2[4];
        load_u(i, h, acc, u);
        mat8x8(u, w1, b1, z);
#pragma unroll
        for (int j = 0; j < 8; ++j) u1[j] = ftanh(z[j] * ss3[j] + ss3[8 + j]);
        mat8x4(u1, w2, b2, z4);
#pragma unroll
        for (int c = 0; c < 4; ++c) u2[c] = ftanh(z4[c] * ss4[c] + ss4[4 + c]);
        float o0 = pb[0] + u2[0] * pw[0] + u2[1] * pw[2] + u2[2] * pw[4] + u2[3] * pw[6];
        float o1 = pb[1] + u2[0] * pw[1] + u2[1] * pw[3] + u2[2] * pw[5] + u2[3] * pw[7];
        out[i] = make_float2(o0, o1);
    }
}

extern "C" void kernel_launch(void* const* d_in, const int* in_sizes, int n_in,
                              void* d_out, int out_size, void* d_ws, size_t ws_size,
                              hipStream_t stream) {
    const float* pos  = (const float*)d_in[0];
    const float* vel  = (const float*)d_in[1];
    const int*   eidx = (const int*)d_in[2];
    const float* lin_w = (const float*)d_in[3];
    const float* lin_b = (const float*)d_in[4];
    const float* mw1 = (const float*)d_in[5];
    const float* mb1 = (const float*)d_in[6];
    const float* mg1 = (const float*)d_in[7];
    const float* mbe1 = (const float*)d_in[8];
    const float* mw2 = (const float*)d_in[9];
    const float* mb2 = (const float*)d_in[10];
    const float* mg2 = (const float*)d_in[11];
    const float* mbe2 = (const float*)d_in[12];
    const float* uw1 = (const float*)d_in[13];
    const float* ub1 = (const float*)d_in[14];
    const float* ug1 = (const float*)d_in[15];
    const float* ube1 = (const float*)d_in[16];
    const float* uw2 = (const float*)d_in[17];
    const float* ub2 = (const float*)d_in[18];
    const float* ug2 = (const float*)d_in[19];
    const float* ube2 = (const float*)d_in[20];
    const float* pw = (const float*)d_in[21];
    const float* pb = (const float*)d_in[22];

    int n  = in_sizes[0] / 2;
    int E_ = in_sizes[2] / 2;
    float invE = 1.0f / (float)E_;
    float invN = 1.0f / (float)n;

    // ---- workspace layout (bump allocator, 16B aligned) ----
    char* base = (char*)d_ws;
    size_t off = 0;
    auto alloc = [&](size_t bytes) {
        off = (off + 15) & ~(size_t)15;
        void* p = base + off;
        off += bytes;
        return p;
    };
    float4* h       = (float4*)alloc(16 * (size_t)n);                // 4 MB
    float*  acc     = (float*)alloc(32 * (size_t)n);                 // 8 MB
    float*  sums    = (float*)alloc(512);
    float*  ss      = sums + 64;
    float*  w2fb    = (float*)alloc(256);                            // folded w2 (32) + b2 (4)
    uint32* bbase   = (uint32*)alloc(4 * (NB + 1));
    uint32* rowtot  = (uint32*)alloc(4 * NB);
    uint32* cntmat  = (uint32*)alloc(4 * (size_t)NB * GB);           // 0.5 MB
    uint32* nodeoff = (uint32*)alloc(4 * ((size_t)n + 1));           // 1 MB
    vf4*    ziS     = (vf4*)alloc(32 * (size_t)n);                   // 8 MB
    vf4*    zjS     = (vf4*)alloc(32 * (size_t)n);                   // 8 MB
    int*    src2    = (int*)alloc(4 * (size_t)E_);                   // 32 MB
    vi2*    sp      = (vi2*)alloc(8 * (size_t)E_);                   // 64 MB
    size_t need_sort = off;                                           // ~126 MB

    bool big = ws_size >= need_sort;

    int nblk = (n + 255) / 256;
    int nbuckets = (n + 511) >> 9;
    int T = (E_ + GB - 1) / GB;

    k_h<<<nblk, 256, 0, stream>>>(pos, vel, lin_w, lin_b, h, n);

    if (big) {
        (void)hipMemsetAsync(sums, 0, 256, stream);

        k_zt<<<nblk, 256, 0, stream>>>(h, mw1, mb1, ziS, zjS, n);

        // fused histogram + z1 stats (gather-only)
        k_cnt<<<GB, 256, 0, stream>>>(eidx, h, mw1, mb1, cntmat, sums, E_, T);
        k_scanA<<<NB, 256, 0, stream>>>(cntmat, rowtot);
        k_scanB<<<1, 256, 0, stream>>>(rowtot, bbase);

        // fold BN1 into z-tables
        k_fold<<<nblk, 256, 0, stream>>>(ziS, zjS, sums, mg1, mbe1, invE, n);

        k_reorder<<<GB, 256, 0, stream>>>(eidx, cntmat, bbase, sp, E_, T);
        k_sort2<<<nbuckets, 256, CAP * 4, stream>>>(sp, bbase, rowtot, src2, nodeoff, n);

        e_pass2<<<2048, 256, 0, stream>>>(sp, ziS, zjS, mw2, mb2, sums + 16, E_);

        k_foldw<<<1, 64, 0, stream>>>(sums + 16, mg2, mbe2, invE, mw2, mb2, w2fb, w2fb + 32);

        e_aggr_csr<<<4096, 256, 0, stream>>>(src2, nodeoff, ziS, zjS, w2fb, w2fb + 32, acc, n);

        n_stats1<<<nblk, 256, 0, stream>>>(h, acc, uw1, ub1, sums + 24, n);
        n_stats2<<<nblk, 256, 0, stream>>>(h, acc, uw1, ub1, sums + 24, ug1, ube1, invN,
                                           uw2, ub2, sums + 40, n);
        n_final<<<nblk, 256, 0, stream>>>(h, acc, uw1, ub1, sums + 24, ug1, ube1,
                                          sums + 40, ug2, ube2, invN,
                                          uw2, ub2, pw, pb, (float2*)d_out, n);
    } else {
        (void)hipMemsetAsync(acc, 0, 32 * (size_t)n + 256, stream);

        fb_stats1<<<4096, 256, 0, stream>>>(eidx, h, mw1, mb1, sums, acc, E_);
        k_fin<<<1, 64, 0, stream>>>(sums, ss, mg1, mbe1, 8, invE);

        fb_stats2<<<4096, 256, 0, stream>>>(eidx, h, mw1, mb1, ss, mw2, mb2, sums + 16, E_);
        k_fin<<<1, 64, 0, stream>>>(sums + 16, ss + 16, mg2, mbe2, 4, invE);

        fb_scatter<<<4096, 256, 0, stream>>>(eidx, h, mw1, mb1, ss, mw2, mb2, ss + 16, acc, E_);

        n_stats1<<<nblk, 256, 0, stream>>>(h, acc, uw1, ub1, sums + 24, n);
        n_stats2<<<nblk, 256, 0, stream>>>(h, acc, uw1, ub1, sums + 24, ug1, ube1, invN,
                                           uw2, ub2, sums + 40, n);
        n_final<<<nblk, 256, 0, stream>>>(h, acc, uw1, ub1, sums + 24, ug1, ube1,
                                          sums + 40, ug2, ube2, invN,
                                          uw2, ub2, pw, pb, (float2*)d_out, n);
    }
}

// Round 21
// 533.657 us; speedup vs baseline: 1.0939x; 1.0400x over previous
//
#include <hip/hip_runtime.h>

#define EPSBN 1e-5f
#define NB 512            // buckets (dst >> 9), 512 nodes per bucket
#define GB 256            // blocks for cnt/reorder tiles
#define CAP 18000         // LDS sort buffer capacity (edges); mean ~16360 + 13 sigma

typedef float vf4 __attribute__((ext_vector_type(4)));
typedef int   vi2 __attribute__((ext_vector_type(2)));
typedef unsigned int uint32;
typedef uint32 vu4 __attribute__((ext_vector_type(4)));

__device__ __forceinline__ float ftanh(float x) {
    return 1.0f - 2.0f / (__expf(2.0f * x) + 1.0f);
}

__device__ __forceinline__ float wave_sum(float v) {
#pragma unroll
    for (int off = 32; off > 0; off >>= 1) v += __shfl_down(v, off);
    return v;
}

__device__ __forceinline__ void z1_of(const float4 hi, const float4 hj,
                                      const float* __restrict__ w, const float* __restrict__ b,
                                      float* z) {
#pragma unroll
    for (int j = 0; j < 8; ++j) {
        z[j] = b[j]
             + hi.x * w[0 * 8 + j] + hi.y * w[1 * 8 + j] + hi.z * w[2 * 8 + j] + hi.w * w[3 * 8 + j]
             + hj.x * w[4 * 8 + j] + hj.y * w[5 * 8 + j] + hj.z * w[6 * 8 + j] + hj.w * w[7 * 8 + j];
    }
}

__device__ __forceinline__ void mat8x4(const float* u, const float* w,
                                       const float* b, float* z) {
#pragma unroll
    for (int c = 0; c < 4; ++c) {
        float t = b[c];
#pragma unroll
        for (int k = 0; k < 8; ++k) t += u[k] * w[k * 4 + c];
        z[c] = t;
    }
}

__device__ __forceinline__ void mat8x8(const float* u, const float* __restrict__ w,
                                       const float* __restrict__ b, float* z) {
#pragma unroll
    for (int j = 0; j < 8; ++j) {
        float t = b[j];
#pragma unroll
        for (int k = 0; k < 8; ++k) t += u[k] * w[k * 8 + j];
        z[j] = t;
    }
}

template <int NV>
__device__ __forceinline__ void block_reduce_atomics(float* a, float* __restrict__ sums) {
    __shared__ float red[NV * 4];
    int wid = threadIdx.x >> 6, lane = threadIdx.x & 63;
#pragma unroll
    for (int i = 0; i < NV; ++i) {
        float v = wave_sum(a[i]);
        if (lane == 0) red[i * 4 + wid] = v;
    }
    __syncthreads();
    if (threadIdx.x < NV) {
        float v = red[threadIdx.x * 4 + 0] + red[threadIdx.x * 4 + 1]
                + red[threadIdx.x * 4 + 2] + red[threadIdx.x * 4 + 3];
        atomicAdd(&sums[threadIdx.x], v);
    }
}

// compute BN scale/shift into LDS from raw sums (all threads; syncs inside)
__device__ __forceinline__ void fin_lds(const float* __restrict__ sums,
                                        const float* __restrict__ g, const float* __restrict__ be,
                                        int d, float inv, float* out) {
    int j = threadIdx.x;
    if (j < d) {
        float mu = sums[j] * inv;
        float var = sums[d + j] * inv - mu * mu;
        float s = g[j] * rsqrtf(var + EPSBN);
        out[j] = s;
        out[d + j] = be[j] - mu * s;
    }
    __syncthreads();
}

// per-edge z1-stats accumulate (h-based; fused k_cnt + fallback)
__device__ __forceinline__ void stats1_edge(float4 hi, float4 hj,
                                            const float* __restrict__ w1, const float* __restrict__ b1,
                                            float* a) {
    float z[8];
    z1_of(hi, hj, w1, b1, z);
#pragma unroll
    for (int j = 0; j < 8; ++j) { a[j] += z[j]; a[8 + j] += z[j] * z[j]; }
}

// h-based z2 (fallback path only)
__device__ __forceinline__ vf4 z2_edge(float4 hi, float4 hj,
                                       const float* __restrict__ w1, const float* __restrict__ b1,
                                       const float* ss1,
                                       const float* __restrict__ w2, const float* __restrict__ b2) {
    float z[8], m1[8], z2[4];
    z1_of(hi, hj, w1, b1, z);
#pragma unroll
    for (int j = 0; j < 8; ++j) m1[j] = ftanh(z[j] * ss1[j] + ss1[8 + j]);
    mat8x4(m1, w2, b2, z2);
    vf4 r = {z2[0], z2[1], z2[2], z2[3]};
    return r;
}

__device__ __forceinline__ void stats2_edge(float4 hi, float4 hj,
                                            const float* __restrict__ w1, const float* __restrict__ b1,
                                            const float* ss1,
                                            const float* __restrict__ w2, const float* __restrict__ b2,
                                            float* a) {
    vf4 q = z2_edge(hi, hj, w1, b1, ss1, w2, b2);
    a[0] += q.x; a[4] += q.x * q.x;
    a[1] += q.y; a[5] += q.y * q.y;
    a[2] += q.z; a[6] += q.z * q.z;
    a[3] += q.w; a[7] += q.w * q.w;
}

// table-based m1 (BN1 pre-folded into tables)
__device__ __forceinline__ void m1_of(vf4 ziA, vf4 ziB, vf4 zjA, vf4 zjB, float* m1) {
    m1[0] = ftanh(ziA.x + zjA.x); m1[1] = ftanh(ziA.y + zjA.y);
    m1[2] = ftanh(ziA.z + zjA.z); m1[3] = ftanh(ziA.w + zjA.w);
    m1[4] = ftanh(ziB.x + zjB.x); m1[5] = ftanh(ziB.y + zjB.y);
    m1[6] = ftanh(ziB.z + zjB.z); m1[7] = ftanh(ziB.w + zjB.w);
}

// ---------------- node input projection ----------------
__global__ __launch_bounds__(256) void k_h(const float* __restrict__ pos, const float* __restrict__ vel,
                                           const float* __restrict__ w, const float* __restrict__ b,
                                           float4* __restrict__ h, int n) {
    int i = blockIdx.x * blockDim.x + threadIdx.x;
    if (i >= n) return;
    float2 p = ((const float2*)pos)[i];
    float2 v = ((const float2*)vel)[i];
    float o[4];
#pragma unroll
    for (int d = 0; d < 4; ++d)
        o[d] = b[d] + p.x * w[0 * 4 + d] + p.y * w[1 * 4 + d] + v.x * w[2 * 4 + d] + v.y * w[3 * 4 + d];
    h[i] = make_float4(o[0], o[1], o[2], o[3]);
}

// ---------------- z-tables: zi_raw = Wi^T h, zj_raw = Wj^T h + b1 ----------------
__global__ __launch_bounds__(256) void k_zt(const float4* __restrict__ h,
                                            const float* __restrict__ w1, const float* __restrict__ b1,
                                            vf4* __restrict__ zi, vf4* __restrict__ zj, int n) {
    int i = blockIdx.x * blockDim.x + threadIdx.x;
    if (i >= n) return;
    float4 hv = h[i];
    float zi8[8], zj8[8];
#pragma unroll
    for (int j = 0; j < 8; ++j) {
        zi8[j] = hv.x * w1[0 * 8 + j] + hv.y * w1[1 * 8 + j] + hv.z * w1[2 * 8 + j] + hv.w * w1[3 * 8 + j];
        zj8[j] = b1[j]
               + hv.x * w1[4 * 8 + j] + hv.y * w1[5 * 8 + j] + hv.z * w1[6 * 8 + j] + hv.w * w1[7 * 8 + j];
    }
    vf4 a = {zi8[0], zi8[1], zi8[2], zi8[3]};
    vf4 b_ = {zi8[4], zi8[5], zi8[6], zi8[7]};
    vf4 c = {zj8[0], zj8[1], zj8[2], zj8[3]};
    vf4 d = {zj8[4], zj8[5], zj8[6], zj8[7]};
    zi[2 * (size_t)i] = a; zi[2 * (size_t)i + 1] = b_;
    zj[2 * (size_t)i] = c; zj[2 * (size_t)i + 1] = d;
}

// ---------------- fold BN1 into z-tables ----------------
__global__ __launch_bounds__(256) void k_fold(vf4* __restrict__ zi, vf4* __restrict__ zj,
                                              const float* __restrict__ sums1,
                                              const float* __restrict__ g1, const float* __restrict__ be1,
                                              float invE, int n) {
    __shared__ float ss1[16];
    fin_lds(sums1, g1, be1, 8, invE, ss1);
    int i = blockIdx.x * blockDim.x + threadIdx.x;
    if (i >= n) return;
    vf4 a = zi[2 * (size_t)i], b = zi[2 * (size_t)i + 1];
    a.x *= ss1[0]; a.y *= ss1[1]; a.z *= ss1[2]; a.w *= ss1[3];
    b.x *= ss1[4]; b.y *= ss1[5]; b.z *= ss1[6]; b.w *= ss1[7];
    zi[2 * (size_t)i] = a; zi[2 * (size_t)i + 1] = b;
    vf4 c = zj[2 * (size_t)i], d = zj[2 * (size_t)i + 1];
    c.x = c.x * ss1[0] + ss1[8];  c.y = c.y * ss1[1] + ss1[9];
    c.z = c.z * ss1[2] + ss1[10]; c.w = c.w * ss1[3] + ss1[11];
    d.x = d.x * ss1[4] + ss1[12]; d.y = d.y * ss1[5] + ss1[13];
    d.z = d.z * ss1[6] + ss1[14]; d.w = d.w * ss1[7] + ss1[15];
    zj[2 * (size_t)i] = c; zj[2 * (size_t)i + 1] = d;
}

// ---------------- fold BN2 into w2/b2 ----------------
__global__ void k_foldw(const float* __restrict__ sums2,
                        const float* __restrict__ g2, const float* __restrict__ be2, float invE,
                        const float* __restrict__ w2, const float* __restrict__ b2,
                        float* __restrict__ w2f, float* __restrict__ b2f) {
    __shared__ float ss2[8];
    int j = threadIdx.x;
    if (j < 4) {
        float mu = sums2[j] * invE;
        float var = sums2[4 + j] * invE - mu * mu;
        float s = g2[j] * rsqrtf(var + EPSBN);
        ss2[j] = s;
        ss2[4 + j] = be2[j] - mu * s;
    }
    __syncthreads();
    if (j < 32) w2f[j] = w2[j] * ss2[j & 3];
    if (j < 4)  b2f[j] = b2[j] * ss2[j] + ss2[4 + j];
}

// ---------------- count + fused z1 stats (h-based gathers; no scatter) ----------------
__global__ __launch_bounds__(256, 2) void k_cnt(const int* __restrict__ idx, const float4* __restrict__ h,
                                                const float* __restrict__ w1, const float* __restrict__ b1,
                                                uint32* __restrict__ cntmat, float* __restrict__ sums,
                                                int E_, int T) {
    __shared__ uint32 hist[NB];
    for (int b = threadIdx.x; b < NB; b += 256) hist[b] = 0;
    float a[16];
#pragma unroll
    for (int i = 0; i < 16; ++i) a[i] = 0.f;
    __syncthreads();
    int lo = blockIdx.x * T, hi2 = min(E_, lo + T);
    for (int e0 = lo + 4 * threadIdx.x; e0 < hi2; e0 += 1024) {
        int m = min(4, hi2 - e0);
        if (m == 4) {
            int s0 = __builtin_nontemporal_load(idx + e0);
            int s1 = __builtin_nontemporal_load(idx + e0 + 1);
            int s2 = __builtin_nontemporal_load(idx + e0 + 2);
            int s3 = __builtin_nontemporal_load(idx + e0 + 3);
            int d0 = __builtin_nontemporal_load(idx + E_ + e0);
            int d1 = __builtin_nontemporal_load(idx + E_ + e0 + 1);
            int d2 = __builtin_nontemporal_load(idx + E_ + e0 + 2);
            int d3 = __builtin_nontemporal_load(idx + E_ + e0 + 3);
            float4 hi0 = h[d0], hj0 = h[s0];
            float4 hi1 = h[d1], hj1 = h[s1];
            float4 hi2 = h[d2], hj2 = h[s2];
            float4 hi3 = h[d3], hj3 = h[s3];
            atomicAdd(&hist[d0 >> 9], 1u);
            atomicAdd(&hist[d1 >> 9], 1u);
            atomicAdd(&hist[d2 >> 9], 1u);
            atomicAdd(&hist[d3 >> 9], 1u);
            stats1_edge(hi0, hj0, w1, b1, a);
            stats1_edge(hi1, hj1, w1, b1, a);
            stats1_edge(hi2, hj2, w1, b1, a);
            stats1_edge(hi3, hj3, w1, b1, a);
        } else {
            for (int k = 0; k < m; ++k) {
                int s = __builtin_nontemporal_load(idx + e0 + k);
                int d = __builtin_nontemporal_load(idx + E_ + e0 + k);
                float4 hi = h[d], hj = h[s];
                atomicAdd(&hist[d >> 9], 1u);
                stats1_edge(hi, hj, w1, b1, a);
            }
        }
    }
    __syncthreads();
    for (int b = threadIdx.x; b < NB; b += 256)
        cntmat[(size_t)b * GB + blockIdx.x] = hist[b];
    block_reduce_atomics<16>(a, sums);
}

// block-scan of 256 uints (1/thread), exclusive
__device__ __forceinline__ void scan256(uint32 v, uint32* excl_out, uint32* total) {
    __shared__ uint32 ts[256];
    ts[threadIdx.x] = v;
    __syncthreads();
    for (int off = 1; off < 256; off <<= 1) {
        uint32 t = (threadIdx.x >= (uint32)off) ? ts[threadIdx.x - off] : 0u;
        __syncthreads();
        ts[threadIdx.x] += t;
        __syncthreads();
    }
    *excl_out = ts[threadIdx.x] - v;
    *total = ts[255];
}

// block-scan of 512 uints (2/thread), exclusive
__device__ __forceinline__ void scan512(uint32* v, uint32* excl_out, uint32* total) {
    __shared__ uint32 ts[256];
    uint32 local = v[0] + v[1];
    ts[threadIdx.x] = local;
    __syncthreads();
    for (int off = 1; off < 256; off <<= 1) {
        uint32 t = (threadIdx.x >= (uint32)off) ? ts[threadIdx.x - off] : 0u;
        __syncthreads();
        ts[threadIdx.x] += t;
        __syncthreads();
    }
    *excl_out = ts[threadIdx.x] - local;
    *total = ts[255];
}

__global__ __launch_bounds__(256) void k_scanA(uint32* __restrict__ cntmat, uint32* __restrict__ rowtot) {
    size_t base = (size_t)blockIdx.x * GB + threadIdx.x;
    uint32 v = cntmat[base];
    uint32 excl, tot;
    scan256(v, &excl, &tot);
    cntmat[base] = excl;
    if (threadIdx.x == 0) rowtot[blockIdx.x] = tot;
}

__global__ __launch_bounds__(256) void k_scanB(const uint32* __restrict__ rowtot, uint32* __restrict__ bbase) {
    uint32 v[2];
    v[0] = rowtot[threadIdx.x * 2]; v[1] = rowtot[threadIdx.x * 2 + 1];
    uint32 excl, tot;
    scan512(v, &excl, &tot);
    bbase[threadIdx.x * 2] = excl;
    bbase[threadIdx.x * 2 + 1] = excl + v[0];
    if (threadIdx.x == 0) bbase[NB] = tot;
}

// ---------------- reorder: packed 4B scatter ((dst&511)<<23 | src) ----------------
__global__ __launch_bounds__(256) void k_reorder(const int* __restrict__ idx,
                                                 const uint32* __restrict__ cntmat, const uint32* __restrict__ bbase,
                                                 uint32* __restrict__ sp, int E_, int T) {
    __shared__ uint32 cur[NB];
    for (int b = threadIdx.x; b < NB; b += 256)
        cur[b] = bbase[b] + cntmat[(size_t)b * GB + blockIdx.x];
    __syncthreads();
    int lo = blockIdx.x * T, hi2 = min(E_, lo + T);
    for (int e0 = lo + 4 * threadIdx.x; e0 < hi2; e0 += 1024) {
        int m = min(4, hi2 - e0);
        if (m == 4) {
            int s0 = __builtin_nontemporal_load(idx + e0);
            int s1 = __builtin_nontemporal_load(idx + e0 + 1);
            int s2 = __builtin_nontemporal_load(idx + e0 + 2);
            int s3 = __builtin_nontemporal_load(idx + e0 + 3);
            int d0 = __builtin_nontemporal_load(idx + E_ + e0);
            int d1 = __builtin_nontemporal_load(idx + E_ + e0 + 1);
            int d2 = __builtin_nontemporal_load(idx + E_ + e0 + 2);
            int d3 = __builtin_nontemporal_load(idx + E_ + e0 + 3);
            uint32 p0 = atomicAdd(&cur[d0 >> 9], 1u);
            uint32 p1 = atomicAdd(&cur[d1 >> 9], 1u);
            uint32 p2 = atomicAdd(&cur[d2 >> 9], 1u);
            uint32 p3 = atomicAdd(&cur[d3 >> 9], 1u);
            sp[p0] = ((uint32)(d0 & 511) << 23) | (uint32)s0;
            sp[p1] = ((uint32)(d1 & 511) << 23) | (uint32)s1;
            sp[p2] = ((uint32)(d2 & 511) << 23) | (uint32)s2;
            sp[p3] = ((uint32)(d3 & 511) << 23) | (uint32)s3;
        } else {
            for (int k = 0; k < m; ++k) {
                int s = __builtin_nontemporal_load(idx + e0 + k);
                int d = __builtin_nontemporal_load(idx + E_ + e0 + k);
                uint32 pos = atomicAdd(&cur[d >> 9], 1u);
                sp[pos] = ((uint32)(d & 511) << 23) | (uint32)s;
            }
        }
    }
}

// ---------------- sort2: per-bucket counting sort staged in LDS -> CSR ----------------
__global__ __launch_bounds__(256) void k_sort2(const uint32* __restrict__ sp,
                                               const uint32* __restrict__ bbase, const uint32* __restrict__ rowtot,
                                               int* __restrict__ src2, uint32* __restrict__ nodeoff, int n) {
    extern __shared__ uint32 buf[];      // CAP entries (72 KB)
    __shared__ uint32 hist[512];
    __shared__ uint32 cur[512];
    int b = blockIdx.x;
    uint32 start = bbase[b];
    uint32 len = rowtot[b];
    uint32 end = start + len;
    hist[threadIdx.x] = 0;
    hist[threadIdx.x + 256] = 0;
    __syncthreads();
    for (uint32 e = start + threadIdx.x; e < end; e += 256) {
        uint32 pk = __builtin_nontemporal_load(&sp[e]);
        atomicAdd(&hist[pk >> 23], 1u);
    }
    __syncthreads();
    uint32 vv[2];
    vv[0] = hist[2 * threadIdx.x];
    vv[1] = hist[2 * threadIdx.x + 1];
    uint32 excl, tot;
    scan512(vv, &excl, &tot);
    cur[2 * threadIdx.x] = excl;
    cur[2 * threadIdx.x + 1] = excl + vv[0];
    int nodebase = b << 9;
    int node0 = nodebase + 2 * threadIdx.x;
    if (node0 <= n)     nodeoff[node0] = start + excl;
    if (node0 + 1 <= n) nodeoff[node0 + 1] = start + excl + vv[0];
    __syncthreads();
    for (uint32 e = start + threadIdx.x; e < end; e += 256) {
        uint32 pk = __builtin_nontemporal_load(&sp[e]);
        uint32 pos = atomicAdd(&cur[pk >> 23], 1u);
        uint32 src = pk & 0x7FFFFFu;
        if (pos < (uint32)CAP) buf[pos] = src;
        else src2[start + pos] = (int)src;
    }
    __syncthreads();
    uint32 lim = min(len, (uint32)CAP);
    for (uint32 k = threadIdx.x; k < lim; k += 256)
        src2[start + k] = (int)buf[k];
}

// ---------------- finalize BN stats (fallback path only) ----------------
__global__ void k_fin(const float* __restrict__ sums, float* __restrict__ ss,
                      const float* __restrict__ g, const float* __restrict__ be,
                      int d, float inv_count) {
    int j = threadIdx.x;
    if (j >= d) return;
    float mu = sums[j] * inv_count;
    float var = sums[d + j] * inv_count - mu * mu;
    float s = g[j] * rsqrtf(var + EPSBN);
    ss[j] = s;
    ss[d + j] = be[j] - mu * s;
}

// ---------------- E2: z2 stats over CSR; zi loop-invariant; 16-lane groups ----------------
__global__ __launch_bounds__(256, 2) void e_pass2(const int* __restrict__ src2, const uint32* __restrict__ nodeoff,
                                                  const vf4* __restrict__ ziS, const vf4* __restrict__ zjS,
                                                  const float* __restrict__ w2, const float* __restrict__ b2,
                                                  float* __restrict__ sums2, int n) {
    __shared__ float w2l[32];
    __shared__ float b2l[4];
    if (threadIdx.x < 32) w2l[threadIdx.x] = w2[threadIdx.x];
    if (threadIdx.x < 4)  b2l[threadIdx.x] = b2[threadIdx.x];
    __syncthreads();
    float a[8];
#pragma unroll
    for (int i = 0; i < 8; ++i) a[i] = 0.f;
    int lane = threadIdx.x & 15;
    int gid0 = (blockIdx.x * 256 + threadIdx.x) >> 4;
    int gstride = (gridDim.x * 256) >> 4;
    for (int i = gid0; i < n; i += gstride) {
        uint32 e0 = nodeoff[i], e1 = nodeoff[i + 1];
        vf4 ziA = ziS[2 * (size_t)i], ziB = ziS[2 * (size_t)i + 1];
        for (uint32 e = e0 + lane; e < e1; e += 16) {
            int s = src2[e];
            vf4 zjA = zjS[2 * (size_t)s], zjB = zjS[2 * (size_t)s + 1];
            float m1[8], z2[4];
            m1_of(ziA, ziB, zjA, zjB, m1);
            mat8x4(m1, w2l, b2l, z2);
            a[0] += z2[0]; a[4] += z2[0] * z2[0];
            a[1] += z2[1]; a[5] += z2[1] * z2[1];
            a[2] += z2[2]; a[6] += z2[2] * z2[2];
            a[3] += z2[3]; a[7] += z2[3] * z2[3];
        }
    }
    block_reduce_atomics<8>(a, sums2);
}

// ---------------- aggregate over CSR: 16-lane group per node; folded BN2 ----------------
__global__ __launch_bounds__(256, 2) void e_aggr_csr(const int* __restrict__ src2, const uint32* __restrict__ nodeoff,
                                                     const vf4* __restrict__ ziS, const vf4* __restrict__ zjS,
                                                     const float* __restrict__ w2f, const float* __restrict__ b2f,
                                                     float* __restrict__ acc, int n) {
    __shared__ float w2l[32];
    __shared__ float b2l[4];
    if (threadIdx.x < 32) w2l[threadIdx.x] = w2f[threadIdx.x];
    if (threadIdx.x < 4)  b2l[threadIdx.x] = b2f[threadIdx.x];
    __syncthreads();
    int lane = threadIdx.x & 15;
    int gid0 = (blockIdx.x * 256 + threadIdx.x) >> 4;
    int gstride = (gridDim.x * 256) >> 4;
    for (int i = gid0; i < n; i += gstride) {
        uint32 e0 = nodeoff[i], e1 = nodeoff[i + 1];
        vf4 ziA = ziS[2 * (size_t)i], ziB = ziS[2 * (size_t)i + 1];
        float a0 = 0.f, a1 = 0.f, a2 = 0.f, a3 = 0.f;
        for (uint32 e = e0 + lane; e < e1; e += 16) {
            int s = src2[e];
            vf4 zjA = zjS[2 * (size_t)s], zjB = zjS[2 * (size_t)s + 1];
            if (s != i) {    // self-loop <=> h_i == h_j for random-normal inputs
                float m1[8], z2[4];
                m1_of(ziA, ziB, zjA, zjB, m1);
                mat8x4(m1, w2l, b2l, z2);
                a0 += ftanh(z2[0]);
                a1 += ftanh(z2[1]);
                a2 += ftanh(z2[2]);
                a3 += ftanh(z2[3]);
            }
        }
#pragma unroll
        for (int off = 8; off > 0; off >>= 1) {
            a0 += __shfl_down(a0, off, 16);
            a1 += __shfl_down(a1, off, 16);
            a2 += __shfl_down(a2, off, 16);
            a3 += __shfl_down(a3, off, 16);
        }
        if (lane == 0) {
            float* ap = acc + 8 * (size_t)i;
            ap[0] = a0; ap[1] = a1; ap[2] = a2; ap[3] = a3;
            ap[4] = (float)(e1 - e0);
        }
    }
}

// ---------------- fallback edge kernels (round-1 style, used if ws too small) ----------------
__global__ __launch_bounds__(256) void fb_stats1(const int* __restrict__ idx, const float4* __restrict__ h,
                                                 const float* __restrict__ w1, const float* __restrict__ b1,
                                                 float* __restrict__ sums, float* __restrict__ acc, int E_) {
    float a[16];
#pragma unroll
    for (int i = 0; i < 16; ++i) a[i] = 0.f;
    int stride = gridDim.x * blockDim.x;
    for (int e = blockIdx.x * blockDim.x + threadIdx.x; e < E_; e += stride) {
        int s = __builtin_nontemporal_load(idx + e);
        int d = __builtin_nontemporal_load(idx + E_ + e);
        float4 hi = h[d], hj = h[s];
        stats1_edge(hi, hj, w1, b1, a);
        atomicAdd(acc + 8 * (size_t)d + 4, 1.0f);
    }
    block_reduce_atomics<16>(a, sums);
}

__global__ __launch_bounds__(256) void fb_stats2(const int* __restrict__ idx, const float4* __restrict__ h,
                                                 const float* __restrict__ w1, const float* __restrict__ b1,
                                                 const float* __restrict__ ss1,
                                                 const float* __restrict__ w2, const float* __restrict__ b2,
                                                 float* __restrict__ sums2, int E_) {
    float a[8];
#pragma unroll
    for (int i = 0; i < 8; ++i) a[i] = 0.f;
    int stride = gridDim.x * blockDim.x;
    for (int e = blockIdx.x * blockDim.x + threadIdx.x; e < E_; e += stride) {
        int s = __builtin_nontemporal_load(idx + e);
        int d = __builtin_nontemporal_load(idx + E_ + e);
        float4 hi = h[d], hj = h[s];
        stats2_edge(hi, hj, w1, b1, ss1, w2, b2, a);
    }
    block_reduce_atomics<8>(a, sums2);
}

__global__ __launch_bounds__(256) void fb_scatter(const int* __restrict__ idx, const float4* __restrict__ h,
                                                  const float* __restrict__ w1, const float* __restrict__ b1,
                                                  const float* __restrict__ ss1,
                                                  const float* __restrict__ w2, const float* __restrict__ b2,
                                                  const float* __restrict__ ss2,
                                                  float* __restrict__ acc, int E_) {
    int stride = gridDim.x * blockDim.x;
    for (int e = blockIdx.x * blockDim.x + threadIdx.x; e < E_; e += stride) {
        int s = __builtin_nontemporal_load(idx + e);
        int d = __builtin_nontemporal_load(idx + E_ + e);
        float4 hi = h[d], hj = h[s];
        bool zero = (hi.x == hj.x) && (hi.y == hj.y) && (hi.z == hj.z) && (hi.w == hj.w);
        if (zero) continue;
        vf4 q = z2_edge(hi, hj, w1, b1, ss1, w2, b2);
        float m0 = ftanh(q.x * ss2[0] + ss2[4]);
        float m1v = ftanh(q.y * ss2[1] + ss2[5]);
        float m2v = ftanh(q.z * ss2[2] + ss2[6]);
        float m3 = ftanh(q.w * ss2[3] + ss2[7]);
        float* ap = acc + 8 * (size_t)d;
        atomicAdd(ap + 0, m0);
        atomicAdd(ap + 1, m1v);
        atomicAdd(ap + 2, m2v);
        atomicAdd(ap + 3, m3);
    }
}

// ---------------- node update MLP ----------------
__device__ __forceinline__ void load_u(int i, const float4* __restrict__ h,
                                       const float* __restrict__ acc, float* u) {
    float4 hv = h[i];
    const float* ap = acc + 8 * (size_t)i;
    float c = fmaxf(ap[4], 1.0f);
    u[0] = hv.x; u[1] = hv.y; u[2] = hv.z; u[3] = hv.w;
    u[4] = ap[0]; u[5] = ap[1]; u[6] = ap[2] / c; u[7] = ap[3] / c;
}

__global__ __launch_bounds__(256) void n_stats1(const float4* __restrict__ h,
                                                const float* __restrict__ acc,
                                                const float* __restrict__ w, const float* __restrict__ b,
                                                float* __restrict__ sums, int n) {
    float a[16];
#pragma unroll
    for (int i = 0; i < 16; ++i) a[i] = 0.f;
    int stride = gridDim.x * blockDim.x;
    for (int i = blockIdx.x * blockDim.x + threadIdx.x; i < n; i += stride) {
        float u[8], z[8];
        load_u(i, h, acc, u);
        mat8x8(u, w, b, z);
#pragma unroll
        for (int j = 0; j < 8; ++j) { a[j] += z[j]; a[8 + j] += z[j] * z[j]; }
    }
    block_reduce_atomics<16>(a, sums);
}

__global__ __launch_bounds__(256) void n_stats2(const float4* __restrict__ h,
                                                const float* __restrict__ acc,
                                                const float* __restrict__ w1, const float* __restrict__ b1,
                                                const float* __restrict__ sums3,
                                                const float* __restrict__ g3, const float* __restrict__ be3,
                                                float invN,
                                                const float* __restrict__ w2, const float* __restrict__ b2,
                                                float* __restrict__ sums, int n) {
    __shared__ float ss3[16];
    fin_lds(sums3, g3, be3, 8, invN, ss3);
    float a[8];
#pragma unroll
    for (int i = 0; i < 8; ++i) a[i] = 0.f;
    int stride = gridDim.x * blockDim.x;
    for (int i = blockIdx.x * blockDim.x + threadIdx.x; i < n; i += stride) {
        float u[8], z[8], u1[8], z4[4];
        load_u(i, h, acc, u);
        mat8x8(u, w1, b1, z);
#pragma unroll
        for (int j = 0; j < 8; ++j) u1[j] = ftanh(z[j] * ss3[j] + ss3[8 + j]);
        mat8x4(u1, w2, b2, z4);
#pragma unroll
        for (int c = 0; c < 4; ++c) { a[c] += z4[c]; a[4 + c] += z4[c] * z4[c]; }
    }
    block_reduce_atomics<8>(a, sums);
}

__global__ __launch_bounds__(256) void n_final(const float4* __restrict__ h,
                                               const float* __restrict__ acc,
                                               const float* __restrict__ w1, const float* __restrict__ b1,
                                               const float* __restrict__ sums3,
                                               const float* __restrict__ g3, const float* __restrict__ be3,
                                               const float* __restrict__ sums4,
                                               const float* __restrict__ g4, const float* __restrict__ be4,
                                               float invN,
                                               const float* __restrict__ w2, const float* __restrict__ b2,
                                               const float* __restrict__ pw, const float* __restrict__ pb,
                                               float2* __restrict__ out, int n) {
    __shared__ float ss3[16];
    __shared__ float ss4[8];
    fin_lds(sums3, g3, be3, 8, invN, ss3);
    fin_lds(sums4, g4, be4, 4, invN, ss4);
    int stride = gridDim.x * blockDim.x;
    for (int i = blockIdx.x * blockDim.x + threadIdx.x; i < n; i += stride) {
        float u[8], z[8], u1[8], z4[4], u2[4];
        load_u(i, h, acc, u);
        mat8x8(u, w1, b1, z);
#pragma unroll
        for (int j = 0; j < 8; ++j) u1[j] = ftanh(z[j] * ss3[j] + ss3[8 + j]);
        mat8x4(u1, w2, b2, z4);
#pragma unroll
        for (int c = 0; c < 4; ++c) u2[c] = ftanh(z4[c] * ss4[c] + ss4[4 + c]);
        float o0 = pb[0] + u2[0] * pw[0] + u2[1] * pw[2] + u2[2] * pw[4] + u2[3] * pw[6];
        float o1 = pb[1] + u2[0] * pw[1] + u2[1] * pw[3] + u2[2] * pw[5] + u2[3] * pw[7];
        out[i] = make_float2(o0, o1);
    }
}

extern "C" void kernel_launch(void* const* d_in, const int* in_sizes, int n_in,
                              void* d_out, int out_size, void* d_ws, size_t ws_size,
                              hipStream_t stream) {
    const float* pos  = (const float*)d_in[0];
    const float* vel  = (const float*)d_in[1];
    const int*   eidx = (const int*)d_in[2];
    const float* lin_w = (const float*)d_in[3];
    const float* lin_b = (const float*)d_in[4];
    const float* mw1 = (const float*)d_in[5];
    const float* mb1 = (const float*)d_in[6];
    const float* mg1 = (const float*)d_in[7];
    const float* mbe1 = (const float*)d_in[8];
    const float* mw2 = (const float*)d_in[9];
    const float* mb2 = (const float*)d_in[10];
    const float* mg2 = (const float*)d_in[11];
    const float* mbe2 = (const float*)d_in[12];
    const float* uw1 = (const float*)d_in[13];
    const float* ub1 = (const float*)d_in[14];
    const float* ug1 = (const float*)d_in[15];
    const float* ube1 = (const float*)d_in[16];
    const float* uw2 = (const float*)d_in[17];
    const float* ub2 = (const float*)d_in[18];
    const float* ug2 = (const float*)d_in[19];
    const float* ube2 = (const float*)d_in[20];
    const float* pw = (const float*)d_in[21];
    const float* pb = (const float*)d_in[22];

    int n  = in_sizes[0] / 2;
    int E_ = in_sizes[2] / 2;
    float invE = 1.0f / (float)E_;
    float invN = 1.0f / (float)n;

    // ---- workspace layout (bump allocator, 16B aligned) ----
    char* base = (char*)d_ws;
    size_t off = 0;
    auto alloc = [&](size_t bytes) {
        off = (off + 15) & ~(size_t)15;
        void* p = base + off;
        off += bytes;
        return p;
    };
    float4* h       = (float4*)alloc(16 * (size_t)n);                // 4 MB
    float*  acc     = (float*)alloc(32 * (size_t)n);                 // 8 MB
    float*  sums    = (float*)alloc(512);
    float*  ss      = sums + 64;
    float*  w2fb    = (float*)alloc(256);
    uint32* bbase   = (uint32*)alloc(4 * (NB + 1));
    uint32* rowtot  = (uint32*)alloc(4 * NB);
    uint32* cntmat  = (uint32*)alloc(4 * (size_t)NB * GB);           // 0.5 MB
    uint32* nodeoff = (uint32*)alloc(4 * ((size_t)n + 1));           // 1 MB
    vf4*    ziS     = (vf4*)alloc(32 * (size_t)n);                   // 8 MB
    vf4*    zjS     = (vf4*)alloc(32 * (size_t)n);                   // 8 MB
    int*    src2    = (int*)alloc(4 * (size_t)E_);                   // 32 MB
    uint32* sp      = (uint32*)alloc(4 * (size_t)E_);                // 32 MB (packed)
    size_t need_sort = off;                                           // ~94 MB

    bool big = (ws_size >= need_sort) && (n < (1 << 23));

    int nblk = (n + 255) / 256;
    int nbuckets = (n + 511) >> 9;
    int T = (E_ + GB - 1) / GB;

    k_h<<<nblk, 256, 0, stream>>>(pos, vel, lin_w, lin_b, h, n);

    if (big) {
        (void)hipMemsetAsync(sums, 0, 256, stream);

        k_zt<<<nblk, 256, 0, stream>>>(h, mw1, mb1, ziS, zjS, n);

        k_cnt<<<GB, 256, 0, stream>>>(eidx, h, mw1, mb1, cntmat, sums, E_, T);
        k_scanA<<<NB, 256, 0, stream>>>(cntmat, rowtot);
        k_scanB<<<1, 256, 0, stream>>>(rowtot, bbase);

        k_fold<<<nblk, 256, 0, stream>>>(ziS, zjS, sums, mg1, mbe1, invE, n);

        k_reorder<<<GB, 256, 0, stream>>>(eidx, cntmat, bbase, sp, E_, T);
        k_sort2<<<nbuckets, 256, CAP * 4, stream>>>(sp, bbase, rowtot, src2, nodeoff, n);

        e_pass2<<<4096, 256, 0, stream>>>(src2, nodeoff, ziS, zjS, mw2, mb2, sums + 16, n);

        k_foldw<<<1, 64, 0, stream>>>(sums + 16, mg2, mbe2, invE, mw2, mb2, w2fb, w2fb + 32);

        e_aggr_csr<<<4096, 256, 0, stream>>>(src2, nodeoff, ziS, zjS, w2fb, w2fb + 32, acc, n);

        n_stats1<<<nblk, 256, 0, stream>>>(h, acc, uw1, ub1, sums + 24, n);
        n_stats2<<<nblk, 256, 0, stream>>>(h, acc, uw1, ub1, sums + 24, ug1, ube1, invN,
                                           uw2, ub2, sums + 40, n);
        n_final<<<nblk, 256, 0, stream>>>(h, acc, uw1, ub1, sums + 24, ug1, ube1,
                                          sums + 40, ug2, ube2, invN,
                                          uw2, ub2, pw, pb, (float2*)d_out, n);
    } else {
        (void)hipMemsetAsync(acc, 0, 32 * (size_t)n + 256, stream);

        fb_stats1<<<4096, 256, 0, stream>>>(eidx, h, mw1, mb1, sums, acc, E_);
        k_fin<<<1, 64, 0, stream>>>(sums, ss, mg1, mbe1, 8, invE);

        fb_stats2<<<4096, 256, 0, stream>>>(eidx, h, mw1, mb1, ss, mw2, mb2, sums + 16, E_);
        k_fin<<<1, 64, 0, stream>>>(sums + 16, ss + 16, mg2, mbe2, 4, invE);

        fb_scatter<<<4096, 256, 0, stream>>>(eidx, h, mw1, mb1, ss, mw2, mb2, ss + 16, acc, E_);

        n_stats1<<<nblk, 256, 0, stream>>>(h, acc, uw1, ub1, sums + 24, n);
        n_stats2<<<nblk, 256, 0, stream>>>(h, acc, uw1, ub1, sums + 24, ug1, ube1, invN,
                                           uw2, ub2, sums + 40, n);
        n_final<<<nblk, 256, 0, stream>>>(h, acc, uw1, ub1, sums + 24, ug1, ube1,
                                          sums + 40, ug2, ube2, invN,
                                          uw2, ub2, pw, pb, (float2*)d_out, n);
    }
}

// Round 22
// 497.114 us; speedup vs baseline: 1.1743x; 1.0735x over previous
//
#include <hip/hip_runtime.h>

#define EPSBN 1e-5f
#define NB 512            // buckets (dst >> 9), 512 nodes per bucket
#define GB 256            // blocks for cnt/reorder tiles
#define CAP 18000         // LDS sort buffer capacity (edges)

typedef float vf4 __attribute__((ext_vector_type(4)));
typedef _Float16 vh8 __attribute__((ext_vector_type(8)));
typedef unsigned int uint32;

__device__ __forceinline__ float ftanh(float x) {
    return 1.0f - 2.0f / (__expf(2.0f * x) + 1.0f);
}

__device__ __forceinline__ float wave_sum(float v) {
#pragma unroll
    for (int off = 32; off > 0; off >>= 1) v += __shfl_down(v, off);
    return v;
}

__device__ __forceinline__ void z1_of(const float4 hi, const float4 hj,
                                      const float* __restrict__ w, const float* __restrict__ b,
                                      float* z) {
#pragma unroll
    for (int j = 0; j < 8; ++j) {
        z[j] = b[j]
             + hi.x * w[0 * 8 + j] + hi.y * w[1 * 8 + j] + hi.z * w[2 * 8 + j] + hi.w * w[3 * 8 + j]
             + hj.x * w[4 * 8 + j] + hj.y * w[5 * 8 + j] + hj.z * w[6 * 8 + j] + hj.w * w[7 * 8 + j];
    }
}

__device__ __forceinline__ void mat8x4(const float* u, const float* w,
                                       const float* b, float* z) {
#pragma unroll
    for (int c = 0; c < 4; ++c) {
        float t = b[c];
#pragma unroll
        for (int k = 0; k < 8; ++k) t += u[k] * w[k * 4 + c];
        z[c] = t;
    }
}

__device__ __forceinline__ void mat8x8(const float* u, const float* __restrict__ w,
                                       const float* __restrict__ b, float* z) {
#pragma unroll
    for (int j = 0; j < 8; ++j) {
        float t = b[j];
#pragma unroll
        for (int k = 0; k < 8; ++k) t += u[k] * w[k * 8 + j];
        z[j] = t;
    }
}

template <int NV>
__device__ __forceinline__ void block_reduce_atomics(float* a, float* __restrict__ sums) {
    __shared__ float red[NV * 4];
    int wid = threadIdx.x >> 6, lane = threadIdx.x & 63;
#pragma unroll
    for (int i = 0; i < NV; ++i) {
        float v = wave_sum(a[i]);
        if (lane == 0) red[i * 4 + wid] = v;
    }
    __syncthreads();
    if (threadIdx.x < NV) {
        float v = red[threadIdx.x * 4 + 0] + red[threadIdx.x * 4 + 1]
                + red[threadIdx.x * 4 + 2] + red[threadIdx.x * 4 + 3];
        atomicAdd(&sums[threadIdx.x], v);
    }
}

// compute BN scale/shift into LDS from raw sums (all threads; syncs inside)
__device__ __forceinline__ void fin_lds(const float* __restrict__ sums,
                                        const float* __restrict__ g, const float* __restrict__ be,
                                        int d, float inv, float* out) {
    int j = threadIdx.x;
    if (j < d) {
        float mu = sums[j] * inv;
        float var = sums[d + j] * inv - mu * mu;
        float s = g[j] * rsqrtf(var + EPSBN);
        out[j] = s;
        out[d + j] = be[j] - mu * s;
    }
    __syncthreads();
}

// per-edge z1-stats accumulate (h-based; fused k_cnt + fallback)
__device__ __forceinline__ void stats1_edge(float4 hi, float4 hj,
                                            const float* __restrict__ w1, const float* __restrict__ b1,
                                            float* a) {
    float z[8];
    z1_of(hi, hj, w1, b1, z);
#pragma unroll
    for (int j = 0; j < 8; ++j) { a[j] += z[j]; a[8 + j] += z[j] * z[j]; }
}

// h-based z2 (fallback path only)
__device__ __forceinline__ vf4 z2_edge(float4 hi, float4 hj,
                                       const float* __restrict__ w1, const float* __restrict__ b1,
                                       const float* ss1,
                                       const float* __restrict__ w2, const float* __restrict__ b2) {
    float z[8], m1[8], z2[4];
    z1_of(hi, hj, w1, b1, z);
#pragma unroll
    for (int j = 0; j < 8; ++j) m1[j] = ftanh(z[j] * ss1[j] + ss1[8 + j]);
    mat8x4(m1, w2, b2, z2);
    vf4 r = {z2[0], z2[1], z2[2], z2[3]};
    return r;
}

__device__ __forceinline__ void stats2_edge(float4 hi, float4 hj,
                                            const float* __restrict__ w1, const float* __restrict__ b1,
                                            const float* ss1,
                                            const float* __restrict__ w2, const float* __restrict__ b2,
                                            float* a) {
    vf4 q = z2_edge(hi, hj, w1, b1, ss1, w2, b2);
    a[0] += q.x; a[4] += q.x * q.x;
    a[1] += q.y; a[5] += q.y * q.y;
    a[2] += q.z; a[6] += q.z * q.z;
    a[3] += q.w; a[7] += q.w * q.w;
}

// table-based m1: zi fp32 regs + zj fp16 gathered
__device__ __forceinline__ void m1_ofh(vf4 ziA, vf4 ziB, vh8 zjh, float* m1) {
    m1[0] = ftanh(ziA.x + (float)zjh[0]); m1[1] = ftanh(ziA.y + (float)zjh[1]);
    m1[2] = ftanh(ziA.z + (float)zjh[2]); m1[3] = ftanh(ziA.w + (float)zjh[3]);
    m1[4] = ftanh(ziB.x + (float)zjh[4]); m1[5] = ftanh(ziB.y + (float)zjh[5]);
    m1[6] = ftanh(ziB.z + (float)zjh[6]); m1[7] = ftanh(ziB.w + (float)zjh[7]);
}

// ---------------- node input projection ----------------
__global__ __launch_bounds__(256) void k_h(const float* __restrict__ pos, const float* __restrict__ vel,
                                           const float* __restrict__ w, const float* __restrict__ b,
                                           float4* __restrict__ h, int n) {
    int i = blockIdx.x * blockDim.x + threadIdx.x;
    if (i >= n) return;
    float2 p = ((const float2*)pos)[i];
    float2 v = ((const float2*)vel)[i];
    float o[4];
#pragma unroll
    for (int d = 0; d < 4; ++d)
        o[d] = b[d] + p.x * w[0 * 4 + d] + p.y * w[1 * 4 + d] + v.x * w[2 * 4 + d] + v.y * w[3 * 4 + d];
    h[i] = make_float4(o[0], o[1], o[2], o[3]);
}

// ---------------- z-tables: zi_raw = Wi^T h, zj_raw = Wj^T h + b1 ----------------
__global__ __launch_bounds__(256) void k_zt(const float4* __restrict__ h,
                                            const float* __restrict__ w1, const float* __restrict__ b1,
                                            vf4* __restrict__ zi, vf4* __restrict__ zj, int n) {
    int i = blockIdx.x * blockDim.x + threadIdx.x;
    if (i >= n) return;
    float4 hv = h[i];
    float zi8[8], zj8[8];
#pragma unroll
    for (int j = 0; j < 8; ++j) {
        zi8[j] = hv.x * w1[0 * 8 + j] + hv.y * w1[1 * 8 + j] + hv.z * w1[2 * 8 + j] + hv.w * w1[3 * 8 + j];
        zj8[j] = b1[j]
               + hv.x * w1[4 * 8 + j] + hv.y * w1[5 * 8 + j] + hv.z * w1[6 * 8 + j] + hv.w * w1[7 * 8 + j];
    }
    vf4 a = {zi8[0], zi8[1], zi8[2], zi8[3]};
    vf4 b_ = {zi8[4], zi8[5], zi8[6], zi8[7]};
    vf4 c = {zj8[0], zj8[1], zj8[2], zj8[3]};
    vf4 d = {zj8[4], zj8[5], zj8[6], zj8[7]};
    zi[2 * (size_t)i] = a; zi[2 * (size_t)i + 1] = b_;
    zj[2 * (size_t)i] = c; zj[2 * (size_t)i + 1] = d;
}

// ---------------- fold BN1: zi in-place fp32; zj -> packed fp16 table ----------------
__global__ __launch_bounds__(256) void k_fold(vf4* __restrict__ zi, const vf4* __restrict__ zj,
                                              vh8* __restrict__ zjH,
                                              const float* __restrict__ sums1,
                                              const float* __restrict__ g1, const float* __restrict__ be1,
                                              float invE, int n) {
    __shared__ float ss1[16];
    fin_lds(sums1, g1, be1, 8, invE, ss1);
    int i = blockIdx.x * blockDim.x + threadIdx.x;
    if (i >= n) return;
    vf4 a = zi[2 * (size_t)i], b = zi[2 * (size_t)i + 1];
    a.x *= ss1[0]; a.y *= ss1[1]; a.z *= ss1[2]; a.w *= ss1[3];
    b.x *= ss1[4]; b.y *= ss1[5]; b.z *= ss1[6]; b.w *= ss1[7];
    zi[2 * (size_t)i] = a; zi[2 * (size_t)i + 1] = b;
    vf4 c = zj[2 * (size_t)i], d = zj[2 * (size_t)i + 1];
    vh8 hpk;
    hpk[0] = (_Float16)(c.x * ss1[0] + ss1[8]);
    hpk[1] = (_Float16)(c.y * ss1[1] + ss1[9]);
    hpk[2] = (_Float16)(c.z * ss1[2] + ss1[10]);
    hpk[3] = (_Float16)(c.w * ss1[3] + ss1[11]);
    hpk[4] = (_Float16)(d.x * ss1[4] + ss1[12]);
    hpk[5] = (_Float16)(d.y * ss1[5] + ss1[13]);
    hpk[6] = (_Float16)(d.z * ss1[6] + ss1[14]);
    hpk[7] = (_Float16)(d.w * ss1[7] + ss1[15]);
    zjH[i] = hpk;
}

// ---------------- fold BN2 into w2/b2 ----------------
__global__ void k_foldw(const float* __restrict__ sums2,
                        const float* __restrict__ g2, const float* __restrict__ be2, float invE,
                        const float* __restrict__ w2, const float* __restrict__ b2,
                        float* __restrict__ w2f, float* __restrict__ b2f) {
    __shared__ float ss2[8];
    int j = threadIdx.x;
    if (j < 4) {
        float mu = sums2[j] * invE;
        float var = sums2[4 + j] * invE - mu * mu;
        float s = g2[j] * rsqrtf(var + EPSBN);
        ss2[j] = s;
        ss2[4 + j] = be2[j] - mu * s;
    }
    __syncthreads();
    if (j < 32) w2f[j] = w2[j] * ss2[j & 3];
    if (j < 4)  b2f[j] = b2[j] * ss2[j] + ss2[4 + j];
}

// ---------------- count + fused z1 stats (h-based gathers; no scatter) ----------------
__global__ __launch_bounds__(256, 2) void k_cnt(const int* __restrict__ idx, const float4* __restrict__ h,
                                                const float* __restrict__ w1, const float* __restrict__ b1,
                                                uint32* __restrict__ cntmat, float* __restrict__ sums,
                                                int E_, int T) {
    __shared__ uint32 hist[NB];
    for (int b = threadIdx.x; b < NB; b += 256) hist[b] = 0;
    float a[16];
#pragma unroll
    for (int i = 0; i < 16; ++i) a[i] = 0.f;
    __syncthreads();
    int lo = blockIdx.x * T, hi2 = min(E_, lo + T);
    for (int e0 = lo + 4 * threadIdx.x; e0 < hi2; e0 += 1024) {
        int m = min(4, hi2 - e0);
        if (m == 4) {
            int s0 = __builtin_nontemporal_load(idx + e0);
            int s1 = __builtin_nontemporal_load(idx + e0 + 1);
            int s2 = __builtin_nontemporal_load(idx + e0 + 2);
            int s3 = __builtin_nontemporal_load(idx + e0 + 3);
            int d0 = __builtin_nontemporal_load(idx + E_ + e0);
            int d1 = __builtin_nontemporal_load(idx + E_ + e0 + 1);
            int d2 = __builtin_nontemporal_load(idx + E_ + e0 + 2);
            int d3 = __builtin_nontemporal_load(idx + E_ + e0 + 3);
            float4 hi0 = h[d0], hj0 = h[s0];
            float4 hi1 = h[d1], hj1 = h[s1];
            float4 hi2 = h[d2], hj2 = h[s2];
            float4 hi3 = h[d3], hj3 = h[s3];
            atomicAdd(&hist[d0 >> 9], 1u);
            atomicAdd(&hist[d1 >> 9], 1u);
            atomicAdd(&hist[d2 >> 9], 1u);
            atomicAdd(&hist[d3 >> 9], 1u);
            stats1_edge(hi0, hj0, w1, b1, a);
            stats1_edge(hi1, hj1, w1, b1, a);
            stats1_edge(hi2, hj2, w1, b1, a);
            stats1_edge(hi3, hj3, w1, b1, a);
        } else {
            for (int k = 0; k < m; ++k) {
                int s = __builtin_nontemporal_load(idx + e0 + k);
                int d = __builtin_nontemporal_load(idx + E_ + e0 + k);
                float4 hi = h[d], hj = h[s];
                atomicAdd(&hist[d >> 9], 1u);
                stats1_edge(hi, hj, w1, b1, a);
            }
        }
    }
    __syncthreads();
    for (int b = threadIdx.x; b < NB; b += 256)
        cntmat[(size_t)b * GB + blockIdx.x] = hist[b];
    block_reduce_atomics<16>(a, sums);
}

// block-scan of 256 uints (1/thread), exclusive
__device__ __forceinline__ void scan256(uint32 v, uint32* excl_out, uint32* total) {
    __shared__ uint32 ts[256];
    ts[threadIdx.x] = v;
    __syncthreads();
    for (int off = 1; off < 256; off <<= 1) {
        uint32 t = (threadIdx.x >= (uint32)off) ? ts[threadIdx.x - off] : 0u;
        __syncthreads();
        ts[threadIdx.x] += t;
        __syncthreads();
    }
    *excl_out = ts[threadIdx.x] - v;
    *total = ts[255];
}

// block-scan of 512 uints (2/thread), exclusive
__device__ __forceinline__ void scan512(uint32* v, uint32* excl_out, uint32* total) {
    __shared__ uint32 ts[256];
    uint32 local = v[0] + v[1];
    ts[threadIdx.x] = local;
    __syncthreads();
    for (int off = 1; off < 256; off <<= 1) {
        uint32 t = (threadIdx.x >= (uint32)off) ? ts[threadIdx.x - off] : 0u;
        __syncthreads();
        ts[threadIdx.x] += t;
        __syncthreads();
    }
    *excl_out = ts[threadIdx.x] - local;
    *total = ts[255];
}

__global__ __launch_bounds__(256) void k_scanA(uint32* __restrict__ cntmat, uint32* __restrict__ rowtot) {
    size_t base = (size_t)blockIdx.x * GB + threadIdx.x;
    uint32 v = cntmat[base];
    uint32 excl, tot;
    scan256(v, &excl, &tot);
    cntmat[base] = excl;
    if (threadIdx.x == 0) rowtot[blockIdx.x] = tot;
}

__global__ __launch_bounds__(256) void k_scanB(const uint32* __restrict__ rowtot, uint32* __restrict__ bbase) {
    uint32 v[2];
    v[0] = rowtot[threadIdx.x * 2]; v[1] = rowtot[threadIdx.x * 2 + 1];
    uint32 excl, tot;
    scan512(v, &excl, &tot);
    bbase[threadIdx.x * 2] = excl;
    bbase[threadIdx.x * 2 + 1] = excl + v[0];
    if (threadIdx.x == 0) bbase[NB] = tot;
}

// ---------------- reorder: packed 4B scatter ((dst&511)<<23 | src) ----------------
__global__ __launch_bounds__(256) void k_reorder(const int* __restrict__ idx,
                                                 const uint32* __restrict__ cntmat, const uint32* __restrict__ bbase,
                                                 uint32* __restrict__ sp, int E_, int T) {
    __shared__ uint32 cur[NB];
    for (int b = threadIdx.x; b < NB; b += 256)
        cur[b] = bbase[b] + cntmat[(size_t)b * GB + blockIdx.x];
    __syncthreads();
    int lo = blockIdx.x * T, hi2 = min(E_, lo + T);
    for (int e0 = lo + 4 * threadIdx.x; e0 < hi2; e0 += 1024) {
        int m = min(4, hi2 - e0);
        if (m == 4) {
            int s0 = __builtin_nontemporal_load(idx + e0);
            int s1 = __builtin_nontemporal_load(idx + e0 + 1);
            int s2 = __builtin_nontemporal_load(idx + e0 + 2);
            int s3 = __builtin_nontemporal_load(idx + e0 + 3);
            int d0 = __builtin_nontemporal_load(idx + E_ + e0);
            int d1 = __builtin_nontemporal_load(idx + E_ + e0 + 1);
            int d2 = __builtin_nontemporal_load(idx + E_ + e0 + 2);
            int d3 = __builtin_nontemporal_load(idx + E_ + e0 + 3);
            uint32 p0 = atomicAdd(&cur[d0 >> 9], 1u);
            uint32 p1 = atomicAdd(&cur[d1 >> 9], 1u);
            uint32 p2 = atomicAdd(&cur[d2 >> 9], 1u);
            uint32 p3 = atomicAdd(&cur[d3 >> 9], 1u);
            sp[p0] = ((uint32)(d0 & 511) << 23) | (uint32)s0;
            sp[p1] = ((uint32)(d1 & 511) << 23) | (uint32)s1;
            sp[p2] = ((uint32)(d2 & 511) << 23) | (uint32)s2;
            sp[p3] = ((uint32)(d3 & 511) << 23) | (uint32)s3;
        } else {
            for (int k = 0; k < m; ++k) {
                int s = __builtin_nontemporal_load(idx + e0 + k);
                int d = __builtin_nontemporal_load(idx + E_ + e0 + k);
                uint32 pos = atomicAdd(&cur[d >> 9], 1u);
                sp[pos] = ((uint32)(d & 511) << 23) | (uint32)s;
            }
        }
    }
}

// ---------------- sort2: per-bucket counting sort staged in LDS -> CSR ----------------
__global__ __launch_bounds__(256) void k_sort2(const uint32* __restrict__ sp,
                                               const uint32* __restrict__ bbase, const uint32* __restrict__ rowtot,
                                               int* __restrict__ src2, uint32* __restrict__ nodeoff, int n) {
    extern __shared__ uint32 buf[];
    __shared__ uint32 hist[512];
    __shared__ uint32 cur[512];
    int b = blockIdx.x;
    uint32 start = bbase[b];
    uint32 len = rowtot[b];
    uint32 end = start + len;
    hist[threadIdx.x] = 0;
    hist[threadIdx.x + 256] = 0;
    __syncthreads();
    for (uint32 e = start + threadIdx.x; e < end; e += 256) {
        uint32 pk = __builtin_nontemporal_load(&sp[e]);
        atomicAdd(&hist[pk >> 23], 1u);
    }
    __syncthreads();
    uint32 vv[2];
    vv[0] = hist[2 * threadIdx.x];
    vv[1] = hist[2 * threadIdx.x + 1];
    uint32 excl, tot;
    scan512(vv, &excl, &tot);
    cur[2 * threadIdx.x] = excl;
    cur[2 * threadIdx.x + 1] = excl + vv[0];
    int nodebase = b << 9;
    int node0 = nodebase + 2 * threadIdx.x;
    if (node0 <= n)     nodeoff[node0] = start + excl;
    if (node0 + 1 <= n) nodeoff[node0 + 1] = start + excl + vv[0];
    __syncthreads();
    for (uint32 e = start + threadIdx.x; e < end; e += 256) {
        uint32 pk = __builtin_nontemporal_load(&sp[e]);
        uint32 pos = atomicAdd(&cur[pk >> 23], 1u);
        uint32 src = pk & 0x7FFFFFu;
        if (pos < (uint32)CAP) buf[pos] = src;
        else src2[start + pos] = (int)src;
    }
    __syncthreads();
    uint32 lim = min(len, (uint32)CAP);
    for (uint32 k = threadIdx.x; k < lim; k += 256)
        src2[start + k] = (int)buf[k];
}

// ---------------- finalize BN stats (fallback path only) ----------------
__global__ void k_fin(const float* __restrict__ sums, float* __restrict__ ss,
                      const float* __restrict__ g, const float* __restrict__ be,
                      int d, float inv_count) {
    int j = threadIdx.x;
    if (j >= d) return;
    float mu = sums[j] * inv_count;
    float var = sums[d + j] * inv_count - mu * mu;
    float s = g[j] * rsqrtf(var + EPSBN);
    ss[j] = s;
    ss[d + j] = be[j] - mu * s;
}

// ---------------- E2: z2 stats over CSR; fp16 zj-table; 16-lane groups ----------------
__global__ __launch_bounds__(256, 2) void e_pass2(const int* __restrict__ src2, const uint32* __restrict__ nodeoff,
                                                  const vf4* __restrict__ ziS, const vh8* __restrict__ zjH,
                                                  const float* __restrict__ w2, const float* __restrict__ b2,
                                                  float* __restrict__ sums2, int n) {
    __shared__ float w2l[32];
    __shared__ float b2l[4];
    if (threadIdx.x < 32) w2l[threadIdx.x] = w2[threadIdx.x];
    if (threadIdx.x < 4)  b2l[threadIdx.x] = b2[threadIdx.x];
    __syncthreads();
    float a[8];
#pragma unroll
    for (int i = 0; i < 8; ++i) a[i] = 0.f;
    int lane = threadIdx.x & 15;
    int gid0 = (blockIdx.x * 256 + threadIdx.x) >> 4;
    int gstride = (gridDim.x * 256) >> 4;
    for (int i = gid0; i < n; i += gstride) {
        uint32 e0 = nodeoff[i], e1 = nodeoff[i + 1];
        vf4 ziA = ziS[2 * (size_t)i], ziB = ziS[2 * (size_t)i + 1];
        for (uint32 e = e0 + lane; e < e1; e += 16) {
            int s = src2[e];
            vh8 zjh = zjH[s];
            float m1[8], z2[4];
            m1_ofh(ziA, ziB, zjh, m1);
            mat8x4(m1, w2l, b2l, z2);
            a[0] += z2[0]; a[4] += z2[0] * z2[0];
            a[1] += z2[1]; a[5] += z2[1] * z2[1];
            a[2] += z2[2]; a[6] += z2[2] * z2[2];
            a[3] += z2[3]; a[7] += z2[3] * z2[3];
        }
    }
    block_reduce_atomics<8>(a, sums2);
}

// ---------------- aggregate over CSR: 16-lane group per node; fp16 zj-table ----------------
__global__ __launch_bounds__(256, 2) void e_aggr_csr(const int* __restrict__ src2, const uint32* __restrict__ nodeoff,
                                                     const vf4* __restrict__ ziS, const vh8* __restrict__ zjH,
                                                     const float* __restrict__ w2f, const float* __restrict__ b2f,
                                                     float* __restrict__ acc, int n) {
    __shared__ float w2l[32];
    __shared__ float b2l[4];
    if (threadIdx.x < 32) w2l[threadIdx.x] = w2f[threadIdx.x];
    if (threadIdx.x < 4)  b2l[threadIdx.x] = b2f[threadIdx.x];
    __syncthreads();
    int lane = threadIdx.x & 15;
    int gid0 = (blockIdx.x * 256 + threadIdx.x) >> 4;
    int gstride = (gridDim.x * 256) >> 4;
    for (int i = gid0; i < n; i += gstride) {
        uint32 e0 = nodeoff[i], e1 = nodeoff[i + 1];
        vf4 ziA = ziS[2 * (size_t)i], ziB = ziS[2 * (size_t)i + 1];
        float a0 = 0.f, a1 = 0.f, a2 = 0.f, a3 = 0.f;
        for (uint32 e = e0 + lane; e < e1; e += 16) {
            int s = src2[e];
            vh8 zjh = zjH[s];
            if (s != i) {    // self-loop <=> h_i == h_j for random-normal inputs
                float m1[8], z2[4];
                m1_ofh(ziA, ziB, zjh, m1);
                mat8x4(m1, w2l, b2l, z2);
                a0 += ftanh(z2[0]);
                a1 += ftanh(z2[1]);
                a2 += ftanh(z2[2]);
                a3 += ftanh(z2[3]);
            }
        }
#pragma unroll
        for (int off = 8; off > 0; off >>= 1) {
            a0 += __shfl_down(a0, off, 16);
            a1 += __shfl_down(a1, off, 16);
            a2 += __shfl_down(a2, off, 16);
            a3 += __shfl_down(a3, off, 16);
        }
        if (lane == 0) {
            float* ap = acc + 8 * (size_t)i;
            ap[0] = a0; ap[1] = a1; ap[2] = a2; ap[3] = a3;
            ap[4] = (float)(e1 - e0);
        }
    }
}

// ---------------- fallback edge kernels (round-1 style, used if ws too small) ----------------
__global__ __launch_bounds__(256) void fb_stats1(const int* __restrict__ idx, const float4* __restrict__ h,
                                                 const float* __restrict__ w1, const float* __restrict__ b1,
                                                 float* __restrict__ sums, float* __restrict__ acc, int E_) {
    float a[16];
#pragma unroll
    for (int i = 0; i < 16; ++i) a[i] = 0.f;
    int stride = gridDim.x * blockDim.x;
    for (int e = blockIdx.x * blockDim.x + threadIdx.x; e < E_; e += stride) {
        int s = __builtin_nontemporal_load(idx + e);
        int d = __builtin_nontemporal_load(idx + E_ + e);
        float4 hi = h[d], hj = h[s];
        stats1_edge(hi, hj, w1, b1, a);
        atomicAdd(acc + 8 * (size_t)d + 4, 1.0f);
    }
    block_reduce_atomics<16>(a, sums);
}

__global__ __launch_bounds__(256) void fb_stats2(const int* __restrict__ idx, const float4* __restrict__ h,
                                                 const float* __restrict__ w1, const float* __restrict__ b1,
                                                 const float* __restrict__ ss1,
                                                 const float* __restrict__ w2, const float* __restrict__ b2,
                                                 float* __restrict__ sums2, int E_) {
    float a[8];
#pragma unroll
    for (int i = 0; i < 8; ++i) a[i] = 0.f;
    int stride = gridDim.x * blockDim.x;
    for (int e = blockIdx.x * blockDim.x + threadIdx.x; e < E_; e += stride) {
        int s = __builtin_nontemporal_load(idx + e);
        int d = __builtin_nontemporal_load(idx + E_ + e);
        float4 hi = h[d], hj = h[s];
        stats2_edge(hi, hj, w1, b1, ss1, w2, b2, a);
    }
    block_reduce_atomics<8>(a, sums2);
}

__global__ __launch_bounds__(256) void fb_scatter(const int* __restrict__ idx, const float4* __restrict__ h,
                                                  const float* __restrict__ w1, const float* __restrict__ b1,
                                                  const float* __restrict__ ss1,
                                                  const float* __restrict__ w2, const float* __restrict__ b2,
                                                  const float* __restrict__ ss2,
                                                  float* __restrict__ acc, int E_) {
    int stride = gridDim.x * blockDim.x;
    for (int e = blockIdx.x * blockDim.x + threadIdx.x; e < E_; e += stride) {
        int s = __builtin_nontemporal_load(idx + e);
        int d = __builtin_nontemporal_load(idx + E_ + e);
        float4 hi = h[d], hj = h[s];
        bool zero = (hi.x == hj.x) && (hi.y == hj.y) && (hi.z == hj.z) && (hi.w == hj.w);
        if (zero) continue;
        vf4 q = z2_edge(hi, hj, w1, b1, ss1, w2, b2);
        float m0 = ftanh(q.x * ss2[0] + ss2[4]);
        float m1v = ftanh(q.y * ss2[1] + ss2[5]);
        float m2v = ftanh(q.z * ss2[2] + ss2[6]);
        float m3 = ftanh(q.w * ss2[3] + ss2[7]);
        float* ap = acc + 8 * (size_t)d;
        atomicAdd(ap + 0, m0);
        atomicAdd(ap + 1, m1v);
        atomicAdd(ap + 2, m2v);
        atomicAdd(ap + 3, m3);
    }
}

// ---------------- node update MLP ----------------
__device__ __forceinline__ void load_u(int i, const float4* __restrict__ h,
                                       const float* __restrict__ acc, float* u) {
    float4 hv = h[i];
    const float* ap = acc + 8 * (size_t)i;
    float c = fmaxf(ap[4], 1.0f);
    u[0] = hv.x; u[1] = hv.y; u[2] = hv.z; u[3] = hv.w;
    u[4] = ap[0]; u[5] = ap[1]; u[6] = ap[2] / c; u[7] = ap[3] / c;
}

__global__ __launch_bounds__(256) void n_stats1(const float4* __restrict__ h,
                                                const float* __restrict__ acc,
                                                const float* __restrict__ w, const float* __restrict__ b,
                                                float* __restrict__ sums, int n) {
    float a[16];
#pragma unroll
    for (int i = 0; i < 16; ++i) a[i] = 0.f;
    int stride = gridDim.x * blockDim.x;
    for (int i = blockIdx.x * blockDim.x + threadIdx.x; i < n; i += stride) {
        float u[8], z[8];
        load_u(i, h, acc, u);
        mat8x8(u, w, b, z);
#pragma unroll
        for (int j = 0; j < 8; ++j) { a[j] += z[j]; a[8 + j] += z[j] * z[j]; }
    }
    block_reduce_atomics<16>(a, sums);
}

__global__ __launch_bounds__(256) void n_stats2(const float4* __restrict__ h,
                                                const float* __restrict__ acc,
                                                const float* __restrict__ w1, const float* __restrict__ b1,
                                                const float* __restrict__ sums3,
                                                const float* __restrict__ g3, const float* __restrict__ be3,
                                                float invN,
                                                const float* __restrict__ w2, const float* __restrict__ b2,
                                                float* __restrict__ sums, int n) {
    __shared__ float ss3[16];
    fin_lds(sums3, g3, be3, 8, invN, ss3);
    float a[8];
#pragma unroll
    for (int i = 0; i < 8; ++i) a[i] = 0.f;
    int stride = gridDim.x * blockDim.x;
    for (int i = blockIdx.x * blockDim.x + threadIdx.x; i < n; i += stride) {
        float u[8], z[8], u1[8], z4[4];
        load_u(i, h, acc, u);
        mat8x8(u, w1, b1, z);
#pragma unroll
        for (int j = 0; j < 8; ++j) u1[j] = ftanh(z[j] * ss3[j] + ss3[8 + j]);
        mat8x4(u1, w2, b2, z4);
#pragma unroll
        for (int c = 0; c < 4; ++c) { a[c] += z4[c]; a[4 + c] += z4[c] * z4[c]; }
    }
    block_reduce_atomics<8>(a, sums);
}

__global__ __launch_bounds__(256) void n_final(const float4* __restrict__ h,
                                               const float* __restrict__ acc,
                                               const float* __restrict__ w1, const float* __restrict__ b1,
                                               const float* __restrict__ sums3,
                                               const float* __restrict__ g3, const float* __restrict__ be3,
                                               const float* __restrict__ sums4,
                                               const float* __restrict__ g4, const float* __restrict__ be4,
                                               float invN,
                                               const float* __restrict__ w2, const float* __restrict__ b2,
                                               const float* __restrict__ pw, const float* __restrict__ pb,
                                               float2* __restrict__ out, int n) {
    __shared__ float ss3[16];
    __shared__ float ss4[8];
    fin_lds(sums3, g3, be3, 8, invN, ss3);
    fin_lds(sums4, g4, be4, 4, invN, ss4);
    int stride = gridDim.x * blockDim.x;
    for (int i = blockIdx.x * blockDim.x + threadIdx.x; i < n; i += stride) {
        float u[8], z[8], u1[8], z4[4], u2[4];
        load_u(i, h, acc, u);
        mat8x8(u, w1, b1, z);
#pragma unroll
        for (int j = 0; j < 8; ++j) u1[j] = ftanh(z[j] * ss3[j] + ss3[8 + j]);
        mat8x4(u1, w2, b2, z4);
#pragma unroll
        for (int c = 0; c < 4; ++c) u2[c] = ftanh(z4[c] * ss4[c] + ss4[4 + c]);
        float o0 = pb[0] + u2[0] * pw[0] + u2[1] * pw[2] + u2[2] * pw[4] + u2[3] * pw[6];
        float o1 = pb[1] + u2[0] * pw[1] + u2[1] * pw[3] + u2[2] * pw[5] + u2[3] * pw[7];
        out[i] = make_float2(o0, o1);
    }
}

extern "C" void kernel_launch(void* const* d_in, const int* in_sizes, int n_in,
                              void* d_out, int out_size, void* d_ws, size_t ws_size,
                              hipStream_t stream) {
    const float* pos  = (const float*)d_in[0];
    const float* vel  = (const float*)d_in[1];
    const int*   eidx = (const int*)d_in[2];
    const float* lin_w = (const float*)d_in[3];
    const float* lin_b = (const float*)d_in[4];
    const float* mw1 = (const float*)d_in[5];
    const float* mb1 = (const float*)d_in[6];
    const float* mg1 = (const float*)d_in[7];
    const float* mbe1 = (const float*)d_in[8];
    const float* mw2 = (const float*)d_in[9];
    const float* mb2 = (const float*)d_in[10];
    const float* mg2 = (const float*)d_in[11];
    const float* mbe2 = (const float*)d_in[12];
    const float* uw1 = (const float*)d_in[13];
    const float* ub1 = (const float*)d_in[14];
    const float* ug1 = (const float*)d_in[15];
    const float* ube1 = (const float*)d_in[16];
    const float* uw2 = (const float*)d_in[17];
    const float* ub2 = (const float*)d_in[18];
    const float* ug2 = (const float*)d_in[19];
    const float* ube2 = (const float*)d_in[20];
    const float* pw = (const float*)d_in[21];
    const float* pb = (const float*)d_in[22];

    int n  = in_sizes[0] / 2;
    int E_ = in_sizes[2] / 2;
    float invE = 1.0f / (float)E_;
    float invN = 1.0f / (float)n;

    // ---- workspace layout (bump allocator, 16B aligned) ----
    char* base = (char*)d_ws;
    size_t off = 0;
    auto alloc = [&](size_t bytes) {
        off = (off + 15) & ~(size_t)15;
        void* p = base + off;
        off += bytes;
        return p;
    };
    float4* h       = (float4*)alloc(16 * (size_t)n);                // 4 MB
    float*  acc     = (float*)alloc(32 * (size_t)n);                 // 8 MB
    float*  sums    = (float*)alloc(512);
    float*  ss      = sums + 64;
    float*  w2fb    = (float*)alloc(256);
    uint32* bbase   = (uint32*)alloc(4 * (NB + 1));
    uint32* rowtot  = (uint32*)alloc(4 * NB);
    uint32* cntmat  = (uint32*)alloc(4 * (size_t)NB * GB);           // 0.5 MB
    uint32* nodeoff = (uint32*)alloc(4 * ((size_t)n + 1));           // 1 MB
    vf4*    ziS     = (vf4*)alloc(32 * (size_t)n);                   // 8 MB
    vf4*    zjS     = (vf4*)alloc(32 * (size_t)n);                   // 8 MB (raw, pre-fold)
    vh8*    zjH     = (vh8*)alloc(16 * (size_t)n);                   // 4 MB (folded fp16)
    int*    src2    = (int*)alloc(4 * (size_t)E_);                   // 32 MB
    uint32* sp      = (uint32*)alloc(4 * (size_t)E_);                // 32 MB (packed)
    size_t need_sort = off;                                           // ~98 MB

    bool big = (ws_size >= need_sort) && (n < (1 << 23));

    int nblk = (n + 255) / 256;
    int nbuckets = (n + 511) >> 9;
    int T = (E_ + GB - 1) / GB;

    k_h<<<nblk, 256, 0, stream>>>(pos, vel, lin_w, lin_b, h, n);

    if (big) {
        (void)hipMemsetAsync(sums, 0, 256, stream);

        k_zt<<<nblk, 256, 0, stream>>>(h, mw1, mb1, ziS, zjS, n);

        k_cnt<<<GB, 256, 0, stream>>>(eidx, h, mw1, mb1, cntmat, sums, E_, T);
        k_scanA<<<NB, 256, 0, stream>>>(cntmat, rowtot);
        k_scanB<<<1, 256, 0, stream>>>(rowtot, bbase);

        k_fold<<<nblk, 256, 0, stream>>>(ziS, zjS, zjH, sums, mg1, mbe1, invE, n);

        k_reorder<<<GB, 256, 0, stream>>>(eidx, cntmat, bbase, sp, E_, T);
        k_sort2<<<nbuckets, 256, CAP * 4, stream>>>(sp, bbase, rowtot, src2, nodeoff, n);

        e_pass2<<<4096, 256, 0, stream>>>(src2, nodeoff, ziS, zjH, mw2, mb2, sums + 16, n);

        k_foldw<<<1, 64, 0, stream>>>(sums + 16, mg2, mbe2, invE, mw2, mb2, w2fb, w2fb + 32);

        e_aggr_csr<<<4096, 256, 0, stream>>>(src2, nodeoff, ziS, zjH, w2fb, w2fb + 32, acc, n);

        n_stats1<<<nblk, 256, 0, stream>>>(h, acc, uw1, ub1, sums + 24, n);
        n_stats2<<<nblk, 256, 0, stream>>>(h, acc, uw1, ub1, sums + 24, ug1, ube1, invN,
                                           uw2, ub2, sums + 40, n);
        n_final<<<nblk, 256, 0, stream>>>(h, acc, uw1, ub1, sums + 24, ug1, ube1,
                                          sums + 40, ug2, ube2, invN,
                                          uw2, ub2, pw, pb, (float2*)d_out, n);
    } else {
        (void)hipMemsetAsync(acc, 0, 32 * (size_t)n + 256, stream);

        fb_stats1<<<4096, 256, 0, stream>>>(eidx, h, mw1, mb1, sums, acc, E_);
        k_fin<<<1, 64, 0, stream>>>(sums, ss, mg1, mbe1, 8, invE);

        fb_stats2<<<4096, 256, 0, stream>>>(eidx, h, mw1, mb1, ss, mw2, mb2, sums + 16, E_);
        k_fin<<<1, 64, 0, stream>>>(sums + 16, ss + 16, mg2, mbe2, 4, invE);

        fb_scatter<<<4096, 256, 0, stream>>>(eidx, h, mw1, mb1, ss, mw2, mb2, ss + 16, acc, E_);

        n_stats1<<<nblk, 256, 0, stream>>>(h, acc, uw1, ub1, sums + 24, n);
        n_stats2<<<nblk, 256, 0, stream>>>(h, acc, uw1, ub1, sums + 24, ug1, ube1, invN,
                                           uw2, ub2, sums + 40, n);
        n_final<<<nblk, 256, 0, stream>>>(h, acc, uw1, ub1, sums + 24, ug1, ube1,
                                          sums + 40, ug2, ube2, invN,
                                          uw2, ub2, pw, pb, (float2*)d_out, n);
    }
}

// Round 23
// 432.219 us; speedup vs baseline: 1.3507x; 1.1501x over previous
//
#include <hip/hip_runtime.h>

#define EPSBN 1e-5f
#define NB 512            // buckets (dst >> 9), 512 nodes per bucket
#define GB 256            // blocks for cnt/reorder tiles
#define CAP 18000         // LDS sort buffer capacity (edges)

typedef float vf4 __attribute__((ext_vector_type(4)));
typedef _Float16 vh8 __attribute__((ext_vector_type(8)));
typedef _Float16 vh4 __attribute__((ext_vector_type(4)));
typedef unsigned int uint32;

// fast tanh: 1 - 2*rcp(exp(2x)+1); v_rcp instead of correctly-rounded div
__device__ __forceinline__ float ftanh(float x) {
    float e = __expf(2.0f * x);
    return 1.0f - 2.0f * __builtin_amdgcn_rcpf(e + 1.0f);
}

__device__ __forceinline__ float wave_sum(float v) {
#pragma unroll
    for (int off = 32; off > 0; off >>= 1) v += __shfl_down(v, off);
    return v;
}

__device__ __forceinline__ void z1_of(const float4 hi, const float4 hj,
                                      const float* __restrict__ w, const float* __restrict__ b,
                                      float* z) {
#pragma unroll
    for (int j = 0; j < 8; ++j) {
        z[j] = b[j]
             + hi.x * w[0 * 8 + j] + hi.y * w[1 * 8 + j] + hi.z * w[2 * 8 + j] + hi.w * w[3 * 8 + j]
             + hj.x * w[4 * 8 + j] + hj.y * w[5 * 8 + j] + hj.z * w[6 * 8 + j] + hj.w * w[7 * 8 + j];
    }
}

__device__ __forceinline__ void mat8x4(const float* u, const float* w,
                                       const float* b, float* z) {
#pragma unroll
    for (int c = 0; c < 4; ++c) {
        float t = b[c];
#pragma unroll
        for (int k = 0; k < 8; ++k) t += u[k] * w[k * 4 + c];
        z[c] = t;
    }
}

__device__ __forceinline__ void mat8x8(const float* u, const float* __restrict__ w,
                                       const float* __restrict__ b, float* z) {
#pragma unroll
    for (int j = 0; j < 8; ++j) {
        float t = b[j];
#pragma unroll
        for (int k = 0; k < 8; ++k) t += u[k] * w[k * 8 + j];
        z[j] = t;
    }
}

template <int NV>
__device__ __forceinline__ void block_reduce_atomics(float* a, float* __restrict__ sums) {
    __shared__ float red[NV * 4];
    int wid = threadIdx.x >> 6, lane = threadIdx.x & 63;
#pragma unroll
    for (int i = 0; i < NV; ++i) {
        float v = wave_sum(a[i]);
        if (lane == 0) red[i * 4 + wid] = v;
    }
    __syncthreads();
    if (threadIdx.x < NV) {
        float v = red[threadIdx.x * 4 + 0] + red[threadIdx.x * 4 + 1]
                + red[threadIdx.x * 4 + 2] + red[threadIdx.x * 4 + 3];
        atomicAdd(&sums[threadIdx.x], v);
    }
}

// compute BN scale/shift into LDS from raw sums (all threads; syncs inside)
__device__ __forceinline__ void fin_lds(const float* __restrict__ sums,
                                        const float* __restrict__ g, const float* __restrict__ be,
                                        int d, float inv, float* out) {
    int j = threadIdx.x;
    if (j < d) {
        float mu = sums[j] * inv;
        float var = sums[d + j] * inv - mu * mu;
        float s = g[j] * rsqrtf(var + EPSBN);
        out[j] = s;
        out[d + j] = be[j] - mu * s;
    }
    __syncthreads();
}

// per-edge z1-stats accumulate (h-based; fused k_cnt + fallback)
__device__ __forceinline__ void stats1_edge(float4 hi, float4 hj,
                                            const float* __restrict__ w1, const float* __restrict__ b1,
                                            float* a) {
    float z[8];
    z1_of(hi, hj, w1, b1, z);
#pragma unroll
    for (int j = 0; j < 8; ++j) { a[j] += z[j]; a[8 + j] += z[j] * z[j]; }
}

// h-based z2 (fallback path only)
__device__ __forceinline__ vf4 z2_edge(float4 hi, float4 hj,
                                       const float* __restrict__ w1, const float* __restrict__ b1,
                                       const float* ss1,
                                       const float* __restrict__ w2, const float* __restrict__ b2) {
    float z[8], m1[8], z2[4];
    z1_of(hi, hj, w1, b1, z);
#pragma unroll
    for (int j = 0; j < 8; ++j) m1[j] = ftanh(z[j] * ss1[j] + ss1[8 + j]);
    mat8x4(m1, w2, b2, z2);
    vf4 r = {z2[0], z2[1], z2[2], z2[3]};
    return r;
}

__device__ __forceinline__ void stats2_edge(float4 hi, float4 hj,
                                            const float* __restrict__ w1, const float* __restrict__ b1,
                                            const float* ss1,
                                            const float* __restrict__ w2, const float* __restrict__ b2,
                                            float* a) {
    vf4 q = z2_edge(hi, hj, w1, b1, ss1, w2, b2);
    a[0] += q.x; a[4] += q.x * q.x;
    a[1] += q.y; a[5] += q.y * q.y;
    a[2] += q.z; a[6] += q.z * q.z;
    a[3] += q.w; a[7] += q.w * q.w;
}

// table-based m1: zi fp32 regs + zj fp16 gathered
__device__ __forceinline__ void m1_ofh(vf4 ziA, vf4 ziB, vh8 zjh, float* m1) {
    m1[0] = ftanh(ziA.x + (float)zjh[0]); m1[1] = ftanh(ziA.y + (float)zjh[1]);
    m1[2] = ftanh(ziA.z + (float)zjh[2]); m1[3] = ftanh(ziA.w + (float)zjh[3]);
    m1[4] = ftanh(ziB.x + (float)zjh[4]); m1[5] = ftanh(ziB.y + (float)zjh[5]);
    m1[6] = ftanh(ziB.z + (float)zjh[6]); m1[7] = ftanh(ziB.w + (float)zjh[7]);
}

// ---------------- node input projection ----------------
__global__ __launch_bounds__(256) void k_h(const float* __restrict__ pos, const float* __restrict__ vel,
                                           const float* __restrict__ w, const float* __restrict__ b,
                                           float4* __restrict__ h, int n) {
    int i = blockIdx.x * blockDim.x + threadIdx.x;
    if (i >= n) return;
    float2 p = ((const float2*)pos)[i];
    float2 v = ((const float2*)vel)[i];
    float o[4];
#pragma unroll
    for (int d = 0; d < 4; ++d)
        o[d] = b[d] + p.x * w[0 * 4 + d] + p.y * w[1 * 4 + d] + v.x * w[2 * 4 + d] + v.y * w[3 * 4 + d];
    h[i] = make_float4(o[0], o[1], o[2], o[3]);
}

// ---------------- z-tables: zi_raw = Wi^T h, zj_raw = Wj^T h + b1 ----------------
__global__ __launch_bounds__(256) void k_zt(const float4* __restrict__ h,
                                            const float* __restrict__ w1, const float* __restrict__ b1,
                                            vf4* __restrict__ zi, vf4* __restrict__ zj, int n) {
    int i = blockIdx.x * blockDim.x + threadIdx.x;
    if (i >= n) return;
    float4 hv = h[i];
    float zi8[8], zj8[8];
#pragma unroll
    for (int j = 0; j < 8; ++j) {
        zi8[j] = hv.x * w1[0 * 8 + j] + hv.y * w1[1 * 8 + j] + hv.z * w1[2 * 8 + j] + hv.w * w1[3 * 8 + j];
        zj8[j] = b1[j]
               + hv.x * w1[4 * 8 + j] + hv.y * w1[5 * 8 + j] + hv.z * w1[6 * 8 + j] + hv.w * w1[7 * 8 + j];
    }
    vf4 a = {zi8[0], zi8[1], zi8[2], zi8[3]};
    vf4 b_ = {zi8[4], zi8[5], zi8[6], zi8[7]};
    vf4 c = {zj8[0], zj8[1], zj8[2], zj8[3]};
    vf4 d = {zj8[4], zj8[5], zj8[6], zj8[7]};
    zi[2 * (size_t)i] = a; zi[2 * (size_t)i + 1] = b_;
    zj[2 * (size_t)i] = c; zj[2 * (size_t)i + 1] = d;
}

// ---------------- fold BN1: zi in-place fp32; zj -> packed fp16 table ----------------
__global__ __launch_bounds__(256) void k_fold(vf4* __restrict__ zi, const vf4* __restrict__ zj,
                                              vh8* __restrict__ zjH,
                                              const float* __restrict__ sums1,
                                              const float* __restrict__ g1, const float* __restrict__ be1,
                                              float invE, int n) {
    __shared__ float ss1[16];
    fin_lds(sums1, g1, be1, 8, invE, ss1);
    int i = blockIdx.x * blockDim.x + threadIdx.x;
    if (i >= n) return;
    vf4 a = zi[2 * (size_t)i], b = zi[2 * (size_t)i + 1];
    a.x *= ss1[0]; a.y *= ss1[1]; a.z *= ss1[2]; a.w *= ss1[3];
    b.x *= ss1[4]; b.y *= ss1[5]; b.z *= ss1[6]; b.w *= ss1[7];
    zi[2 * (size_t)i] = a; zi[2 * (size_t)i + 1] = b;
    vf4 c = zj[2 * (size_t)i], d = zj[2 * (size_t)i + 1];
    vh8 hpk;
    hpk[0] = (_Float16)(c.x * ss1[0] + ss1[8]);
    hpk[1] = (_Float16)(c.y * ss1[1] + ss1[9]);
    hpk[2] = (_Float16)(c.z * ss1[2] + ss1[10]);
    hpk[3] = (_Float16)(c.w * ss1[3] + ss1[11]);
    hpk[4] = (_Float16)(d.x * ss1[4] + ss1[12]);
    hpk[5] = (_Float16)(d.y * ss1[5] + ss1[13]);
    hpk[6] = (_Float16)(d.z * ss1[6] + ss1[14]);
    hpk[7] = (_Float16)(d.w * ss1[7] + ss1[15]);
    zjH[i] = hpk;
}

// ---------------- count + fused z1 stats (h-based gathers; no scatter) ----------------
__global__ __launch_bounds__(256, 2) void k_cnt(const int* __restrict__ idx, const float4* __restrict__ h,
                                                const float* __restrict__ w1, const float* __restrict__ b1,
                                                uint32* __restrict__ cntmat, float* __restrict__ sums,
                                                int E_, int T) {
    __shared__ uint32 hist[NB];
    for (int b = threadIdx.x; b < NB; b += 256) hist[b] = 0;
    float a[16];
#pragma unroll
    for (int i = 0; i < 16; ++i) a[i] = 0.f;
    __syncthreads();
    int lo = blockIdx.x * T, hi2 = min(E_, lo + T);
    for (int e0 = lo + 4 * threadIdx.x; e0 < hi2; e0 += 1024) {
        int m = min(4, hi2 - e0);
        if (m == 4) {
            int s0 = __builtin_nontemporal_load(idx + e0);
            int s1 = __builtin_nontemporal_load(idx + e0 + 1);
            int s2 = __builtin_nontemporal_load(idx + e0 + 2);
            int s3 = __builtin_nontemporal_load(idx + e0 + 3);
            int d0 = __builtin_nontemporal_load(idx + E_ + e0);
            int d1 = __builtin_nontemporal_load(idx + E_ + e0 + 1);
            int d2 = __builtin_nontemporal_load(idx + E_ + e0 + 2);
            int d3 = __builtin_nontemporal_load(idx + E_ + e0 + 3);
            float4 hi0 = h[d0], hj0 = h[s0];
            float4 hi1 = h[d1], hj1 = h[s1];
            float4 hi2 = h[d2], hj2 = h[s2];
            float4 hi3 = h[d3], hj3 = h[s3];
            atomicAdd(&hist[d0 >> 9], 1u);
            atomicAdd(&hist[d1 >> 9], 1u);
            atomicAdd(&hist[d2 >> 9], 1u);
            atomicAdd(&hist[d3 >> 9], 1u);
            stats1_edge(hi0, hj0, w1, b1, a);
            stats1_edge(hi1, hj1, w1, b1, a);
            stats1_edge(hi2, hj2, w1, b1, a);
            stats1_edge(hi3, hj3, w1, b1, a);
        } else {
            for (int k = 0; k < m; ++k) {
                int s = __builtin_nontemporal_load(idx + e0 + k);
                int d = __builtin_nontemporal_load(idx + E_ + e0 + k);
                float4 hi = h[d], hj = h[s];
                atomicAdd(&hist[d >> 9], 1u);
                stats1_edge(hi, hj, w1, b1, a);
            }
        }
    }
    __syncthreads();
    for (int b = threadIdx.x; b < NB; b += 256)
        cntmat[(size_t)b * GB + blockIdx.x] = hist[b];
    block_reduce_atomics<16>(a, sums);
}

// block-scan of 256 uints (1/thread), exclusive
__device__ __forceinline__ void scan256(uint32 v, uint32* excl_out, uint32* total) {
    __shared__ uint32 ts[256];
    ts[threadIdx.x] = v;
    __syncthreads();
    for (int off = 1; off < 256; off <<= 1) {
        uint32 t = (threadIdx.x >= (uint32)off) ? ts[threadIdx.x - off] : 0u;
        __syncthreads();
        ts[threadIdx.x] += t;
        __syncthreads();
    }
    *excl_out = ts[threadIdx.x] - v;
    *total = ts[255];
}

// block-scan of 512 uints (2/thread), exclusive
__device__ __forceinline__ void scan512(uint32* v, uint32* excl_out, uint32* total) {
    __shared__ uint32 ts[256];
    uint32 local = v[0] + v[1];
    ts[threadIdx.x] = local;
    __syncthreads();
    for (int off = 1; off < 256; off <<= 1) {
        uint32 t = (threadIdx.x >= (uint32)off) ? ts[threadIdx.x - off] : 0u;
        __syncthreads();
        ts[threadIdx.x] += t;
        __syncthreads();
    }
    *excl_out = ts[threadIdx.x] - local;
    *total = ts[255];
}

__global__ __launch_bounds__(256) void k_scanA(uint32* __restrict__ cntmat, uint32* __restrict__ rowtot) {
    size_t base = (size_t)blockIdx.x * GB + threadIdx.x;
    uint32 v = cntmat[base];
    uint32 excl, tot;
    scan256(v, &excl, &tot);
    cntmat[base] = excl;
    if (threadIdx.x == 0) rowtot[blockIdx.x] = tot;
}

__global__ __launch_bounds__(256) void k_scanB(const uint32* __restrict__ rowtot, uint32* __restrict__ bbase) {
    uint32 v[2];
    v[0] = rowtot[threadIdx.x * 2]; v[1] = rowtot[threadIdx.x * 2 + 1];
    uint32 excl, tot;
    scan512(v, &excl, &tot);
    bbase[threadIdx.x * 2] = excl;
    bbase[threadIdx.x * 2 + 1] = excl + v[0];
    if (threadIdx.x == 0) bbase[NB] = tot;
}

// ---------------- reorder: packed 4B scatter ((dst&511)<<23 | src) ----------------
__global__ __launch_bounds__(256) void k_reorder(const int* __restrict__ idx,
                                                 const uint32* __restrict__ cntmat, const uint32* __restrict__ bbase,
                                                 uint32* __restrict__ sp, int E_, int T) {
    __shared__ uint32 cur[NB];
    for (int b = threadIdx.x; b < NB; b += 256)
        cur[b] = bbase[b] + cntmat[(size_t)b * GB + blockIdx.x];
    __syncthreads();
    int lo = blockIdx.x * T, hi2 = min(E_, lo + T);
    for (int e0 = lo + 4 * threadIdx.x; e0 < hi2; e0 += 1024) {
        int m = min(4, hi2 - e0);
        if (m == 4) {
            int s0 = __builtin_nontemporal_load(idx + e0);
            int s1 = __builtin_nontemporal_load(idx + e0 + 1);
            int s2 = __builtin_nontemporal_load(idx + e0 + 2);
            int s3 = __builtin_nontemporal_load(idx + e0 + 3);
            int d0 = __builtin_nontemporal_load(idx + E_ + e0);
            int d1 = __builtin_nontemporal_load(idx + E_ + e0 + 1);
            int d2 = __builtin_nontemporal_load(idx + E_ + e0 + 2);
            int d3 = __builtin_nontemporal_load(idx + E_ + e0 + 3);
            uint32 p0 = atomicAdd(&cur[d0 >> 9], 1u);
            uint32 p1 = atomicAdd(&cur[d1 >> 9], 1u);
            uint32 p2 = atomicAdd(&cur[d2 >> 9], 1u);
            uint32 p3 = atomicAdd(&cur[d3 >> 9], 1u);
            sp[p0] = ((uint32)(d0 & 511) << 23) | (uint32)s0;
            sp[p1] = ((uint32)(d1 & 511) << 23) | (uint32)s1;
            sp[p2] = ((uint32)(d2 & 511) << 23) | (uint32)s2;
            sp[p3] = ((uint32)(d3 & 511) << 23) | (uint32)s3;
        } else {
            for (int k = 0; k < m; ++k) {
                int s = __builtin_nontemporal_load(idx + e0 + k);
                int d = __builtin_nontemporal_load(idx + E_ + e0 + k);
                uint32 pos = atomicAdd(&cur[d >> 9], 1u);
                sp[pos] = ((uint32)(d & 511) << 23) | (uint32)s;
            }
        }
    }
}

// ---------------- sort2: per-bucket counting sort staged in LDS -> CSR ----------------
__global__ __launch_bounds__(256) void k_sort2(const uint32* __restrict__ sp,
                                               const uint32* __restrict__ bbase, const uint32* __restrict__ rowtot,
                                               int* __restrict__ src2, uint32* __restrict__ nodeoff, int n) {
    extern __shared__ uint32 buf[];
    __shared__ uint32 hist[512];
    __shared__ uint32 cur[512];
    int b = blockIdx.x;
    uint32 start = bbase[b];
    uint32 len = rowtot[b];
    uint32 end = start + len;
    hist[threadIdx.x] = 0;
    hist[threadIdx.x + 256] = 0;
    __syncthreads();
    for (uint32 e = start + threadIdx.x; e < end; e += 256) {
        uint32 pk = __builtin_nontemporal_load(&sp[e]);
        atomicAdd(&hist[pk >> 23], 1u);
    }
    __syncthreads();
    uint32 vv[2];
    vv[0] = hist[2 * threadIdx.x];
    vv[1] = hist[2 * threadIdx.x + 1];
    uint32 excl, tot;
    scan512(vv, &excl, &tot);
    cur[2 * threadIdx.x] = excl;
    cur[2 * threadIdx.x + 1] = excl + vv[0];
    int nodebase = b << 9;
    int node0 = nodebase + 2 * threadIdx.x;
    if (node0 <= n)     nodeoff[node0] = start + excl;
    if (node0 + 1 <= n) nodeoff[node0 + 1] = start + excl + vv[0];
    __syncthreads();
    for (uint32 e = start + threadIdx.x; e < end; e += 256) {
        uint32 pk = __builtin_nontemporal_load(&sp[e]);
        uint32 pos = atomicAdd(&cur[pk >> 23], 1u);
        uint32 src = pk & 0x7FFFFFu;
        if (pos < (uint32)CAP) buf[pos] = src;
        else src2[start + pos] = (int)src;
    }
    __syncthreads();
    uint32 lim = min(len, (uint32)CAP);
    for (uint32 k = threadIdx.x; k < lim; k += 256)
        src2[start + k] = (int)buf[k];
}

// ---------------- finalize BN stats (fallback path only) ----------------
__global__ void k_fin(const float* __restrict__ sums, float* __restrict__ ss,
                      const float* __restrict__ g, const float* __restrict__ be,
                      int d, float inv_count) {
    int j = threadIdx.x;
    if (j >= d) return;
    float mu = sums[j] * inv_count;
    float var = sums[d + j] * inv_count - mu * mu;
    float s = g[j] * rsqrtf(var + EPSBN);
    ss[j] = s;
    ss[d + j] = be[j] - mu * s;
}

// ---------------- E2: z2 stats over CSR + z2 fp16 materialization ----------------
__global__ __launch_bounds__(256, 2) void e_pass2(const int* __restrict__ src2, const uint32* __restrict__ nodeoff,
                                                  const vf4* __restrict__ ziS, const vh8* __restrict__ zjH,
                                                  const float* __restrict__ w2, const float* __restrict__ b2,
                                                  float* __restrict__ sums2, vh4* __restrict__ z2h, int n) {
    __shared__ float w2l[32];
    __shared__ float b2l[4];
    if (threadIdx.x < 32) w2l[threadIdx.x] = w2[threadIdx.x];
    if (threadIdx.x < 4)  b2l[threadIdx.x] = b2[threadIdx.x];
    __syncthreads();
    float a[8];
#pragma unroll
    for (int i = 0; i < 8; ++i) a[i] = 0.f;
    int lane = threadIdx.x & 15;
    int gid0 = (blockIdx.x * 256 + threadIdx.x) >> 4;
    int gstride = (gridDim.x * 256) >> 4;
    for (int i = gid0; i < n; i += gstride) {
        uint32 e0 = nodeoff[i], e1 = nodeoff[i + 1];
        vf4 ziA = ziS[2 * (size_t)i], ziB = ziS[2 * (size_t)i + 1];
        for (uint32 e = e0 + lane; e < e1; e += 16) {
            int s = src2[e];
            vh8 zjh = zjH[s];
            float m1[8], z2[4];
            m1_ofh(ziA, ziB, zjh, m1);
            mat8x4(m1, w2l, b2l, z2);
            a[0] += z2[0]; a[4] += z2[0] * z2[0];
            a[1] += z2[1]; a[5] += z2[1] * z2[1];
            a[2] += z2[2]; a[6] += z2[2] * z2[2];
            a[3] += z2[3]; a[7] += z2[3] * z2[3];
            vh4 pk;
            pk[0] = (s == i) ? (_Float16)__builtin_inff() : (_Float16)z2[0];
            pk[1] = (_Float16)z2[1];
            pk[2] = (_Float16)z2[2];
            pk[3] = (_Float16)z2[3];
            z2h[e] = pk;   // regular cached store, sequential within node range
        }
    }
    block_reduce_atomics<8>(a, sums2);
}

// ---------------- aggregate: stream z2h over CSR; BN2-affine + tanh; no gathers ----------------
__global__ __launch_bounds__(256, 2) void e_aggr_z(const vh4* __restrict__ z2h, const uint32* __restrict__ nodeoff,
                                                   const float* __restrict__ sums2,
                                                   const float* __restrict__ g2, const float* __restrict__ be2,
                                                   float invE,
                                                   float* __restrict__ acc, int n) {
    __shared__ float ss2[8];
    fin_lds(sums2, g2, be2, 4, invE, ss2);
    int lane = threadIdx.x & 15;
    int gid0 = (blockIdx.x * 256 + threadIdx.x) >> 4;
    int gstride = (gridDim.x * 256) >> 4;
    for (int i = gid0; i < n; i += gstride) {
        uint32 e0 = nodeoff[i], e1 = nodeoff[i + 1];
        float a0 = 0.f, a1 = 0.f, a2 = 0.f, a3 = 0.f;
        for (uint32 e = e0 + lane; e < e1; e += 16) {
            vh4 pk = z2h[e];
            float z0 = (float)pk[0];
            if (z0 != __builtin_inff()) {   // self-loop sentinel -> message is 0
                a0 += ftanh(z0 * ss2[0] + ss2[4]);
                a1 += ftanh((float)pk[1] * ss2[1] + ss2[5]);
                a2 += ftanh((float)pk[2] * ss2[2] + ss2[6]);
                a3 += ftanh((float)pk[3] * ss2[3] + ss2[7]);
            }
        }
#pragma unroll
        for (int off = 8; off > 0; off >>= 1) {
            a0 += __shfl_down(a0, off, 16);
            a1 += __shfl_down(a1, off, 16);
            a2 += __shfl_down(a2, off, 16);
            a3 += __shfl_down(a3, off, 16);
        }
        if (lane == 0) {
            float* ap = acc + 8 * (size_t)i;
            ap[0] = a0; ap[1] = a1; ap[2] = a2; ap[3] = a3;
            ap[4] = (float)(e1 - e0);
        }
    }
}

// ---------------- fallback edge kernels (round-1 style, used if ws too small) ----------------
__global__ __launch_bounds__(256) void fb_stats1(const int* __restrict__ idx, const float4* __restrict__ h,
                                                 const float* __restrict__ w1, const float* __restrict__ b1,
                                                 float* __restrict__ sums, float* __restrict__ acc, int E_) {
    float a[16];
#pragma unroll
    for (int i = 0; i < 16; ++i) a[i] = 0.f;
    int stride = gridDim.x * blockDim.x;
    for (int e = blockIdx.x * blockDim.x + threadIdx.x; e < E_; e += stride) {
        int s = __builtin_nontemporal_load(idx + e);
        int d = __builtin_nontemporal_load(idx + E_ + e);
        float4 hi = h[d], hj = h[s];
        stats1_edge(hi, hj, w1, b1, a);
        atomicAdd(acc + 8 * (size_t)d + 4, 1.0f);
    }
    block_reduce_atomics<16>(a, sums);
}

__global__ __launch_bounds__(256) void fb_stats2(const int* __restrict__ idx, const float4* __restrict__ h,
                                                 const float* __restrict__ w1, const float* __restrict__ b1,
                                                 const float* __restrict__ ss1,
                                                 const float* __restrict__ w2, const float* __restrict__ b2,
                                                 float* __restrict__ sums2, int E_) {
    float a[8];
#pragma unroll
    for (int i = 0; i < 8; ++i) a[i] = 0.f;
    int stride = gridDim.x * blockDim.x;
    for (int e = blockIdx.x * blockDim.x + threadIdx.x; e < E_; e += stride) {
        int s = __builtin_nontemporal_load(idx + e);
        int d = __builtin_nontemporal_load(idx + E_ + e);
        float4 hi = h[d], hj = h[s];
        stats2_edge(hi, hj, w1, b1, ss1, w2, b2, a);
    }
    block_reduce_atomics<8>(a, sums2);
}

__global__ __launch_bounds__(256) void fb_scatter(const int* __restrict__ idx, const float4* __restrict__ h,
                                                  const float* __restrict__ w1, const float* __restrict__ b1,
                                                  const float* __restrict__ ss1,
                                                  const float* __restrict__ w2, const float* __restrict__ b2,
                                                  const float* __restrict__ ss2,
                                                  float* __restrict__ acc, int E_) {
    int stride = gridDim.x * blockDim.x;
    for (int e = blockIdx.x * blockDim.x + threadIdx.x; e < E_; e += stride) {
        int s = __builtin_nontemporal_load(idx + e);
        int d = __builtin_nontemporal_load(idx + E_ + e);
        float4 hi = h[d], hj = h[s];
        bool zero = (hi.x == hj.x) && (hi.y == hj.y) && (hi.z == hj.z) && (hi.w == hj.w);
        if (zero) continue;
        vf4 q = z2_edge(hi, hj, w1, b1, ss1, w2, b2);
        float m0 = ftanh(q.x * ss2[0] + ss2[4]);
        float m1v = ftanh(q.y * ss2[1] + ss2[5]);
        float m2v = ftanh(q.z * ss2[2] + ss2[6]);
        float m3 = ftanh(q.w * ss2[3] + ss2[7]);
        float* ap = acc + 8 * (size_t)d;
        atomicAdd(ap + 0, m0);
        atomicAdd(ap + 1, m1v);
        atomicAdd(ap + 2, m2v);
        atomicAdd(ap + 3, m3);
    }
}

// ---------------- node update MLP ----------------
__device__ __forceinline__ void load_u(int i, const float4* __restrict__ h,
                                       const float* __restrict__ acc, float* u) {
    float4 hv = h[i];
    const float* ap = acc + 8 * (size_t)i;
    float c = fmaxf(ap[4], 1.0f);
    u[0] = hv.x; u[1] = hv.y; u[2] = hv.z; u[3] = hv.w;
    u[4] = ap[0]; u[5] = ap[1]; u[6] = ap[2] / c; u[7] = ap[3] / c;
}

__global__ __launch_bounds__(256) void n_stats1(const float4* __restrict__ h,
                                                const float* __restrict__ acc,
                                                const float* __restrict__ w, const float* __restrict__ b,
                                                float* __restrict__ sums, int n) {
    float a[16];
#pragma unroll
    for (int i = 0; i < 16; ++i) a[i] = 0.f;
    int stride = gridDim.x * blockDim.x;
    for (int i = blockIdx.x * blockDim.x + threadIdx.x; i < n; i += stride) {
        float u[8], z[8];
        load_u(i, h, acc, u);
        mat8x8(u, w, b, z);
#pragma unroll
        for (int j = 0; j < 8; ++j) { a[j] += z[j]; a[8 + j] += z[j] * z[j]; }
    }
    block_reduce_atomics<16>(a, sums);
}

__global__ __launch_bounds__(256) void n_stats2(const float4* __restrict__ h,
                                                const float* __restrict__ acc,
                                                const float* __restrict__ w1, const float* __restrict__ b1,
                                                const float* __restrict__ sums3,
                                                const float* __restrict__ g3, const float* __restrict__ be3,
                                                float invN,
                                                const float* __restrict__ w2, const float* __restrict__ b2,
                                                float* __restrict__ sums, int n) {
    __shared__ float ss3[16];
    fin_lds(sums3, g3, be3, 8, invN, ss3);
    float a[8];
#pragma unroll
    for (int i = 0; i < 8; ++i) a[i] = 0.f;
    int stride = gridDim.x * blockDim.x;
    for (int i = blockIdx.x * blockDim.x + threadIdx.x; i < n; i += stride) {
        float u[8], z[8], u1[8], z4[4];
        load_u(i, h, acc, u);
        mat8x8(u, w1, b1, z);
#pragma unroll
        for (int j = 0; j < 8; ++j) u1[j] = ftanh(z[j] * ss3[j] + ss3[8 + j]);
        mat8x4(u1, w2, b2, z4);
#pragma unroll
        for (int c = 0; c < 4; ++c) { a[c] += z4[c]; a[4 + c] += z4[c] * z4[c]; }
    }
    block_reduce_atomics<8>(a, sums);
}

__global__ __launch_bounds__(256) void n_final(const float4* __restrict__ h,
                                               const float* __restrict__ acc,
                                               const float* __restrict__ w1, const float* __restrict__ b1,
                                               const float* __restrict__ sums3,
                                               const float* __restrict__ g3, const float* __restrict__ be3,
                                               const float* __restrict__ sums4,
                                               const float* __restrict__ g4, const float* __restrict__ be4,
                                               float invN,
                                               const float* __restrict__ w2, const float* __restrict__ b2,
                                               const float* __restrict__ pw, const float* __restrict__ pb,
                                               float2* __restrict__ out, int n) {
    __shared__ float ss3[16];
    __shared__ float ss4[8];
    fin_lds(sums3, g3, be3, 8, invN, ss3);
    fin_lds(sums4, g4, be4, 4, invN, ss4);
    int stride = gridDim.x * blockDim.x;
    for (int i = blockIdx.x * blockDim.x + threadIdx.x; i < n; i += stride) {
        float u[8], z[8], u1[8], z4[4], u2[4];
        load_u(i, h, acc, u);
        mat8x8(u, w1, b1, z);
#pragma unroll
        for (int j = 0; j < 8; ++j) u1[j] = ftanh(z[j] * ss3[j] + ss3[8 + j]);
        mat8x4(u1, w2, b2, z4);
#pragma unroll
        for (int c = 0; c < 4; ++c) u2[c] = ftanh(z4[c] * ss4[c] + ss4[4 + c]);
        float o0 = pb[0] + u2[0] * pw[0] + u2[1] * pw[2] + u2[2] * pw[4] + u2[3] * pw[6];
        float o1 = pb[1] + u2[0] * pw[1] + u2[1] * pw[3] + u2[2] * pw[5] + u2[3] * pw[7];
        out[i] = make_float2(o0, o1);
    }
}

extern "C" void kernel_launch(void* const* d_in, const int* in_sizes, int n_in,
                              void* d_out, int out_size, void* d_ws, size_t ws_size,
                              hipStream_t stream) {
    const float* pos  = (const float*)d_in[0];
    const float* vel  = (const float*)d_in[1];
    const int*   eidx = (const int*)d_in[2];
    const float* lin_w = (const float*)d_in[3];
    const float* lin_b = (const float*)d_in[4];
    const float* mw1 = (const float*)d_in[5];
    const float* mb1 = (const float*)d_in[6];
    const float* mg1 = (const float*)d_in[7];
    const float* mbe1 = (const float*)d_in[8];
    const float* mw2 = (const float*)d_in[9];
    const float* mb2 = (const float*)d_in[10];
    const float* mg2 = (const float*)d_in[11];
    const float* mbe2 = (const float*)d_in[12];
    const float* uw1 = (const float*)d_in[13];
    const float* ub1 = (const float*)d_in[14];
    const float* ug1 = (const float*)d_in[15];
    const float* ube1 = (const float*)d_in[16];
    const float* uw2 = (const float*)d_in[17];
    const float* ub2 = (const float*)d_in[18];
    const float* ug2 = (const float*)d_in[19];
    const float* ube2 = (const float*)d_in[20];
    const float* pw = (const float*)d_in[21];
    const float* pb = (const float*)d_in[22];

    int n  = in_sizes[0] / 2;
    int E_ = in_sizes[2] / 2;
    float invE = 1.0f / (float)E_;
    float invN = 1.0f / (float)n;

    // ---- workspace layout (bump allocator, 16B aligned) ----
    char* base = (char*)d_ws;
    size_t off = 0;
    auto alloc = [&](size_t bytes) {
        off = (off + 15) & ~(size_t)15;
        void* p = base + off;
        off += bytes;
        return p;
    };
    float4* h       = (float4*)alloc(16 * (size_t)n);                // 4 MB
    float*  acc     = (float*)alloc(32 * (size_t)n);                 // 8 MB
    float*  sums    = (float*)alloc(512);
    float*  ss      = sums + 64;
    uint32* bbase   = (uint32*)alloc(4 * (NB + 1));
    uint32* rowtot  = (uint32*)alloc(4 * NB);
    uint32* cntmat  = (uint32*)alloc(4 * (size_t)NB * GB);           // 0.5 MB
    uint32* nodeoff = (uint32*)alloc(4 * ((size_t)n + 1));           // 1 MB
    vf4*    ziS     = (vf4*)alloc(32 * (size_t)n);                   // 8 MB
    vf4*    zjS     = (vf4*)alloc(32 * (size_t)n);                   // 8 MB (raw, pre-fold)
    vh8*    zjH     = (vh8*)alloc(16 * (size_t)n);                   // 4 MB (folded fp16)
    int*    src2    = (int*)alloc(4 * (size_t)E_);                   // 32 MB
    uint32* sp      = (uint32*)alloc(4 * (size_t)E_);                // 32 MB (packed)
    vh4*    z2h     = (vh4*)alloc(8 * (size_t)E_);                   // 64 MB (fp16 z2)
    size_t need_sort = off;                                           // ~162 MB

    bool big = (ws_size >= need_sort) && (n < (1 << 23));

    int nblk = (n + 255) / 256;
    int nbuckets = (n + 511) >> 9;
    int T = (E_ + GB - 1) / GB;

    k_h<<<nblk, 256, 0, stream>>>(pos, vel, lin_w, lin_b, h, n);

    if (big) {
        (void)hipMemsetAsync(sums, 0, 256, stream);

        k_zt<<<nblk, 256, 0, stream>>>(h, mw1, mb1, ziS, zjS, n);

        k_cnt<<<GB, 256, 0, stream>>>(eidx, h, mw1, mb1, cntmat, sums, E_, T);
        k_scanA<<<NB, 256, 0, stream>>>(cntmat, rowtot);
        k_scanB<<<1, 256, 0, stream>>>(rowtot, bbase);

        k_fold<<<nblk, 256, 0, stream>>>(ziS, zjS, zjH, sums, mg1, mbe1, invE, n);

        k_reorder<<<GB, 256, 0, stream>>>(eidx, cntmat, bbase, sp, E_, T);
        k_sort2<<<nbuckets, 256, CAP * 4, stream>>>(sp, bbase, rowtot, src2, nodeoff, n);

        e_pass2<<<4096, 256, 0, stream>>>(src2, nodeoff, ziS, zjH, mw2, mb2, sums + 16, z2h, n);

        e_aggr_z<<<4096, 256, 0, stream>>>(z2h, nodeoff, sums + 16, mg2, mbe2, invE, acc, n);

        n_stats1<<<nblk, 256, 0, stream>>>(h, acc, uw1, ub1, sums + 24, n);
        n_stats2<<<nblk, 256, 0, stream>>>(h, acc, uw1, ub1, sums + 24, ug1, ube1, invN,
                                           uw2, ub2, sums + 40, n);
        n_final<<<nblk, 256, 0, stream>>>(h, acc, uw1, ub1, sums + 24, ug1, ube1,
                                          sums + 40, ug2, ube2, invN,
                                          uw2, ub2, pw, pb, (float2*)d_out, n);
    } else {
        (void)hipMemsetAsync(acc, 0, 32 * (size_t)n + 256, stream);

        fb_stats1<<<4096, 256, 0, stream>>>(eidx, h, mw1, mb1, sums, acc, E_);
        k_fin<<<1, 64, 0, stream>>>(sums, ss, mg1, mbe1, 8, invE);

        fb_stats2<<<4096, 256, 0, stream>>>(eidx, h, mw1, mb1, ss, mw2, mb2, sums + 16, E_);
        k_fin<<<1, 64, 0, stream>>>(sums + 16, ss + 16, mg2, mbe2, 4, invE);

        fb_scatter<<<4096, 256, 0, stream>>>(eidx, h, mw1, mb1, ss, mw2, mb2, ss + 16, acc, E_);

        n_stats1<<<nblk, 256, 0, stream>>>(h, acc, uw1, ub1, sums + 24, n);
        n_stats2<<<nblk, 256, 0, stream>>>(h, acc, uw1, ub1, sums + 24, ug1, ube1, invN,
                                           uw2, ub2, sums + 40, n);
        n_final<<<nblk, 256, 0, stream>>>(h, acc, uw1, ub1, sums + 24, ug1, ube1,
                                          sums + 40, ug2, ube2, invN,
                                          uw2, ub2, pw, pb, (float2*)d_out, n);
    }
}

// Round 24
// 412.282 us; speedup vs baseline: 1.4160x; 1.0484x over previous
//
#include <hip/hip_runtime.h>

#define EPSBN 1e-5f
#define NB 512            // buckets (dst >> 9), 512 nodes per bucket
#define GB 256            // blocks for cnt/reorder tiles
#define CAP 18000         // LDS sort buffer capacity (edges)

typedef float vf4 __attribute__((ext_vector_type(4)));
typedef _Float16 vh8 __attribute__((ext_vector_type(8)));
typedef _Float16 vh4 __attribute__((ext_vector_type(4)));
typedef unsigned int uint32;

// fast tanh: 1 - 2*rcp(exp(2x)+1); v_rcp instead of correctly-rounded div
__device__ __forceinline__ float ftanh(float x) {
    float e = __expf(2.0f * x);
    return 1.0f - 2.0f * __builtin_amdgcn_rcpf(e + 1.0f);
}

__device__ __forceinline__ float wave_sum(float v) {
#pragma unroll
    for (int off = 32; off > 0; off >>= 1) v += __shfl_down(v, off);
    return v;
}

__device__ __forceinline__ void z1_of(const float4 hi, const float4 hj,
                                      const float* __restrict__ w, const float* __restrict__ b,
                                      float* z) {
#pragma unroll
    for (int j = 0; j < 8; ++j) {
        z[j] = b[j]
             + hi.x * w[0 * 8 + j] + hi.y * w[1 * 8 + j] + hi.z * w[2 * 8 + j] + hi.w * w[3 * 8 + j]
             + hj.x * w[4 * 8 + j] + hj.y * w[5 * 8 + j] + hj.z * w[6 * 8 + j] + hj.w * w[7 * 8 + j];
    }
}

__device__ __forceinline__ void mat8x4(const float* u, const float* w,
                                       const float* b, float* z) {
#pragma unroll
    for (int c = 0; c < 4; ++c) {
        float t = b[c];
#pragma unroll
        for (int k = 0; k < 8; ++k) t += u[k] * w[k * 4 + c];
        z[c] = t;
    }
}

__device__ __forceinline__ void mat8x8(const float* u, const float* __restrict__ w,
                                       const float* __restrict__ b, float* z) {
#pragma unroll
    for (int j = 0; j < 8; ++j) {
        float t = b[j];
#pragma unroll
        for (int k = 0; k < 8; ++k) t += u[k] * w[k * 8 + j];
        z[j] = t;
    }
}

// block reduction: NV partials per thread, NW waves per block
template <int NV, int NW>
__device__ __forceinline__ void block_reduce_atomics(float* a, float* __restrict__ sums) {
    __shared__ float red[NV * NW];
    int wid = threadIdx.x >> 6, lane = threadIdx.x & 63;
#pragma unroll
    for (int i = 0; i < NV; ++i) {
        float v = wave_sum(a[i]);
        if (lane == 0) red[i * NW + wid] = v;
    }
    __syncthreads();
    if (threadIdx.x < NV) {
        float v = 0.f;
#pragma unroll
        for (int k = 0; k < NW; ++k) v += red[threadIdx.x * NW + k];
        atomicAdd(&sums[threadIdx.x], v);
    }
}

// compute BN scale/shift into LDS from raw sums (all threads; syncs inside)
__device__ __forceinline__ void fin_lds(const float* __restrict__ sums,
                                        const float* __restrict__ g, const float* __restrict__ be,
                                        int d, float inv, float* out) {
    int j = threadIdx.x;
    if (j < d) {
        float mu = sums[j] * inv;
        float var = sums[d + j] * inv - mu * mu;
        float s = g[j] * rsqrtf(var + EPSBN);
        out[j] = s;
        out[d + j] = be[j] - mu * s;
    }
    __syncthreads();
}

// per-edge z1-stats accumulate (h-based; fused k_cnt + fallback)
__device__ __forceinline__ void stats1_edge(float4 hi, float4 hj,
                                            const float* __restrict__ w1, const float* __restrict__ b1,
                                            float* a) {
    float z[8];
    z1_of(hi, hj, w1, b1, z);
#pragma unroll
    for (int j = 0; j < 8; ++j) { a[j] += z[j]; a[8 + j] += z[j] * z[j]; }
}

// h-based z2 (fallback path only)
__device__ __forceinline__ vf4 z2_edge(float4 hi, float4 hj,
                                       const float* __restrict__ w1, const float* __restrict__ b1,
                                       const float* ss1,
                                       const float* __restrict__ w2, const float* __restrict__ b2) {
    float z[8], m1[8], z2[4];
    z1_of(hi, hj, w1, b1, z);
#pragma unroll
    for (int j = 0; j < 8; ++j) m1[j] = ftanh(z[j] * ss1[j] + ss1[8 + j]);
    mat8x4(m1, w2, b2, z2);
    vf4 r = {z2[0], z2[1], z2[2], z2[3]};
    return r;
}

__device__ __forceinline__ void stats2_edge(float4 hi, float4 hj,
                                            const float* __restrict__ w1, const float* __restrict__ b1,
                                            const float* ss1,
                                            const float* __restrict__ w2, const float* __restrict__ b2,
                                            float* a) {
    vf4 q = z2_edge(hi, hj, w1, b1, ss1, w2, b2);
    a[0] += q.x; a[4] += q.x * q.x;
    a[1] += q.y; a[5] += q.y * q.y;
    a[2] += q.z; a[6] += q.z * q.z;
    a[3] += q.w; a[7] += q.w * q.w;
}

// table-based m1: zi fp32 regs + zj fp16 gathered
__device__ __forceinline__ void m1_ofh(vf4 ziA, vf4 ziB, vh8 zjh, float* m1) {
    m1[0] = ftanh(ziA.x + (float)zjh[0]); m1[1] = ftanh(ziA.y + (float)zjh[1]);
    m1[2] = ftanh(ziA.z + (float)zjh[2]); m1[3] = ftanh(ziA.w + (float)zjh[3]);
    m1[4] = ftanh(ziB.x + (float)zjh[4]); m1[5] = ftanh(ziB.y + (float)zjh[5]);
    m1[6] = ftanh(ziB.z + (float)zjh[6]); m1[7] = ftanh(ziB.w + (float)zjh[7]);
}

// ---------------- node input projection ----------------
__global__ __launch_bounds__(256) void k_h(const float* __restrict__ pos, const float* __restrict__ vel,
                                           const float* __restrict__ w, const float* __restrict__ b,
                                           float4* __restrict__ h, int n) {
    int i = blockIdx.x * blockDim.x + threadIdx.x;
    if (i >= n) return;
    float2 p = ((const float2*)pos)[i];
    float2 v = ((const float2*)vel)[i];
    float o[4];
#pragma unroll
    for (int d = 0; d < 4; ++d)
        o[d] = b[d] + p.x * w[0 * 4 + d] + p.y * w[1 * 4 + d] + v.x * w[2 * 4 + d] + v.y * w[3 * 4 + d];
    h[i] = make_float4(o[0], o[1], o[2], o[3]);
}

// ---------------- z-tables: zi_raw = Wi^T h, zj_raw = Wj^T h + b1 ----------------
__global__ __launch_bounds__(256) void k_zt(const float4* __restrict__ h,
                                            const float* __restrict__ w1, const float* __restrict__ b1,
                                            vf4* __restrict__ zi, vf4* __restrict__ zj, int n) {
    int i = blockIdx.x * blockDim.x + threadIdx.x;
    if (i >= n) return;
    float4 hv = h[i];
    float zi8[8], zj8[8];
#pragma unroll
    for (int j = 0; j < 8; ++j) {
        zi8[j] = hv.x * w1[0 * 8 + j] + hv.y * w1[1 * 8 + j] + hv.z * w1[2 * 8 + j] + hv.w * w1[3 * 8 + j];
        zj8[j] = b1[j]
               + hv.x * w1[4 * 8 + j] + hv.y * w1[5 * 8 + j] + hv.z * w1[6 * 8 + j] + hv.w * w1[7 * 8 + j];
    }
    vf4 a = {zi8[0], zi8[1], zi8[2], zi8[3]};
    vf4 b_ = {zi8[4], zi8[5], zi8[6], zi8[7]};
    vf4 c = {zj8[0], zj8[1], zj8[2], zj8[3]};
    vf4 d = {zj8[4], zj8[5], zj8[6], zj8[7]};
    zi[2 * (size_t)i] = a; zi[2 * (size_t)i + 1] = b_;
    zj[2 * (size_t)i] = c; zj[2 * (size_t)i + 1] = d;
}

// ---------------- fold BN1: zi in-place fp32; zj -> packed fp16 table ----------------
__global__ __launch_bounds__(256) void k_fold(vf4* __restrict__ zi, const vf4* __restrict__ zj,
                                              vh8* __restrict__ zjH,
                                              const float* __restrict__ sums1,
                                              const float* __restrict__ g1, const float* __restrict__ be1,
                                              float invE, int n) {
    __shared__ float ss1[16];
    fin_lds(sums1, g1, be1, 8, invE, ss1);
    int i = blockIdx.x * blockDim.x + threadIdx.x;
    if (i >= n) return;
    vf4 a = zi[2 * (size_t)i], b = zi[2 * (size_t)i + 1];
    a.x *= ss1[0]; a.y *= ss1[1]; a.z *= ss1[2]; a.w *= ss1[3];
    b.x *= ss1[4]; b.y *= ss1[5]; b.z *= ss1[6]; b.w *= ss1[7];
    zi[2 * (size_t)i] = a; zi[2 * (size_t)i + 1] = b;
    vf4 c = zj[2 * (size_t)i], d = zj[2 * (size_t)i + 1];
    vh8 hpk;
    hpk[0] = (_Float16)(c.x * ss1[0] + ss1[8]);
    hpk[1] = (_Float16)(c.y * ss1[1] + ss1[9]);
    hpk[2] = (_Float16)(c.z * ss1[2] + ss1[10]);
    hpk[3] = (_Float16)(c.w * ss1[3] + ss1[11]);
    hpk[4] = (_Float16)(d.x * ss1[4] + ss1[12]);
    hpk[5] = (_Float16)(d.y * ss1[5] + ss1[13]);
    hpk[6] = (_Float16)(d.z * ss1[6] + ss1[14]);
    hpk[7] = (_Float16)(d.w * ss1[7] + ss1[15]);
    zjH[i] = hpk;
}

// ---------------- count + fused z1 stats: 1024-thread blocks (16 waves/CU) ----------------
__global__ __launch_bounds__(1024, 1) void k_cnt(const int* __restrict__ idx, const float4* __restrict__ h,
                                                 const float* __restrict__ w1, const float* __restrict__ b1,
                                                 uint32* __restrict__ cntmat, float* __restrict__ sums,
                                                 int E_, int T) {
    __shared__ uint32 hist[NB];
    for (int b = threadIdx.x; b < NB; b += 1024) hist[b] = 0;
    float a[16];
#pragma unroll
    for (int i = 0; i < 16; ++i) a[i] = 0.f;
    __syncthreads();
    int lo = blockIdx.x * T, hi2 = min(E_, lo + T);
    for (int e0 = lo + 4 * threadIdx.x; e0 < hi2; e0 += 4096) {
        int m = min(4, hi2 - e0);
        if (m == 4) {
            int s0 = __builtin_nontemporal_load(idx + e0);
            int s1 = __builtin_nontemporal_load(idx + e0 + 1);
            int s2 = __builtin_nontemporal_load(idx + e0 + 2);
            int s3 = __builtin_nontemporal_load(idx + e0 + 3);
            int d0 = __builtin_nontemporal_load(idx + E_ + e0);
            int d1 = __builtin_nontemporal_load(idx + E_ + e0 + 1);
            int d2 = __builtin_nontemporal_load(idx + E_ + e0 + 2);
            int d3 = __builtin_nontemporal_load(idx + E_ + e0 + 3);
            float4 hi0 = h[d0], hj0 = h[s0];
            float4 hi1 = h[d1], hj1 = h[s1];
            float4 hi2 = h[d2], hj2 = h[s2];
            float4 hi3 = h[d3], hj3 = h[s3];
            atomicAdd(&hist[d0 >> 9], 1u);
            atomicAdd(&hist[d1 >> 9], 1u);
            atomicAdd(&hist[d2 >> 9], 1u);
            atomicAdd(&hist[d3 >> 9], 1u);
            stats1_edge(hi0, hj0, w1, b1, a);
            stats1_edge(hi1, hj1, w1, b1, a);
            stats1_edge(hi2, hj2, w1, b1, a);
            stats1_edge(hi3, hj3, w1, b1, a);
        } else {
            for (int k = 0; k < m; ++k) {
                int s = __builtin_nontemporal_load(idx + e0 + k);
                int d = __builtin_nontemporal_load(idx + E_ + e0 + k);
                float4 hi = h[d], hj = h[s];
                atomicAdd(&hist[d >> 9], 1u);
                stats1_edge(hi, hj, w1, b1, a);
            }
        }
    }
    __syncthreads();
    for (int b = threadIdx.x; b < NB; b += 1024)
        cntmat[(size_t)b * GB + blockIdx.x] = hist[b];
    block_reduce_atomics<16, 16>(a, sums);
}

// block-scan of 256 uints (1/thread), exclusive
__device__ __forceinline__ void scan256(uint32 v, uint32* excl_out, uint32* total) {
    __shared__ uint32 ts[256];
    ts[threadIdx.x] = v;
    __syncthreads();
    for (int off = 1; off < 256; off <<= 1) {
        uint32 t = (threadIdx.x >= (uint32)off) ? ts[threadIdx.x - off] : 0u;
        __syncthreads();
        ts[threadIdx.x] += t;
        __syncthreads();
    }
    *excl_out = ts[threadIdx.x] - v;
    *total = ts[255];
}

// block-scan of 512 uints (2/thread), exclusive
__device__ __forceinline__ void scan512(uint32* v, uint32* excl_out, uint32* total) {
    __shared__ uint32 ts[256];
    uint32 local = v[0] + v[1];
    ts[threadIdx.x] = local;
    __syncthreads();
    for (int off = 1; off < 256; off <<= 1) {
        uint32 t = (threadIdx.x >= (uint32)off) ? ts[threadIdx.x - off] : 0u;
        __syncthreads();
        ts[threadIdx.x] += t;
        __syncthreads();
    }
    *excl_out = ts[threadIdx.x] - local;
    *total = ts[255];
}

__global__ __launch_bounds__(256) void k_scanA(uint32* __restrict__ cntmat, uint32* __restrict__ rowtot) {
    size_t base = (size_t)blockIdx.x * GB + threadIdx.x;
    uint32 v = cntmat[base];
    uint32 excl, tot;
    scan256(v, &excl, &tot);
    cntmat[base] = excl;
    if (threadIdx.x == 0) rowtot[blockIdx.x] = tot;
}

__global__ __launch_bounds__(256) void k_scanB(const uint32* __restrict__ rowtot, uint32* __restrict__ bbase) {
    uint32 v[2];
    v[0] = rowtot[threadIdx.x * 2]; v[1] = rowtot[threadIdx.x * 2 + 1];
    uint32 excl, tot;
    scan512(v, &excl, &tot);
    bbase[threadIdx.x * 2] = excl;
    bbase[threadIdx.x * 2 + 1] = excl + v[0];
    if (threadIdx.x == 0) bbase[NB] = tot;
}

// ---------------- reorder: packed 4B scatter, 1024-thread blocks ----------------
__global__ __launch_bounds__(1024, 1) void k_reorder(const int* __restrict__ idx,
                                                     const uint32* __restrict__ cntmat, const uint32* __restrict__ bbase,
                                                     uint32* __restrict__ sp, int E_, int T) {
    __shared__ uint32 cur[NB];
    for (int b = threadIdx.x; b < NB; b += 1024)
        cur[b] = bbase[b] + cntmat[(size_t)b * GB + blockIdx.x];
    __syncthreads();
    int lo = blockIdx.x * T, hi2 = min(E_, lo + T);
    for (int e0 = lo + 4 * threadIdx.x; e0 < hi2; e0 += 4096) {
        int m = min(4, hi2 - e0);
        if (m == 4) {
            int s0 = __builtin_nontemporal_load(idx + e0);
            int s1 = __builtin_nontemporal_load(idx + e0 + 1);
            int s2 = __builtin_nontemporal_load(idx + e0 + 2);
            int s3 = __builtin_nontemporal_load(idx + e0 + 3);
            int d0 = __builtin_nontemporal_load(idx + E_ + e0);
            int d1 = __builtin_nontemporal_load(idx + E_ + e0 + 1);
            int d2 = __builtin_nontemporal_load(idx + E_ + e0 + 2);
            int d3 = __builtin_nontemporal_load(idx + E_ + e0 + 3);
            uint32 p0 = atomicAdd(&cur[d0 >> 9], 1u);
            uint32 p1 = atomicAdd(&cur[d1 >> 9], 1u);
            uint32 p2 = atomicAdd(&cur[d2 >> 9], 1u);
            uint32 p3 = atomicAdd(&cur[d3 >> 9], 1u);
            sp[p0] = ((uint32)(d0 & 511) << 23) | (uint32)s0;
            sp[p1] = ((uint32)(d1 & 511) << 23) | (uint32)s1;
            sp[p2] = ((uint32)(d2 & 511) << 23) | (uint32)s2;
            sp[p3] = ((uint32)(d3 & 511) << 23) | (uint32)s3;
        } else {
            for (int k = 0; k < m; ++k) {
                int s = __builtin_nontemporal_load(idx + e0 + k);
                int d = __builtin_nontemporal_load(idx + E_ + e0 + k);
                uint32 pos = atomicAdd(&cur[d >> 9], 1u);
                sp[pos] = ((uint32)(d & 511) << 23) | (uint32)s;
            }
        }
    }
}

// ---------------- sort2: per-bucket counting sort staged in LDS -> CSR ----------------
__global__ __launch_bounds__(256) void k_sort2(const uint32* __restrict__ sp,
                                               const uint32* __restrict__ bbase, const uint32* __restrict__ rowtot,
                                               int* __restrict__ src2, uint32* __restrict__ nodeoff, int n) {
    extern __shared__ uint32 buf[];
    __shared__ uint32 hist[512];
    __shared__ uint32 cur[512];
    int b = blockIdx.x;
    uint32 start = bbase[b];
    uint32 len = rowtot[b];
    uint32 end = start + len;
    hist[threadIdx.x] = 0;
    hist[threadIdx.x + 256] = 0;
    __syncthreads();
    for (uint32 e = start + threadIdx.x; e < end; e += 256) {
        uint32 pk = __builtin_nontemporal_load(&sp[e]);
        atomicAdd(&hist[pk >> 23], 1u);
    }
    __syncthreads();
    uint32 vv[2];
    vv[0] = hist[2 * threadIdx.x];
    vv[1] = hist[2 * threadIdx.x + 1];
    uint32 excl, tot;
    scan512(vv, &excl, &tot);
    cur[2 * threadIdx.x] = excl;
    cur[2 * threadIdx.x + 1] = excl + vv[0];
    int nodebase = b << 9;
    int node0 = nodebase + 2 * threadIdx.x;
    if (node0 <= n)     nodeoff[node0] = start + excl;
    if (node0 + 1 <= n) nodeoff[node0 + 1] = start + excl + vv[0];
    __syncthreads();
    for (uint32 e = start + threadIdx.x; e < end; e += 256) {
        uint32 pk = __builtin_nontemporal_load(&sp[e]);
        uint32 pos = atomicAdd(&cur[pk >> 23], 1u);
        uint32 src = pk & 0x7FFFFFu;
        if (pos < (uint32)CAP) buf[pos] = src;
        else src2[start + pos] = (int)src;
    }
    __syncthreads();
    uint32 lim = min(len, (uint32)CAP);
    for (uint32 k = threadIdx.x; k < lim; k += 256)
        src2[start + k] = (int)buf[k];
}

// ---------------- finalize BN stats (fallback path only) ----------------
__global__ void k_fin(const float* __restrict__ sums, float* __restrict__ ss,
                      const float* __restrict__ g, const float* __restrict__ be,
                      int d, float inv_count) {
    int j = threadIdx.x;
    if (j >= d) return;
    float mu = sums[j] * inv_count;
    float var = sums[d + j] * inv_count - mu * mu;
    float s = g[j] * rsqrtf(var + EPSBN);
    ss[j] = s;
    ss[d + j] = be[j] - mu * s;
}

// ---------------- E2: z2 stats over CSR + z2 fp16 materialization ----------------
__global__ __launch_bounds__(256, 2) void e_pass2(const int* __restrict__ src2, const uint32* __restrict__ nodeoff,
                                                  const vf4* __restrict__ ziS, const vh8* __restrict__ zjH,
                                                  const float* __restrict__ w2, const float* __restrict__ b2,
                                                  float* __restrict__ sums2, vh4* __restrict__ z2h, int n) {
    __shared__ float w2l[32];
    __shared__ float b2l[4];
    if (threadIdx.x < 32) w2l[threadIdx.x] = w2[threadIdx.x];
    if (threadIdx.x < 4)  b2l[threadIdx.x] = b2[threadIdx.x];
    __syncthreads();
    float a[8];
#pragma unroll
    for (int i = 0; i < 8; ++i) a[i] = 0.f;
    int lane = threadIdx.x & 15;
    int gid0 = (blockIdx.x * 256 + threadIdx.x) >> 4;
    int gstride = (gridDim.x * 256) >> 4;
    for (int i = gid0; i < n; i += gstride) {
        uint32 e0 = nodeoff[i], e1 = nodeoff[i + 1];
        vf4 ziA = ziS[2 * (size_t)i], ziB = ziS[2 * (size_t)i + 1];
        for (uint32 e = e0 + lane; e < e1; e += 16) {
            int s = src2[e];
            vh8 zjh = zjH[s];
            float m1[8], z2[4];
            m1_ofh(ziA, ziB, zjh, m1);
            mat8x4(m1, w2l, b2l, z2);
            a[0] += z2[0]; a[4] += z2[0] * z2[0];
            a[1] += z2[1]; a[5] += z2[1] * z2[1];
            a[2] += z2[2]; a[6] += z2[2] * z2[2];
            a[3] += z2[3]; a[7] += z2[3] * z2[3];
            vh4 pk;
            pk[0] = (s == i) ? (_Float16)__builtin_inff() : (_Float16)z2[0];
            pk[1] = (_Float16)z2[1];
            pk[2] = (_Float16)z2[2];
            pk[3] = (_Float16)z2[3];
            z2h[e] = pk;   // regular cached store, sequential within node range
        }
    }
    block_reduce_atomics<8, 4>(a, sums2);
}

// ---------------- aggregate: stream z2h over CSR; BN2-affine + tanh; no gathers ----------------
__global__ __launch_bounds__(256, 2) void e_aggr_z(const vh4* __restrict__ z2h, const uint32* __restrict__ nodeoff,
                                                   const float* __restrict__ sums2,
                                                   const float* __restrict__ g2, const float* __restrict__ be2,
                                                   float invE,
                                                   float* __restrict__ acc, int n) {
    __shared__ float ss2[8];
    fin_lds(sums2, g2, be2, 4, invE, ss2);
    int lane = threadIdx.x & 15;
    int gid0 = (blockIdx.x * 256 + threadIdx.x) >> 4;
    int gstride = (gridDim.x * 256) >> 4;
    for (int i = gid0; i < n; i += gstride) {
        uint32 e0 = nodeoff[i], e1 = nodeoff[i + 1];
        float a0 = 0.f, a1 = 0.f, a2 = 0.f, a3 = 0.f;
        for (uint32 e = e0 + lane; e < e1; e += 16) {
            vh4 pk = z2h[e];
            float z0 = (float)pk[0];
            if (z0 != __builtin_inff()) {   // self-loop sentinel -> message is 0
                a0 += ftanh(z0 * ss2[0] + ss2[4]);
                a1 += ftanh((float)pk[1] * ss2[1] + ss2[5]);
                a2 += ftanh((float)pk[2] * ss2[2] + ss2[6]);
                a3 += ftanh((float)pk[3] * ss2[3] + ss2[7]);
            }
        }
#pragma unroll
        for (int off = 8; off > 0; off >>= 1) {
            a0 += __shfl_down(a0, off, 16);
            a1 += __shfl_down(a1, off, 16);
            a2 += __shfl_down(a2, off, 16);
            a3 += __shfl_down(a3, off, 16);
        }
        if (lane == 0) {
            float* ap = acc + 8 * (size_t)i;
            ap[0] = a0; ap[1] = a1; ap[2] = a2; ap[3] = a3;
            ap[4] = (float)(e1 - e0);
        }
    }
}

// ---------------- fallback edge kernels (round-1 style, used if ws too small) ----------------
__global__ __launch_bounds__(256) void fb_stats1(const int* __restrict__ idx, const float4* __restrict__ h,
                                                 const float* __restrict__ w1, const float* __restrict__ b1,
                                                 float* __restrict__ sums, float* __restrict__ acc, int E_) {
    float a[16];
#pragma unroll
    for (int i = 0; i < 16; ++i) a[i] = 0.f;
    int stride = gridDim.x * blockDim.x;
    for (int e = blockIdx.x * blockDim.x + threadIdx.x; e < E_; e += stride) {
        int s = __builtin_nontemporal_load(idx + e);
        int d = __builtin_nontemporal_load(idx + E_ + e);
        float4 hi = h[d], hj = h[s];
        stats1_edge(hi, hj, w1, b1, a);
        atomicAdd(acc + 8 * (size_t)d + 4, 1.0f);
    }
    block_reduce_atomics<16, 4>(a, sums);
}

__global__ __launch_bounds__(256) void fb_stats2(const int* __restrict__ idx, const float4* __restrict__ h,
                                                 const float* __restrict__ w1, const float* __restrict__ b1,
                                                 const float* __restrict__ ss1,
                                                 const float* __restrict__ w2, const float* __restrict__ b2,
                                                 float* __restrict__ sums2, int E_) {
    float a[8];
#pragma unroll
    for (int i = 0; i < 8; ++i) a[i] = 0.f;
    int stride = gridDim.x * blockDim.x;
    for (int e = blockIdx.x * blockDim.x + threadIdx.x; e < E_; e += stride) {
        int s = __builtin_nontemporal_load(idx + e);
        int d = __builtin_nontemporal_load(idx + E_ + e);
        float4 hi = h[d], hj = h[s];
        stats2_edge(hi, hj, w1, b1, ss1, w2, b2, a);
    }
    block_reduce_atomics<8, 4>(a, sums2);
}

__global__ __launch_bounds__(256) void fb_scatter(const int* __restrict__ idx, const float4* __restrict__ h,
                                                  const float* __restrict__ w1, const float* __restrict__ b1,
                                                  const float* __restrict__ ss1,
                                                  const float* __restrict__ w2, const float* __restrict__ b2,
                                                  const float* __restrict__ ss2,
                                                  float* __restrict__ acc, int E_) {
    int stride = gridDim.x * blockDim.x;
    for (int e = blockIdx.x * blockDim.x + threadIdx.x; e < E_; e += stride) {
        int s = __builtin_nontemporal_load(idx + e);
        int d = __builtin_nontemporal_load(idx + E_ + e);
        float4 hi = h[d], hj = h[s];
        bool zero = (hi.x == hj.x) && (hi.y == hj.y) && (hi.z == hj.z) && (hi.w == hj.w);
        if (zero) continue;
        vf4 q = z2_edge(hi, hj, w1, b1, ss1, w2, b2);
        float m0 = ftanh(q.x * ss2[0] + ss2[4]);
        float m1v = ftanh(q.y * ss2[1] + ss2[5]);
        float m2v = ftanh(q.z * ss2[2] + ss2[6]);
        float m3 = ftanh(q.w * ss2[3] + ss2[7]);
        float* ap = acc + 8 * (size_t)d;
        atomicAdd(ap + 0, m0);
        atomicAdd(ap + 1, m1v);
        atomicAdd(ap + 2, m2v);
        atomicAdd(ap + 3, m3);
    }
}

// ---------------- node update MLP ----------------
__device__ __forceinline__ void load_u(int i, const float4* __restrict__ h,
                                       const float* __restrict__ acc, float* u) {
    float4 hv = h[i];
    const float* ap = acc + 8 * (size_t)i;
    float c = fmaxf(ap[4], 1.0f);
    u[0] = hv.x; u[1] = hv.y; u[2] = hv.z; u[3] = hv.w;
    u[4] = ap[0]; u[5] = ap[1]; u[6] = ap[2] / c; u[7] = ap[3] / c;
}

__global__ __launch_bounds__(256) void n_stats1(const float4* __restrict__ h,
                                                const float* __restrict__ acc,
                                                const float* __restrict__ w, const float* __restrict__ b,
                                                float* __restrict__ sums, int n) {
    float a[16];
#pragma unroll
    for (int i = 0; i < 16; ++i) a[i] = 0.f;
    int stride = gridDim.x * blockDim.x;
    for (int i = blockIdx.x * blockDim.x + threadIdx.x; i < n; i += stride) {
        float u[8], z[8];
        load_u(i, h, acc, u);
        mat8x8(u, w, b, z);
#pragma unroll
        for (int j = 0; j < 8; ++j) { a[j] += z[j]; a[8 + j] += z[j] * z[j]; }
    }
    block_reduce_atomics<16, 4>(a, sums);
}

__global__ __launch_bounds__(256) void n_stats2(const float4* __restrict__ h,
                                                const float* __restrict__ acc,
                                                const float* __restrict__ w1, const float* __restrict__ b1,
                                                const float* __restrict__ sums3,
                                                const float* __restrict__ g3, const float* __restrict__ be3,
                                                float invN,
                                                const float* __restrict__ w2, const float* __restrict__ b2,
                                                float* __restrict__ sums, int n) {
    __shared__ float ss3[16];
    fin_lds(sums3, g3, be3, 8, invN, ss3);
    float a[8];
#pragma unroll
    for (int i = 0; i < 8; ++i) a[i] = 0.f;
    int stride = gridDim.x * blockDim.x;
    for (int i = blockIdx.x * blockDim.x + threadIdx.x; i < n; i += stride) {
        float u[8], z[8], u1[8], z4[4];
        load_u(i, h, acc, u);
        mat8x8(u, w1, b1, z);
#pragma unroll
        for (int j = 0; j < 8; ++j) u1[j] = ftanh(z[j] * ss3[j] + ss3[8 + j]);
        mat8x4(u1, w2, b2, z4);
#pragma unroll
        for (int c = 0; c < 4; ++c) { a[c] += z4[c]; a[4 + c] += z4[c] * z4[c]; }
    }
    block_reduce_atomics<8, 4>(a, sums);
}

__global__ __launch_bounds__(256) void n_final(const float4* __restrict__ h,
                                               const float* __restrict__ acc,
                                               const float* __restrict__ w1, const float* __restrict__ b1,
                                               const float* __restrict__ sums3,
                                               const float* __restrict__ g3, const float* __restrict__ be3,
                                               const float* __restrict__ sums4,
                                               const float* __restrict__ g4, const float* __restrict__ be4,
                                               float invN,
                                               const float* __restrict__ w2, const float* __restrict__ b2,
                                               const float* __restrict__ pw, const float* __restrict__ pb,
                                               float2* __restrict__ out, int n) {
    __shared__ float ss3[16];
    __shared__ float ss4[8];
    fin_lds(sums3, g3, be3, 8, invN, ss3);
    fin_lds(sums4, g4, be4, 4, invN, ss4);
    int stride = gridDim.x * blockDim.x;
    for (int i = blockIdx.x * blockDim.x + threadIdx.x; i < n; i += stride) {
        float u[8], z[8], u1[8], z4[4], u2[4];
        load_u(i, h, acc, u);
        mat8x8(u, w1, b1, z);
#pragma unroll
        for (int j = 0; j < 8; ++j) u1[j] = ftanh(z[j] * ss3[j] + ss3[8 + j]);
        mat8x4(u1, w2, b2, z4);
#pragma unroll
        for (int c = 0; c < 4; ++c) u2[c] = ftanh(z4[c] * ss4[c] + ss4[4 + c]);
        float o0 = pb[0] + u2[0] * pw[0] + u2[1] * pw[2] + u2[2] * pw[4] + u2[3] * pw[6];
        float o1 = pb[1] + u2[0] * pw[1] + u2[1] * pw[3] + u2[2] * pw[5] + u2[3] * pw[7];
        out[i] = make_float2(o0, o1);
    }
}

extern "C" void kernel_launch(void* const* d_in, const int* in_sizes, int n_in,
                              void* d_out, int out_size, void* d_ws, size_t ws_size,
                              hipStream_t stream) {
    const float* pos  = (const float*)d_in[0];
    const float* vel  = (const float*)d_in[1];
    const int*   eidx = (const int*)d_in[2];
    const float* lin_w = (const float*)d_in[3];
    const float* lin_b = (const float*)d_in[4];
    const float* mw1 = (const float*)d_in[5];
    const float* mb1 = (const float*)d_in[6];
    const float* mg1 = (const float*)d_in[7];
    const float* mbe1 = (const float*)d_in[8];
    const float* mw2 = (const float*)d_in[9];
    const float* mb2 = (const float*)d_in[10];
    const float* mg2 = (const float*)d_in[11];
    const float* mbe2 = (const float*)d_in[12];
    const float* uw1 = (const float*)d_in[13];
    const float* ub1 = (const float*)d_in[14];
    const float* ug1 = (const float*)d_in[15];
    const float* ube1 = (const float*)d_in[16];
    const float* uw2 = (const float*)d_in[17];
    const float* ub2 = (const float*)d_in[18];
    const float* ug2 = (const float*)d_in[19];
    const float* ube2 = (const float*)d_in[20];
    const float* pw = (const float*)d_in[21];
    const float* pb = (const float*)d_in[22];

    int n  = in_sizes[0] / 2;
    int E_ = in_sizes[2] / 2;
    float invE = 1.0f / (float)E_;
    float invN = 1.0f / (float)n;

    // ---- workspace layout (bump allocator, 16B aligned) ----
    char* base = (char*)d_ws;
    size_t off = 0;
    auto alloc = [&](size_t bytes) {
        off = (off + 15) & ~(size_t)15;
        void* p = base + off;
        off += bytes;
        return p;
    };
    float4* h       = (float4*)alloc(16 * (size_t)n);                // 4 MB
    float*  acc     = (float*)alloc(32 * (size_t)n);                 // 8 MB
    float*  sums    = (float*)alloc(512);
    float*  ss      = sums + 64;
    uint32* bbase   = (uint32*)alloc(4 * (NB + 1));
    uint32* rowtot  = (uint32*)alloc(4 * NB);
    uint32* cntmat  = (uint32*)alloc(4 * (size_t)NB * GB);           // 0.5 MB
    uint32* nodeoff = (uint32*)alloc(4 * ((size_t)n + 1));           // 1 MB
    vf4*    ziS     = (vf4*)alloc(32 * (size_t)n);                   // 8 MB
    vf4*    zjS     = (vf4*)alloc(32 * (size_t)n);                   // 8 MB (raw, pre-fold)
    vh8*    zjH     = (vh8*)alloc(16 * (size_t)n);                   // 4 MB (folded fp16)
    int*    src2    = (int*)alloc(4 * (size_t)E_);                   // 32 MB
    uint32* sp      = (uint32*)alloc(4 * (size_t)E_);                // 32 MB (packed)
    vh4*    z2h     = (vh4*)alloc(8 * (size_t)E_);                   // 64 MB (fp16 z2)
    size_t need_sort = off;                                           // ~162 MB

    bool big = (ws_size >= need_sort) && (n < (1 << 23));

    int nblk = (n + 255) / 256;
    int nbuckets = (n + 511) >> 9;
    int T = (E_ + GB - 1) / GB;

    k_h<<<nblk, 256, 0, stream>>>(pos, vel, lin_w, lin_b, h, n);

    if (big) {
        (void)hipMemsetAsync(sums, 0, 256, stream);

        k_zt<<<nblk, 256, 0, stream>>>(h, mw1, mb1, ziS, zjS, n);

        k_cnt<<<GB, 1024, 0, stream>>>(eidx, h, mw1, mb1, cntmat, sums, E_, T);
        k_scanA<<<NB, 256, 0, stream>>>(cntmat, rowtot);
        k_scanB<<<1, 256, 0, stream>>>(rowtot, bbase);

        k_fold<<<nblk, 256, 0, stream>>>(ziS, zjS, zjH, sums, mg1, mbe1, invE, n);

        k_reorder<<<GB, 1024, 0, stream>>>(eidx, cntmat, bbase, sp, E_, T);
        k_sort2<<<nbuckets, 256, CAP * 4, stream>>>(sp, bbase, rowtot, src2, nodeoff, n);

        e_pass2<<<4096, 256, 0, stream>>>(src2, nodeoff, ziS, zjH, mw2, mb2, sums + 16, z2h, n);

        e_aggr_z<<<4096, 256, 0, stream>>>(z2h, nodeoff, sums + 16, mg2, mbe2, invE, acc, n);

        n_stats1<<<nblk, 256, 0, stream>>>(h, acc, uw1, ub1, sums + 24, n);
        n_stats2<<<nblk, 256, 0, stream>>>(h, acc, uw1, ub1, sums + 24, ug1, ube1, invN,
                                           uw2, ub2, sums + 40, n);
        n_final<<<nblk, 256, 0, stream>>>(h, acc, uw1, ub1, sums + 24, ug1, ube1,
                                          sums + 40, ug2, ube2, invN,
                                          uw2, ub2, pw, pb, (float2*)d_out, n);
    } else {
        (void)hipMemsetAsync(acc, 0, 32 * (size_t)n + 256, stream);

        fb_stats1<<<4096, 256, 0, stream>>>(eidx, h, mw1, mb1, sums, acc, E_);
        k_fin<<<1, 64, 0, stream>>>(sums, ss, mg1, mbe1, 8, invE);

        fb_stats2<<<4096, 256, 0, stream>>>(eidx, h, mw1, mb1, ss, mw2, mb2, sums + 16, E_);
        k_fin<<<1, 64, 0, stream>>>(sums + 16, ss + 16, mg2, mbe2, 4, invE);

        fb_scatter<<<4096, 256, 0, stream>>>(eidx, h, mw1, mb1, ss, mw2, mb2, ss + 16, acc, E_);

        n_stats1<<<nblk, 256, 0, stream>>>(h, acc, uw1, ub1, sums + 24, n);
        n_stats2<<<nblk, 256, 0, stream>>>(h, acc, uw1, ub1, sums + 24, ug1, ube1, invN,
                                           uw2, ub2, sums + 40, n);
        n_final<<<nblk, 256, 0, stream>>>(h, acc, uw1, ub1, sums + 24, ug1, ube1,
                                          sums + 40, ug2, ube2, invN,
                                          uw2, ub2, pw, pb, (float2*)d_out, n);
    }
}